// Round 3
// baseline (5202.160 us; speedup 1.0000x reference)
//
#include <hip/hip_runtime.h>
#include <math.h>

#define KS 5
#define K3 125

// ---------- helpers ----------

__device__ __forceinline__ unsigned encf(float f) {
    unsigned u = __float_as_uint(f);
    return (u & 0x80000000u) ? ~u : (u | 0x80000000u);
}
__device__ __forceinline__ float decf(unsigned e) {
    unsigned u = (e & 0x80000000u) ? (e ^ 0x80000000u) : ~e;
    return __uint_as_float(u);
}

__device__ __forceinline__ void spline_k0f(const float ps[3], int k0[3], float f[3]) {
    #pragma unroll
    for (int d = 0; d < 3; d++) {
        float v = ps[d] * (float)(KS - 1);
        float kf = floorf(v);
        kf = fminf(fmaxf(kf, 0.0f), (float)(KS - 2));
        k0[d] = (int)kf;
        f[d] = v - kf;
    }
}

__device__ __forceinline__ void spline_basis(const float ps[3], float w[8], int flat[8]) {
    float f[3]; int k0[3];
    spline_k0f(ps, k0, f);
    #pragma unroll
    for (int c = 0; c < 8; c++) {
        float wc = 1.0f; int id[3];
        #pragma unroll
        for (int d = 0; d < 3; d++) {
            int b = (c >> d) & 1;
            wc *= b ? f[d] : (1.0f - f[d]);
            id[d] = k0[d] + b;
        }
        w[c] = wc;
        flat[c] = (id[0] * KS + id[1]) * KS + id[2];
    }
}

// ---------- pooling ----------

__global__ void pool_enc_kernel(const float* __restrict__ in, const int* __restrict__ cluster,
                                unsigned* __restrict__ enc, int n_in, int C) {
    int tid = blockIdx.x * blockDim.x + threadIdx.x;
    if (tid >= n_in * C) return;
    int node = tid / C, c = tid - node * C;
    atomicMax(&enc[(size_t)cluster[node] * C + c], encf(in[tid]));
}

__global__ void decode_kernel(const unsigned* __restrict__ enc, float* __restrict__ out, int n) {
    int tid = blockIdx.x * blockDim.x + threadIdx.x;
    if (tid >= n) return;
    unsigned e = enc[tid];
    out[tid] = (e == 0u) ? 0.0f : decf(e);
}

// ---------- CSR construction (edges grouped by dst) ----------

__global__ void hist_kernel(const int* __restrict__ ei, int* __restrict__ cnt, int E) {
    int e = blockIdx.x * blockDim.x + threadIdx.x;
    if (e >= E) return;
    atomicAdd(&cnt[ei[E + e]], 1);
}

__global__ void scan_kernel(const int* __restrict__ cnt, int* __restrict__ row_start, int n) {
    __shared__ int sdata[1024];
    __shared__ int carry;
    int t = threadIdx.x;
    if (t == 0) carry = 0;
    __syncthreads();
    for (int base = 0; base < n; base += 1024) {
        int i = base + t;
        int v = (i < n) ? cnt[i] : 0;
        sdata[t] = v;
        __syncthreads();
        for (int off = 1; off < 1024; off <<= 1) {
            int add = (t >= off) ? sdata[t - off] : 0;
            __syncthreads();
            sdata[t] += add;
            __syncthreads();
        }
        int incl = sdata[t];
        int total = sdata[1023];
        if (i < n) row_start[i] = carry + incl - v;
        __syncthreads();
        if (t == 0) carry += total;
        __syncthreads();
    }
    if (t == 0) row_start[n] = carry;
}

__global__ void scatter_kernel(const int* __restrict__ ei, int* __restrict__ cursor,
                               const int* __restrict__ row_start, int* __restrict__ csr, int E) {
    int e = blockIdx.x * blockDim.x + threadIdx.x;
    if (e >= E) return;
    int dst = ei[E + e];
    int pos = atomicAdd(&cursor[dst], 1);
    csr[row_start[dst] + pos] = e;
}

// ---------- cell bucketing (edges grouped by 4x4x4 base cell, padded to 256) ----------

__device__ __forceinline__ int cell_of(const float* __restrict__ pseudo, int e) {
    float ps[3] = {pseudo[(size_t)e * 3], pseudo[(size_t)e * 3 + 1], pseudo[(size_t)e * 3 + 2]};
    int k0[3]; float f[3];
    spline_k0f(ps, k0, f);
    return (k0[0] * 4 + k0[1]) * 4 + k0[2];
}

__global__ void cell_hist_kernel(const float* __restrict__ pseudo, int* __restrict__ ccnt, int E) {
    int e = blockIdx.x * blockDim.x + threadIdx.x;
    if (e >= E) return;
    atomicAdd(&ccnt[cell_of(pseudo, e)], 1);
}

__global__ void coff_kernel(const int* __restrict__ ccnt, int* __restrict__ coff) {
    int acc = 0;
    for (int c = 0; c < 64; c++) {
        coff[c] = acc;
        acc += ((ccnt[c] + 255) / 256) * 256;
    }
}

__global__ void cell_scatter_kernel(const float* __restrict__ pseudo, int* __restrict__ ccur,
                                    const int* __restrict__ coff, int* __restrict__ eidx_pad,
                                    int* __restrict__ rank, int E) {
    int e = blockIdx.x * blockDim.x + threadIdx.x;
    if (e >= E) return;
    int cell = cell_of(pseudo, e);
    int pos = atomicAdd(&ccur[cell], 1);
    int slot = coff[cell] + pos;
    eidx_pad[slot] = e;
    rank[e] = slot;
}

// ---------- cell conv: per-workgroup W block in LDS, register-tiled edge-GEMM ----------
// block = 256 threads, TILE = 256 edge slots (all same cell). thread: 4 edges x 8 outputs.

__global__ __launch_bounds__(256, 2) void conv_cell_kernel(
        const float* __restrict__ x, const int* __restrict__ ei, const float* __restrict__ pseudo,
        const int* __restrict__ eidx_pad, const float* __restrict__ W,
        float* __restrict__ y_pad, int E) {
    __shared__ float Wlds[8 * 1024];   // [c][i][o]  32 KB
    __shared__ float xjT[32 * 256];    // [i][slot]  32 KB
    __shared__ float w8l[8 * 256];     // [c][slot]   8 KB
    __shared__ int einfo[256];

    int t = threadIdx.x;
    int base = blockIdx.x * 256;
    int e = eidx_pad[base + t];
    einfo[t] = e;
    __syncthreads();
    int e0 = einfo[0];
    if (e0 < 0) return;   // fully-padded trailing block

    // cell corner bins from slot-0 edge (all edges in block share them)
    {
        float ps0[3] = {pseudo[(size_t)e0 * 3], pseudo[(size_t)e0 * 3 + 1], pseudo[(size_t)e0 * 3 + 2]};
        int k0[3]; float f0[3];
        spline_k0f(ps0, k0, f0);
        int c = t >> 5, ib = t & 31;
        int id0 = k0[0] + ((c >> 0) & 1);
        int id1 = k0[1] + ((c >> 1) & 1);
        int id2 = k0[2] + ((c >> 2) & 1);
        int flat = (id0 * KS + id1) * KS + id2;
        const float4* Wg = (const float4*)(W + (size_t)flat * 1024 + ib * 32);
        float4* Wd = (float4*)&Wlds[c * 1024 + ib * 32];
        #pragma unroll
        for (int j = 0; j < 8; j++) Wd[j] = Wg[j];
    }

    // stage xj (transposed [i][slot]) and per-edge corner weights
    if (e >= 0) {
        int src = ei[e];
        const float4* xr = (const float4*)(x + (size_t)src * 32);
        float4 v[8];
        #pragma unroll
        for (int j = 0; j < 8; j++) v[j] = xr[j];
        const float* vf = (const float*)v;
        #pragma unroll
        for (int i = 0; i < 32; i++) xjT[i * 256 + t] = vf[i];
        float ps[3] = {pseudo[(size_t)e * 3], pseudo[(size_t)e * 3 + 1], pseudo[(size_t)e * 3 + 2]};
        float w[8]; int flat[8];
        spline_basis(ps, w, flat);
        #pragma unroll
        for (int c = 0; c < 8; c++) w8l[c * 256 + t] = w[c];
    } else {
        #pragma unroll
        for (int i = 0; i < 32; i++) xjT[i * 256 + t] = 0.0f;
        #pragma unroll
        for (int c = 0; c < 8; c++) w8l[c * 256 + t] = 0.0f;
    }
    __syncthreads();

    // main loop: eg = t&63 -> edges es..es+3; og = t>>6 -> outputs o0..o0+7
    int eg = t & 63, og = t >> 6;
    int es = eg * 4, o0 = og * 8;
    float acc[4][8];
    #pragma unroll
    for (int j = 0; j < 4; j++)
        #pragma unroll
        for (int k = 0; k < 8; k++) acc[j][k] = 0.0f;

    for (int c = 0; c < 8; c++) {
        float4 wc = *(const float4*)&w8l[c * 256 + es];
        const float* wcf = (const float*)&wc;
        #pragma unroll
        for (int i = 0; i < 32; i++) {
            float4 xv = *(const float4*)&xjT[i * 256 + es];
            float4 wa = *(const float4*)&Wlds[c * 1024 + i * 32 + o0];
            float4 wb = *(const float4*)&Wlds[c * 1024 + i * 32 + o0 + 4];
            const float* xvf = (const float*)&xv;
            const float* waf = (const float*)&wa;
            const float* wbf = (const float*)&wb;
            #pragma unroll
            for (int j = 0; j < 4; j++) {
                float tv = xvf[j] * wcf[j];
                #pragma unroll
                for (int k = 0; k < 4; k++) acc[j][k] += tv * waf[k];
                #pragma unroll
                for (int k = 0; k < 4; k++) acc[j][4 + k] += tv * wbf[k];
            }
        }
    }

    // write per-edge partials (row = padded slot index)
    #pragma unroll
    for (int j = 0; j < 4; j++) {
        if (einfo[es + j] >= 0) {
            float* yr = y_pad + (size_t)(base + es + j) * 32 + o0;
            *(float4*)yr       = *(const float4*)&acc[j][0];
            *(float4*)(yr + 4) = *(const float4*)&acc[j][4];
        }
    }
}

// ---------- gather finalize: sum per-edge partials via dst-CSR, mean+root+bias+ELU ----------

__global__ void gather_fin_kernel(const float* __restrict__ y_pad, const int* __restrict__ rank,
                                  const int* __restrict__ row_start, const int* __restrict__ csr,
                                  const float* __restrict__ x, const float* __restrict__ root,
                                  const float* __restrict__ b, float* __restrict__ out, int n) {
    int tid = blockIdx.x * blockDim.x + threadIdx.x;
    int nd = tid >> 5, o = tid & 31;
    if (nd >= n) return;
    int beg = row_start[nd], end = row_start[nd + 1];
    float acc = 0.0f;
    for (int idx = beg; idx < end; idx++) {
        int r = rank[csr[idx]];
        acc += y_pad[(size_t)r * 32 + o];
    }
    acc /= fmaxf((float)(end - beg), 1.0f);
    const float* __restrict__ xr = x + (size_t)nd * 32;
    float rsum = 0.0f;
    #pragma unroll
    for (int i = 0; i < 32; i++) rsum += xr[i] * root[i * 32 + o];
    float v = acc + rsum + b[o];
    out[(size_t)nd * 32 + o] = (v > 0.0f) ? v : expm1f(v);
}

// ---------- node-centric convs (conv1 + fallback conv32) ----------

__global__ void conv1_node_kernel(const float* __restrict__ x, const int* __restrict__ ei,
                                  const float* __restrict__ pseudo,
                                  const int* __restrict__ row_start, const int* __restrict__ csr,
                                  const float* __restrict__ W, const float* __restrict__ root,
                                  const float* __restrict__ b, float* __restrict__ out, int n) {
    int tid = blockIdx.x * blockDim.x + threadIdx.x;
    int nd = tid >> 5, o = tid & 31;
    if (nd >= n) return;
    int beg = row_start[nd], end = row_start[nd + 1];
    float acc = 0.0f;
    for (int idx = beg; idx < end; idx++) {
        int e = csr[idx];
        int src = ei[e];
        float ps[3] = {pseudo[e * 3], pseudo[e * 3 + 1], pseudo[e * 3 + 2]};
        float w[8]; int flat[8];
        spline_basis(ps, w, flat);
        float s = 0.0f;
        #pragma unroll
        for (int c = 0; c < 8; c++) s += w[c] * W[flat[c] * 32 + o];
        acc += s * x[src];
    }
    float v = acc / fmaxf((float)(end - beg), 1.0f) + x[nd] * root[o] + b[o];
    out[(size_t)nd * 32 + o] = (v > 0.0f) ? v : expm1f(v);
}

__global__ void conv32_node_kernel(const float* __restrict__ x, const int* __restrict__ ei,
                                   const float* __restrict__ pseudo,
                                   const int* __restrict__ row_start, const int* __restrict__ csr,
                                   const float* __restrict__ W, const float* __restrict__ root,
                                   const float* __restrict__ b, float* __restrict__ out, int n) {
    int tid = blockIdx.x * blockDim.x + threadIdx.x;
    int nd = tid >> 5, o = tid & 31;
    if (nd >= n) return;
    int beg = row_start[nd], end = row_start[nd + 1];
    float acc = 0.0f;
    for (int idx = beg; idx < end; idx++) {
        int e = csr[idx];
        int src = ei[e];
        float ps[3] = {pseudo[e * 3], pseudo[e * 3 + 1], pseudo[e * 3 + 2]};
        float w[8]; int flat[8];
        spline_basis(ps, w, flat);
        const float* __restrict__ xj = x + (size_t)src * 32;
        float xv[32];
        #pragma unroll
        for (int i = 0; i < 32; i++) xv[i] = xj[i];
        #pragma unroll
        for (int c = 0; c < 8; c++) {
            const float* __restrict__ Wk = W + flat[c] * 1024 + o;
            float s = 0.0f;
            #pragma unroll
            for (int i = 0; i < 32; i++) s += xv[i] * Wk[i * 32];
            acc += w[c] * s;
        }
    }
    acc /= fmaxf((float)(end - beg), 1.0f);
    const float* __restrict__ xr = x + (size_t)nd * 32;
    float r = 0.0f;
    #pragma unroll
    for (int i = 0; i < 32; i++) r += xr[i] * root[i * 32 + o];
    float v = acc + r + b[o];
    out[(size_t)nd * 32 + o] = (v > 0.0f) ? v : expm1f(v);
}

// ---------- FC + log_softmax ----------

__global__ void fc_kernel(const float* __restrict__ h, const float* __restrict__ fw,
                          const float* __restrict__ fb, float* __restrict__ out, int B) {
    int b = blockIdx.x * blockDim.x + threadIdx.x;
    if (b >= B) return;
    float logit[10];
    #pragma unroll
    for (int j = 0; j < 10; j++) logit[j] = fb[j];
    const float* hb = h + (size_t)b * 256;
    for (int t = 0; t < 256; t++) {
        float hv = hb[t];
        const float* fwt = fw + t * 10;
        #pragma unroll
        for (int j = 0; j < 10; j++) logit[j] += hv * fwt[j];
    }
    float m = logit[0];
    #pragma unroll
    for (int j = 1; j < 10; j++) m = fmaxf(m, logit[j]);
    float s = 0.0f;
    #pragma unroll
    for (int j = 0; j < 10; j++) s += expf(logit[j] - m);
    float lse = logf(s) + m;
    #pragma unroll
    for (int j = 0; j < 10; j++) out[(size_t)b * 10 + j] = logit[j] - lse;
}

// ---------- launch ----------

static inline int cdiv(long long a, int b) { return (int)((a + b - 1) / b); }

extern "C" void kernel_launch(void* const* d_in, const int* in_sizes, int n_in,
                              void* d_out, int out_size, void* d_ws, size_t ws_size,
                              hipStream_t stream) {
    const int N0 = 131072, N1 = 65536, N2 = 32768, N3 = 16384, B8 = 16384;
    const int B = B8 / 8;

    const float* x      = (const float*)d_in[0];
    const int*   cl0    = (const int*)d_in[1];
    const int*   ei1    = (const int*)d_in[2];
    const float* ps1    = (const float*)d_in[3];
    const int*   cl1    = (const int*)d_in[4];
    const int*   ei2    = (const int*)d_in[5];
    const float* ps2    = (const float*)d_in[6];
    const int*   cl2    = (const int*)d_in[7];
    const int*   ei3    = (const int*)d_in[8];
    const float* ps3    = (const float*)d_in[9];
    const int*   cl3    = (const int*)d_in[10];
    const float* W1     = (const float*)d_in[11];
    const float* root1  = (const float*)d_in[12];
    const float* b1     = (const float*)d_in[13];
    const float* W2     = (const float*)d_in[14];
    const float* root2  = (const float*)d_in[15];
    const float* b2     = (const float*)d_in[16];
    const float* W3     = (const float*)d_in[17];
    const float* root3  = (const float*)d_in[18];
    const float* b3     = (const float*)d_in[19];
    const float* fc_w   = (const float*)d_in[20];
    const float* fc_b   = (const float*)d_in[21];
    float* out = (float*)d_out;

    const int E1 = in_sizes[2] / 2;
    const int E2 = in_sizes[5] / 2;
    const int E3 = in_sizes[8] / 2;

    // padded cell-sorted capacity (host-fixed upper bound)
    const int grid2 = cdiv((long long)E2 + 64 * 255, 256);
    const int grid3 = cdiv((long long)E3 + 64 * 255, 256);
    const int padmax = (grid2 > grid3 ? grid2 : grid3) * 256;   // slots (E2 >= E3)

    // ---- workspace layout ----
    char* wp = (char*)d_ws;
    float* p0  = (float*)wp;               wp += (size_t)N1 * 4;
    float* h1  = (float*)wp;               wp += (size_t)N1 * 32 * 4;
    float* p1  = (float*)wp;               wp += (size_t)N2 * 32 * 4;
    float* h2  = (float*)wp;               wp += (size_t)N2 * 32 * 4;
    float* p2  = (float*)wp;               wp += (size_t)N3 * 32 * 4;
    float* h3  = (float*)wp;               wp += (size_t)N3 * 32 * 4;
    float* p3  = (float*)wp;               wp += (size_t)B8 * 32 * 4;
    int* cnt        = (int*)wp;            wp += (size_t)N1 * 4;
    int* row_start  = (int*)wp;            wp += (size_t)(N1 + 1) * 4;
    int* csr        = (int*)wp;            wp += (size_t)E1 * 4;
    int* rank       = (int*)wp;            wp += (size_t)E2 * 4;
    int* coff       = (int*)wp;            wp += 64 * 4;
    int* eidx_pad   = (int*)wp;            wp += (size_t)padmax * 4;
    float* y_pad    = (float*)wp;          // padmax*32 floats; enc overlaid here
    unsigned* enc   = (unsigned*)y_pad;
    size_t need = (size_t)(wp - (char*)d_ws) + (size_t)padmax * 32 * 4;
    bool fast = (ws_size >= need);
    if (!fast) {
        // fallback layout: enc after eidx_pad region start
        enc = (unsigned*)eidx_pad;
    }

    const int T = 256;

    // ---- level 0 pool: x [N0,1] -> p0 [N1] ----
    hipMemsetAsync(enc, 0, (size_t)N1 * 4, stream);
    pool_enc_kernel<<<cdiv(N0, T), T, 0, stream>>>(x, cl0, enc, N0, 1);
    decode_kernel<<<cdiv(N1, T), T, 0, stream>>>(enc, p0, N1);

    // ---- conv1: p0 -> h1 [N1,32] ----
    hipMemsetAsync(cnt, 0, (size_t)N1 * 4, stream);
    hist_kernel<<<cdiv(E1, T), T, 0, stream>>>(ei1, cnt, E1);
    scan_kernel<<<1, 1024, 0, stream>>>(cnt, row_start, N1);
    hipMemsetAsync(cnt, 0, (size_t)N1 * 4, stream);
    scatter_kernel<<<cdiv(E1, T), T, 0, stream>>>(ei1, cnt, row_start, csr, E1);
    conv1_node_kernel<<<cdiv((long long)N1 * 32, T), T, 0, stream>>>(
        p0, ei1, ps1, row_start, csr, W1, root1, b1, h1, N1);

    // ---- pool1: h1 -> p1 [N2,32] ----
    hipMemsetAsync(enc, 0, (size_t)N2 * 32 * 4, stream);
    pool_enc_kernel<<<cdiv((long long)N1 * 32, T), T, 0, stream>>>(h1, cl1, enc, N1, 32);
    decode_kernel<<<cdiv((long long)N2 * 32, T), T, 0, stream>>>(enc, p1, N2 * 32);

    // ---- conv2: p1 -> h2 [N2,32] ----
    hipMemsetAsync(cnt, 0, (size_t)N2 * 4, stream);
    hist_kernel<<<cdiv(E2, T), T, 0, stream>>>(ei2, cnt, E2);
    scan_kernel<<<1, 1024, 0, stream>>>(cnt, row_start, N2);
    hipMemsetAsync(cnt, 0, (size_t)N2 * 4, stream);
    scatter_kernel<<<cdiv(E2, T), T, 0, stream>>>(ei2, cnt, row_start, csr, E2);
    if (fast) {
        hipMemsetAsync(cnt, 0, 64 * 4, stream);
        cell_hist_kernel<<<cdiv(E2, T), T, 0, stream>>>(ps2, cnt, E2);
        coff_kernel<<<1, 1, 0, stream>>>(cnt, coff);
        hipMemsetAsync(cnt, 0, 64 * 4, stream);
        hipMemsetAsync(eidx_pad, 0xFF, (size_t)grid2 * 256 * 4, stream);
        cell_scatter_kernel<<<cdiv(E2, T), T, 0, stream>>>(ps2, cnt, coff, eidx_pad, rank, E2);
        conv_cell_kernel<<<grid2, 256, 0, stream>>>(p1, ei2, ps2, eidx_pad, W2, y_pad, E2);
        gather_fin_kernel<<<cdiv((long long)N2 * 32, T), T, 0, stream>>>(
            y_pad, rank, row_start, csr, p1, root2, b2, h2, N2);
    } else {
        conv32_node_kernel<<<cdiv((long long)N2 * 32, T), T, 0, stream>>>(
            p1, ei2, ps2, row_start, csr, W2, root2, b2, h2, N2);
    }

    // ---- pool2: h2 -> p2 [N3,32] ----
    hipMemsetAsync(enc, 0, (size_t)N3 * 32 * 4, stream);
    pool_enc_kernel<<<cdiv((long long)N2 * 32, T), T, 0, stream>>>(h2, cl2, enc, N2, 32);
    decode_kernel<<<cdiv((long long)N3 * 32, T), T, 0, stream>>>(enc, p2, N3 * 32);

    // ---- conv3: p2 -> h3 [N3,32] ----
    hipMemsetAsync(cnt, 0, (size_t)N3 * 4, stream);
    hist_kernel<<<cdiv(E3, T), T, 0, stream>>>(ei3, cnt, E3);
    scan_kernel<<<1, 1024, 0, stream>>>(cnt, row_start, N3);
    hipMemsetAsync(cnt, 0, (size_t)N3 * 4, stream);
    scatter_kernel<<<cdiv(E3, T), T, 0, stream>>>(ei3, cnt, row_start, csr, E3);
    if (fast) {
        hipMemsetAsync(cnt, 0, 64 * 4, stream);
        cell_hist_kernel<<<cdiv(E3, T), T, 0, stream>>>(ps3, cnt, E3);
        coff_kernel<<<1, 1, 0, stream>>>(cnt, coff);
        hipMemsetAsync(cnt, 0, 64 * 4, stream);
        hipMemsetAsync(eidx_pad, 0xFF, (size_t)grid3 * 256 * 4, stream);
        cell_scatter_kernel<<<cdiv(E3, T), T, 0, stream>>>(ps3, cnt, coff, eidx_pad, rank, E3);
        conv_cell_kernel<<<grid3, 256, 0, stream>>>(p2, ei3, ps3, eidx_pad, W3, y_pad, E3);
        gather_fin_kernel<<<cdiv((long long)N3 * 32, T), T, 0, stream>>>(
            y_pad, rank, row_start, csr, p2, root3, b3, h3, N3);
    } else {
        conv32_node_kernel<<<cdiv((long long)N3 * 32, T), T, 0, stream>>>(
            p2, ei3, ps3, row_start, csr, W3, root3, b3, h3, N3);
    }

    // ---- pool3: h3 -> p3 [B8,32] ----
    hipMemsetAsync(enc, 0, (size_t)B8 * 32 * 4, stream);
    pool_enc_kernel<<<cdiv((long long)N3 * 32, T), T, 0, stream>>>(h3, cl3, enc, N3, 32);
    decode_kernel<<<cdiv((long long)B8 * 32, T), T, 0, stream>>>(enc, p3, B8 * 32);

    // ---- FC + log_softmax ----
    fc_kernel<<<cdiv(B, T), T, 0, stream>>>(p3, fc_w, fc_b, out, B);
}

// Round 4
// 1375.007 us; speedup vs baseline: 3.7834x; 3.7834x over previous
//
#include <hip/hip_runtime.h>
#include <math.h>

#define KS 5
#define K3 125

// ---------- helpers ----------

__device__ __forceinline__ unsigned encf(float f) {
    unsigned u = __float_as_uint(f);
    return (u & 0x80000000u) ? ~u : (u | 0x80000000u);
}
__device__ __forceinline__ float decf(unsigned e) {
    unsigned u = (e & 0x80000000u) ? (e ^ 0x80000000u) : ~e;
    return __uint_as_float(u);
}

__device__ __forceinline__ void spline_k0f(const float ps[3], int k0[3], float f[3]) {
    #pragma unroll
    for (int d = 0; d < 3; d++) {
        float v = ps[d] * (float)(KS - 1);
        float kf = floorf(v);
        kf = fminf(fmaxf(kf, 0.0f), (float)(KS - 2));
        k0[d] = (int)kf;
        f[d] = v - kf;
    }
}

__device__ __forceinline__ void spline_basis(const float ps[3], float w[8], int flat[8]) {
    float f[3]; int k0[3];
    spline_k0f(ps, k0, f);
    #pragma unroll
    for (int c = 0; c < 8; c++) {
        float wc = 1.0f; int id[3];
        #pragma unroll
        for (int d = 0; d < 3; d++) {
            int b = (c >> d) & 1;
            wc *= b ? f[d] : (1.0f - f[d]);
            id[d] = k0[d] + b;
        }
        w[c] = wc;
        flat[c] = (id[0] * KS + id[1]) * KS + id[2];
    }
}

// ---------- pooling ----------

__global__ void pool_enc_kernel(const float* __restrict__ in, const int* __restrict__ cluster,
                                unsigned* __restrict__ enc, int n_in, int C) {
    int tid = blockIdx.x * blockDim.x + threadIdx.x;
    if (tid >= n_in * C) return;
    int node = tid / C, c = tid - node * C;
    atomicMax(&enc[(size_t)cluster[node] * C + c], encf(in[tid]));
}

__global__ void decode_kernel(const unsigned* __restrict__ enc, float* __restrict__ out, int n) {
    int tid = blockIdx.x * blockDim.x + threadIdx.x;
    if (tid >= n) return;
    unsigned e = enc[tid];
    out[tid] = (e == 0u) ? 0.0f : decf(e);
}

// ---------- CSR construction (edges grouped by dst) ----------

__global__ void hist_kernel(const int* __restrict__ ei, int* __restrict__ cnt, int E) {
    int e = blockIdx.x * blockDim.x + threadIdx.x;
    if (e >= E) return;
    atomicAdd(&cnt[ei[E + e]], 1);
}

__global__ void scan_kernel(const int* __restrict__ cnt, int* __restrict__ row_start, int n) {
    __shared__ int sdata[1024];
    __shared__ int carry;
    int t = threadIdx.x;
    if (t == 0) carry = 0;
    __syncthreads();
    for (int base = 0; base < n; base += 1024) {
        int i = base + t;
        int v = (i < n) ? cnt[i] : 0;
        sdata[t] = v;
        __syncthreads();
        for (int off = 1; off < 1024; off <<= 1) {
            int add = (t >= off) ? sdata[t - off] : 0;
            __syncthreads();
            sdata[t] += add;
            __syncthreads();
        }
        int incl = sdata[t];
        int total = sdata[1023];
        if (i < n) row_start[i] = carry + incl - v;
        __syncthreads();
        if (t == 0) carry += total;
        __syncthreads();
    }
    if (t == 0) row_start[n] = carry;
}

__global__ void scatter_kernel(const int* __restrict__ ei, int* __restrict__ cursor,
                               const int* __restrict__ row_start, int* __restrict__ csr, int E) {
    int e = blockIdx.x * blockDim.x + threadIdx.x;
    if (e >= E) return;
    int dst = ei[E + e];
    int pos = atomicAdd(&cursor[dst], 1);
    csr[row_start[dst] + pos] = e;
}

// ---------- cell bucketing (edges grouped by 4x4x4 base cell, padded to 256) ----------

__device__ __forceinline__ int cell_of(const float* __restrict__ pseudo, int e) {
    float ps[3] = {pseudo[(size_t)e * 3], pseudo[(size_t)e * 3 + 1], pseudo[(size_t)e * 3 + 2]};
    int k0[3]; float f[3];
    spline_k0f(ps, k0, f);
    return (k0[0] * 4 + k0[1]) * 4 + k0[2];
}

// privatized histogram + cache cell id per edge
__global__ void cell_hist2_kernel(const float* __restrict__ pseudo, int* __restrict__ ccnt,
                                  int* __restrict__ cellid, int E) {
    __shared__ int lcnt[64];
    int t = threadIdx.x;
    if (t < 64) lcnt[t] = 0;
    __syncthreads();
    int e = blockIdx.x * blockDim.x + t;
    if (e < E) {
        int c = cell_of(pseudo, e);
        cellid[e] = c;
        atomicAdd(&lcnt[c], 1);
    }
    __syncthreads();
    if (t < 64 && lcnt[t] > 0) atomicAdd(&ccnt[t], lcnt[t]);
}

__global__ void coff_kernel(const int* __restrict__ ccnt, int* __restrict__ coff) {
    int acc = 0;
    for (int c = 0; c < 64; c++) {
        coff[c] = acc;
        acc += ((ccnt[c] + 255) / 256) * 256;
    }
}

// two-level scatter: LDS rank within block + one global atomicAdd per (block,cell)
__global__ void cell_scatter2_kernel(const int* __restrict__ cellid, int* __restrict__ gcur,
                                     const int* __restrict__ coff, int* __restrict__ eidx_pad,
                                     int* __restrict__ rank, int E) {
    __shared__ int lcnt[64];
    __shared__ int lbase[64];
    int t = threadIdx.x;
    if (t < 64) lcnt[t] = 0;
    __syncthreads();
    int e = blockIdx.x * blockDim.x + t;
    int cell = 0, myrank = 0;
    if (e < E) {
        cell = cellid[e];
        myrank = atomicAdd(&lcnt[cell], 1);
    }
    __syncthreads();
    if (t < 64) lbase[t] = (lcnt[t] > 0) ? atomicAdd(&gcur[t], lcnt[t]) : 0;
    __syncthreads();
    if (e < E) {
        int slot = coff[cell] + lbase[cell] + myrank;
        eidx_pad[slot] = e;
        rank[e] = slot;
    }
}

// ---------- cell conv: per-workgroup W block in LDS, register-tiled edge-GEMM ----------
// block = 256 threads, TILE = 256 edge slots (all same cell). thread: 4 edges x 8 outputs.

__global__ __launch_bounds__(256, 2) void conv_cell_kernel(
        const float* __restrict__ x, const int* __restrict__ ei, const float* __restrict__ pseudo,
        const int* __restrict__ eidx_pad, const float* __restrict__ W,
        float* __restrict__ y_pad, int E) {
    __shared__ float Wlds[8 * 1024];   // [c][i][o]  32 KB
    __shared__ float xjT[32 * 256];    // [i][slot]  32 KB
    __shared__ float w8l[8 * 256];     // [c][slot]   8 KB
    __shared__ int einfo[256];

    int t = threadIdx.x;
    int base = blockIdx.x * 256;
    int e = eidx_pad[base + t];
    einfo[t] = e;
    __syncthreads();
    int e0 = einfo[0];
    if (e0 < 0) return;   // fully-padded trailing block

    // cell corner bins from slot-0 edge (all edges in block share them)
    {
        float ps0[3] = {pseudo[(size_t)e0 * 3], pseudo[(size_t)e0 * 3 + 1], pseudo[(size_t)e0 * 3 + 2]};
        int k0[3]; float f0[3];
        spline_k0f(ps0, k0, f0);
        int c = t >> 5, ib = t & 31;
        int id0 = k0[0] + ((c >> 0) & 1);
        int id1 = k0[1] + ((c >> 1) & 1);
        int id2 = k0[2] + ((c >> 2) & 1);
        int flat = (id0 * KS + id1) * KS + id2;
        const float4* Wg = (const float4*)(W + (size_t)flat * 1024 + ib * 32);
        float4* Wd = (float4*)&Wlds[c * 1024 + ib * 32];
        #pragma unroll
        for (int j = 0; j < 8; j++) Wd[j] = Wg[j];
    }

    // stage xj (transposed [i][slot]) and per-edge corner weights
    if (e >= 0) {
        int src = ei[e];
        const float4* xr = (const float4*)(x + (size_t)src * 32);
        float4 v[8];
        #pragma unroll
        for (int j = 0; j < 8; j++) v[j] = xr[j];
        const float* vf = (const float*)v;
        #pragma unroll
        for (int i = 0; i < 32; i++) xjT[i * 256 + t] = vf[i];
        float ps[3] = {pseudo[(size_t)e * 3], pseudo[(size_t)e * 3 + 1], pseudo[(size_t)e * 3 + 2]};
        float w[8]; int flat[8];
        spline_basis(ps, w, flat);
        #pragma unroll
        for (int c = 0; c < 8; c++) w8l[c * 256 + t] = w[c];
    } else {
        #pragma unroll
        for (int i = 0; i < 32; i++) xjT[i * 256 + t] = 0.0f;
        #pragma unroll
        for (int c = 0; c < 8; c++) w8l[c * 256 + t] = 0.0f;
    }
    __syncthreads();

    // main loop: eg = t&63 -> edges es..es+3; og = t>>6 -> outputs o0..o0+7
    int eg = t & 63, og = t >> 6;
    int es = eg * 4, o0 = og * 8;
    float acc[4][8];
    #pragma unroll
    for (int j = 0; j < 4; j++)
        #pragma unroll
        for (int k = 0; k < 8; k++) acc[j][k] = 0.0f;

    for (int c = 0; c < 8; c++) {
        float4 wc = *(const float4*)&w8l[c * 256 + es];
        const float* wcf = (const float*)&wc;
        #pragma unroll
        for (int i = 0; i < 32; i++) {
            float4 xv = *(const float4*)&xjT[i * 256 + es];
            float4 wa = *(const float4*)&Wlds[c * 1024 + i * 32 + o0];
            float4 wb = *(const float4*)&Wlds[c * 1024 + i * 32 + o0 + 4];
            const float* xvf = (const float*)&xv;
            const float* waf = (const float*)&wa;
            const float* wbf = (const float*)&wb;
            #pragma unroll
            for (int j = 0; j < 4; j++) {
                float tv = xvf[j] * wcf[j];
                #pragma unroll
                for (int k = 0; k < 4; k++) acc[j][k] += tv * waf[k];
                #pragma unroll
                for (int k = 0; k < 4; k++) acc[j][4 + k] += tv * wbf[k];
            }
        }
    }

    // write per-edge partials (row = padded slot index)
    #pragma unroll
    for (int j = 0; j < 4; j++) {
        if (einfo[es + j] >= 0) {
            float* yr = y_pad + (size_t)(base + es + j) * 32 + o0;
            *(float4*)yr       = *(const float4*)&acc[j][0];
            *(float4*)(yr + 4) = *(const float4*)&acc[j][4];
        }
    }
}

// ---------- gather finalize: sum per-edge partials via dst-CSR, mean+root+bias+ELU ----------

__global__ void gather_fin_kernel(const float* __restrict__ y_pad, const int* __restrict__ rank,
                                  const int* __restrict__ row_start, const int* __restrict__ csr,
                                  const float* __restrict__ x, const float* __restrict__ root,
                                  const float* __restrict__ b, float* __restrict__ out, int n) {
    int tid = blockIdx.x * blockDim.x + threadIdx.x;
    int nd = tid >> 5, o = tid & 31;
    if (nd >= n) return;
    int beg = row_start[nd], end = row_start[nd + 1];
    float acc = 0.0f;
    for (int idx = beg; idx < end; idx++) {
        int r = rank[csr[idx]];
        acc += y_pad[(size_t)r * 32 + o];
    }
    acc /= fmaxf((float)(end - beg), 1.0f);
    const float* __restrict__ xr = x + (size_t)nd * 32;
    float rsum = 0.0f;
    #pragma unroll
    for (int i = 0; i < 32; i++) rsum += xr[i] * root[i * 32 + o];
    float v = acc + rsum + b[o];
    out[(size_t)nd * 32 + o] = (v > 0.0f) ? v : expm1f(v);
}

// ---------- node-centric convs (conv1 + fallback conv32) ----------

__global__ void conv1_node_kernel(const float* __restrict__ x, const int* __restrict__ ei,
                                  const float* __restrict__ pseudo,
                                  const int* __restrict__ row_start, const int* __restrict__ csr,
                                  const float* __restrict__ W, const float* __restrict__ root,
                                  const float* __restrict__ b, float* __restrict__ out, int n) {
    int tid = blockIdx.x * blockDim.x + threadIdx.x;
    int nd = tid >> 5, o = tid & 31;
    if (nd >= n) return;
    int beg = row_start[nd], end = row_start[nd + 1];
    float acc = 0.0f;
    for (int idx = beg; idx < end; idx++) {
        int e = csr[idx];
        int src = ei[e];
        float ps[3] = {pseudo[e * 3], pseudo[e * 3 + 1], pseudo[e * 3 + 2]};
        float w[8]; int flat[8];
        spline_basis(ps, w, flat);
        float s = 0.0f;
        #pragma unroll
        for (int c = 0; c < 8; c++) s += w[c] * W[flat[c] * 32 + o];
        acc += s * x[src];
    }
    float v = acc / fmaxf((float)(end - beg), 1.0f) + x[nd] * root[o] + b[o];
    out[(size_t)nd * 32 + o] = (v > 0.0f) ? v : expm1f(v);
}

__global__ void conv32_node_kernel(const float* __restrict__ x, const int* __restrict__ ei,
                                   const float* __restrict__ pseudo,
                                   const int* __restrict__ row_start, const int* __restrict__ csr,
                                   const float* __restrict__ W, const float* __restrict__ root,
                                   const float* __restrict__ b, float* __restrict__ out, int n) {
    int tid = blockIdx.x * blockDim.x + threadIdx.x;
    int nd = tid >> 5, o = tid & 31;
    if (nd >= n) return;
    int beg = row_start[nd], end = row_start[nd + 1];
    float acc = 0.0f;
    for (int idx = beg; idx < end; idx++) {
        int e = csr[idx];
        int src = ei[e];
        float ps[3] = {pseudo[e * 3], pseudo[e * 3 + 1], pseudo[e * 3 + 2]};
        float w[8]; int flat[8];
        spline_basis(ps, w, flat);
        const float* __restrict__ xj = x + (size_t)src * 32;
        float xv[32];
        #pragma unroll
        for (int i = 0; i < 32; i++) xv[i] = xj[i];
        #pragma unroll
        for (int c = 0; c < 8; c++) {
            const float* __restrict__ Wk = W + flat[c] * 1024 + o;
            float s = 0.0f;
            #pragma unroll
            for (int i = 0; i < 32; i++) s += xv[i] * Wk[i * 32];
            acc += w[c] * s;
        }
    }
    acc /= fmaxf((float)(end - beg), 1.0f);
    const float* __restrict__ xr = x + (size_t)nd * 32;
    float r = 0.0f;
    #pragma unroll
    for (int i = 0; i < 32; i++) r += xr[i] * root[i * 32 + o];
    float v = acc + r + b[o];
    out[(size_t)nd * 32 + o] = (v > 0.0f) ? v : expm1f(v);
}

// ---------- FC + log_softmax ----------

__global__ void fc_kernel(const float* __restrict__ h, const float* __restrict__ fw,
                          const float* __restrict__ fb, float* __restrict__ out, int B) {
    int b = blockIdx.x * blockDim.x + threadIdx.x;
    if (b >= B) return;
    float logit[10];
    #pragma unroll
    for (int j = 0; j < 10; j++) logit[j] = fb[j];
    const float* hb = h + (size_t)b * 256;
    for (int t = 0; t < 256; t++) {
        float hv = hb[t];
        const float* fwt = fw + t * 10;
        #pragma unroll
        for (int j = 0; j < 10; j++) logit[j] += hv * fwt[j];
    }
    float m = logit[0];
    #pragma unroll
    for (int j = 1; j < 10; j++) m = fmaxf(m, logit[j]);
    float s = 0.0f;
    #pragma unroll
    for (int j = 0; j < 10; j++) s += expf(logit[j] - m);
    float lse = logf(s) + m;
    #pragma unroll
    for (int j = 0; j < 10; j++) out[(size_t)b * 10 + j] = logit[j] - lse;
}

// ---------- launch ----------

static inline int cdiv(long long a, int b) { return (int)((a + b - 1) / b); }

extern "C" void kernel_launch(void* const* d_in, const int* in_sizes, int n_in,
                              void* d_out, int out_size, void* d_ws, size_t ws_size,
                              hipStream_t stream) {
    const int N0 = 131072, N1 = 65536, N2 = 32768, N3 = 16384, B8 = 16384;
    const int B = B8 / 8;

    const float* x      = (const float*)d_in[0];
    const int*   cl0    = (const int*)d_in[1];
    const int*   ei1    = (const int*)d_in[2];
    const float* ps1    = (const float*)d_in[3];
    const int*   cl1    = (const int*)d_in[4];
    const int*   ei2    = (const int*)d_in[5];
    const float* ps2    = (const float*)d_in[6];
    const int*   cl2    = (const int*)d_in[7];
    const int*   ei3    = (const int*)d_in[8];
    const float* ps3    = (const float*)d_in[9];
    const int*   cl3    = (const int*)d_in[10];
    const float* W1     = (const float*)d_in[11];
    const float* root1  = (const float*)d_in[12];
    const float* b1     = (const float*)d_in[13];
    const float* W2     = (const float*)d_in[14];
    const float* root2  = (const float*)d_in[15];
    const float* b2     = (const float*)d_in[16];
    const float* W3     = (const float*)d_in[17];
    const float* root3  = (const float*)d_in[18];
    const float* b3     = (const float*)d_in[19];
    const float* fc_w   = (const float*)d_in[20];
    const float* fc_b   = (const float*)d_in[21];
    float* out = (float*)d_out;

    const int E1 = in_sizes[2] / 2;
    const int E2 = in_sizes[5] / 2;
    const int E3 = in_sizes[8] / 2;

    // padded cell-sorted capacity (host-fixed upper bound)
    const int grid2 = cdiv((long long)E2 + 64 * 255, 256);
    const int grid3 = cdiv((long long)E3 + 64 * 255, 256);
    const int padmax = (grid2 > grid3 ? grid2 : grid3) * 256;   // slots (E2 >= E3)

    // ---- workspace layout ----
    char* wp = (char*)d_ws;
    float* p0  = (float*)wp;               wp += (size_t)N1 * 4;
    float* h1  = (float*)wp;               wp += (size_t)N1 * 32 * 4;
    float* p1  = (float*)wp;               wp += (size_t)N2 * 32 * 4;
    float* h2  = (float*)wp;               wp += (size_t)N2 * 32 * 4;
    float* p2  = (float*)wp;               wp += (size_t)N3 * 32 * 4;
    float* h3  = (float*)wp;               wp += (size_t)N3 * 32 * 4;
    float* p3  = (float*)wp;               wp += (size_t)B8 * 32 * 4;
    int* cnt        = (int*)wp;            wp += (size_t)N1 * 4;
    int* row_start  = (int*)wp;            wp += (size_t)(N1 + 1) * 4;
    int* csr        = (int*)wp;            wp += (size_t)E1 * 4;
    int* rank       = (int*)wp;            wp += (size_t)E2 * 4;
    int* cellid     = (int*)wp;            wp += (size_t)E2 * 4;
    int* coff       = (int*)wp;            wp += 64 * 4;
    int* eidx_pad   = (int*)wp;            wp += (size_t)padmax * 4;
    float* y_pad    = (float*)wp;          // padmax*32 floats; enc overlaid here
    unsigned* enc   = (unsigned*)y_pad;
    size_t need = (size_t)(wp - (char*)d_ws) + (size_t)padmax * 32 * 4;
    bool fast = (ws_size >= need);
    if (!fast) {
        enc = (unsigned*)eidx_pad;
    }

    const int T = 256;

    // ---- level 0 pool: x [N0,1] -> p0 [N1] ----
    hipMemsetAsync(enc, 0, (size_t)N1 * 4, stream);
    pool_enc_kernel<<<cdiv(N0, T), T, 0, stream>>>(x, cl0, enc, N0, 1);
    decode_kernel<<<cdiv(N1, T), T, 0, stream>>>(enc, p0, N1);

    // ---- conv1: p0 -> h1 [N1,32] ----
    hipMemsetAsync(cnt, 0, (size_t)N1 * 4, stream);
    hist_kernel<<<cdiv(E1, T), T, 0, stream>>>(ei1, cnt, E1);
    scan_kernel<<<1, 1024, 0, stream>>>(cnt, row_start, N1);
    hipMemsetAsync(cnt, 0, (size_t)N1 * 4, stream);
    scatter_kernel<<<cdiv(E1, T), T, 0, stream>>>(ei1, cnt, row_start, csr, E1);
    conv1_node_kernel<<<cdiv((long long)N1 * 32, T), T, 0, stream>>>(
        p0, ei1, ps1, row_start, csr, W1, root1, b1, h1, N1);

    // ---- pool1: h1 -> p1 [N2,32] ----
    hipMemsetAsync(enc, 0, (size_t)N2 * 32 * 4, stream);
    pool_enc_kernel<<<cdiv((long long)N1 * 32, T), T, 0, stream>>>(h1, cl1, enc, N1, 32);
    decode_kernel<<<cdiv((long long)N2 * 32, T), T, 0, stream>>>(enc, p1, N2 * 32);

    // ---- conv2: p1 -> h2 [N2,32] ----
    hipMemsetAsync(cnt, 0, (size_t)N2 * 4, stream);
    hist_kernel<<<cdiv(E2, T), T, 0, stream>>>(ei2, cnt, E2);
    scan_kernel<<<1, 1024, 0, stream>>>(cnt, row_start, N2);
    hipMemsetAsync(cnt, 0, (size_t)N2 * 4, stream);
    scatter_kernel<<<cdiv(E2, T), T, 0, stream>>>(ei2, cnt, row_start, csr, E2);
    if (fast) {
        hipMemsetAsync(cnt, 0, 64 * 4, stream);
        cell_hist2_kernel<<<cdiv(E2, 1024), 1024, 0, stream>>>(ps2, cnt, cellid, E2);
        coff_kernel<<<1, 1, 0, stream>>>(cnt, coff);
        hipMemsetAsync(cnt, 0, 64 * 4, stream);
        hipMemsetAsync(eidx_pad, 0xFF, (size_t)grid2 * 256 * 4, stream);
        cell_scatter2_kernel<<<cdiv(E2, 1024), 1024, 0, stream>>>(cellid, cnt, coff, eidx_pad, rank, E2);
        conv_cell_kernel<<<grid2, 256, 0, stream>>>(p1, ei2, ps2, eidx_pad, W2, y_pad, E2);
        gather_fin_kernel<<<cdiv((long long)N2 * 32, T), T, 0, stream>>>(
            y_pad, rank, row_start, csr, p1, root2, b2, h2, N2);
    } else {
        conv32_node_kernel<<<cdiv((long long)N2 * 32, T), T, 0, stream>>>(
            p1, ei2, ps2, row_start, csr, W2, root2, b2, h2, N2);
    }

    // ---- pool2: h2 -> p2 [N3,32] ----
    hipMemsetAsync(enc, 0, (size_t)N3 * 32 * 4, stream);
    pool_enc_kernel<<<cdiv((long long)N2 * 32, T), T, 0, stream>>>(h2, cl2, enc, N2, 32);
    decode_kernel<<<cdiv((long long)N3 * 32, T), T, 0, stream>>>(enc, p2, N3 * 32);

    // ---- conv3: p2 -> h3 [N3,32] ----
    hipMemsetAsync(cnt, 0, (size_t)N3 * 4, stream);
    hist_kernel<<<cdiv(E3, T), T, 0, stream>>>(ei3, cnt, E3);
    scan_kernel<<<1, 1024, 0, stream>>>(cnt, row_start, N3);
    hipMemsetAsync(cnt, 0, (size_t)N3 * 4, stream);
    scatter_kernel<<<cdiv(E3, T), T, 0, stream>>>(ei3, cnt, row_start, csr, E3);
    if (fast) {
        hipMemsetAsync(cnt, 0, 64 * 4, stream);
        cell_hist2_kernel<<<cdiv(E3, 1024), 1024, 0, stream>>>(ps3, cnt, cellid, E3);
        coff_kernel<<<1, 1, 0, stream>>>(cnt, coff);
        hipMemsetAsync(cnt, 0, 64 * 4, stream);
        hipMemsetAsync(eidx_pad, 0xFF, (size_t)grid3 * 256 * 4, stream);
        cell_scatter2_kernel<<<cdiv(E3, 1024), 1024, 0, stream>>>(cellid, cnt, coff, eidx_pad, rank, E3);
        conv_cell_kernel<<<grid3, 256, 0, stream>>>(p2, ei3, ps3, eidx_pad, W3, y_pad, E3);
        gather_fin_kernel<<<cdiv((long long)N3 * 32, T), T, 0, stream>>>(
            y_pad, rank, row_start, csr, p2, root3, b3, h3, N3);
    } else {
        conv32_node_kernel<<<cdiv((long long)N3 * 32, T), T, 0, stream>>>(
            p2, ei3, ps3, row_start, csr, W3, root3, b3, h3, N3);
    }

    // ---- pool3: h3 -> p3 [B8,32] ----
    hipMemsetAsync(enc, 0, (size_t)B8 * 32 * 4, stream);
    pool_enc_kernel<<<cdiv((long long)N3 * 32, T), T, 0, stream>>>(h3, cl3, enc, N3, 32);
    decode_kernel<<<cdiv((long long)B8 * 32, T), T, 0, stream>>>(enc, p3, B8 * 32);

    // ---- FC + log_softmax ----
    fc_kernel<<<cdiv(B, T), T, 0, stream>>>(p3, fc_w, fc_b, out, B);
}

// Round 5
// 1123.460 us; speedup vs baseline: 4.6305x; 1.2239x over previous
//
#include <hip/hip_runtime.h>
#include <math.h>

#define KS 5
#define K3 125

// ---------- helpers ----------

__device__ __forceinline__ unsigned encf(float f) {
    unsigned u = __float_as_uint(f);
    return (u & 0x80000000u) ? ~u : (u | 0x80000000u);
}
__device__ __forceinline__ float decf(unsigned e) {
    unsigned u = (e & 0x80000000u) ? (e ^ 0x80000000u) : ~e;
    return __uint_as_float(u);
}

__device__ __forceinline__ void spline_k0f(const float ps[3], int k0[3], float f[3]) {
    #pragma unroll
    for (int d = 0; d < 3; d++) {
        float v = ps[d] * (float)(KS - 1);
        float kf = floorf(v);
        kf = fminf(fmaxf(kf, 0.0f), (float)(KS - 2));
        k0[d] = (int)kf;
        f[d] = v - kf;
    }
}

__device__ __forceinline__ void spline_basis(const float ps[3], float w[8], int flat[8]) {
    float f[3]; int k0[3];
    spline_k0f(ps, k0, f);
    #pragma unroll
    for (int c = 0; c < 8; c++) {
        float wc = 1.0f; int id[3];
        #pragma unroll
        for (int d = 0; d < 3; d++) {
            int b = (c >> d) & 1;
            wc *= b ? f[d] : (1.0f - f[d]);
            id[d] = k0[d] + b;
        }
        w[c] = wc;
        flat[c] = (id[0] * KS + id[1]) * KS + id[2];
    }
}

__device__ __forceinline__ int cell_of(const float* __restrict__ pseudo, int e) {
    float ps[3] = {pseudo[(size_t)e * 3], pseudo[(size_t)e * 3 + 1], pseudo[(size_t)e * 3 + 2]};
    int k0[3]; float f[3];
    spline_k0f(ps, k0, f);
    return (k0[0] * 4 + k0[1]) * 4 + k0[2];
}

// ---------- pooling ----------

__global__ void pool_enc_kernel(const float* __restrict__ in, const int* __restrict__ cluster,
                                unsigned* __restrict__ enc, int n_in, int C) {
    int tid = blockIdx.x * blockDim.x + threadIdx.x;
    if (tid >= n_in * C) return;
    int node = tid / C, c = tid - node * C;
    atomicMax(&enc[(size_t)cluster[node] * C + c], encf(in[tid]));
}

__global__ void decode_kernel(const unsigned* __restrict__ enc, float* __restrict__ out, int n) {
    int tid = blockIdx.x * blockDim.x + threadIdx.x;
    if (tid >= n) return;
    unsigned e = enc[tid];
    out[tid] = (e == 0u) ? 0.0f : decf(e);
}

// ---------- fused indexing: CSR hist (all 3 levels) + cell hist/cellid (levels 2,3) ----------
// cnt layout: [0,N1) level1 | [N1,N1+N2) level2 | [N1+N2,N1+N2+N3) level3
// ccnt: [0,64) level2 cells | [64,128) level3 cells

__global__ void index_hist_all(const int* __restrict__ ei1, const int* __restrict__ ei2,
                               const int* __restrict__ ei3,
                               const float* __restrict__ ps2, const float* __restrict__ ps3,
                               int* __restrict__ cnt, int* __restrict__ ccnt,
                               int* __restrict__ cellid2, int* __restrict__ cellid3,
                               int E1, int E2, int E3, int N1, int N2) {
    __shared__ int lcnt[128];
    int t = threadIdx.x;
    if (t < 128) lcnt[t] = 0;
    __syncthreads();
    long long g = (long long)blockIdx.x * blockDim.x + t;
    long long Etot = (long long)E1 + E2 + E3;
    if (g < Etot) {
        if (g < E1) {
            int e = (int)g;
            atomicAdd(&cnt[ei1[E1 + e]], 1);
        } else if (g < (long long)E1 + E2) {
            int e = (int)(g - E1);
            atomicAdd(&cnt[N1 + ei2[E2 + e]], 1);
            int c = cell_of(ps2, e);
            cellid2[e] = c;
            atomicAdd(&lcnt[c], 1);
        } else {
            int e = (int)(g - E1 - E2);
            atomicAdd(&cnt[N1 + N2 + ei3[E3 + e]], 1);
            int c = cell_of(ps3, e);
            cellid3[e] = c;
            atomicAdd(&lcnt[64 + c], 1);
        }
    }
    __syncthreads();
    if (t < 128 && lcnt[t] > 0) atomicAdd(&ccnt[t], lcnt[t]);
}

// ---------- hierarchical segmented scan over cnt[0..N1+N2+N3) ----------
// segments are block-aligned (N1,N2,N3 multiples of 1024). rows: row1[N1+1],row2[N2+1],row3[N3+1].

__device__ __forceinline__ int* row_slot(int i, int* row1, int* row2, int* row3, int N1, int N2) {
    if (i < N1) return row1 + i;
    if (i < N1 + N2) return row2 + (i - N1);
    return row3 + (i - N1 - N2);
}

__global__ void scan_blocks_kernel(const int* __restrict__ cnt, int* __restrict__ row1,
                                   int* __restrict__ row2, int* __restrict__ row3,
                                   int* __restrict__ bsum, int N1, int N2) {
    __shared__ int sdata[1024];
    int t = threadIdx.x;
    int i = blockIdx.x * 1024 + t;
    int v = cnt[i];
    sdata[t] = v;
    __syncthreads();
    for (int off = 1; off < 1024; off <<= 1) {
        int add = (t >= off) ? sdata[t - off] : 0;
        __syncthreads();
        sdata[t] += add;
        __syncthreads();
    }
    *row_slot(i, row1, row2, row3, N1, N2) = sdata[t] - v;   // exclusive within block
    if (t == 1023) bsum[blockIdx.x] = sdata[1023];
}

// single block: segmented scan of 112 block sums (resets at blocks nb1, nb1+nb2) + coff for cells
__global__ void scan_sums_kernel(int* __restrict__ bsum, const int* __restrict__ ccnt,
                                 int* __restrict__ coff, int nb, int nb1, int nb12) {
    __shared__ int sdata[128];
    __shared__ int sseg[128];
    int t = threadIdx.x;
    int v = (t < nb) ? bsum[t] : 0;
    int seg = (t < nb1) ? 0 : (t < nb12) ? 1 : 2;
    sdata[t] = v; sseg[t] = seg;
    __syncthreads();
    for (int off = 1; off < 128; off <<= 1) {
        int add = (t >= off && sseg[t - off] == seg) ? sdata[t - off] : 0;
        __syncthreads();
        sdata[t] += add;
        __syncthreads();
    }
    if (t < nb) bsum[t] = sdata[t] - v;   // exclusive base per block, segment-local
    if (t == 0) {
        int acc = 0;
        for (int c = 0; c < 64; c++) { coff[c] = acc; acc += ((ccnt[c] + 255) / 256) * 256; }
    }
    if (t == 1) {
        int acc = 0;
        for (int c = 0; c < 64; c++) { coff[64 + c] = acc; acc += ((ccnt[64 + c] + 255) / 256) * 256; }
    }
}

__global__ void scan_add_kernel(int* __restrict__ row1, int* __restrict__ row2,
                                int* __restrict__ row3, const int* __restrict__ bsum,
                                int N1, int N2, int N3, int E1, int E2, int E3) {
    int t = threadIdx.x;
    int i = blockIdx.x * 1024 + t;
    *row_slot(i, row1, row2, row3, N1, N2) += bsum[blockIdx.x];
    if (blockIdx.x == 0) {
        if (t == 0) row1[N1] = E1;
        if (t == 1) row2[N2] = E2;
        if (t == 2) row3[N3] = E3;
    }
}

// ---------- fused scatter: CSR (all levels) + padded cell buckets (levels 2,3) ----------

__global__ void scatter_all(const int* __restrict__ ei1, const int* __restrict__ ei2,
                            const int* __restrict__ ei3,
                            int* __restrict__ cur,
                            const int* __restrict__ row1, const int* __restrict__ row2,
                            const int* __restrict__ row3,
                            int* __restrict__ csr1, int* __restrict__ csr2, int* __restrict__ csr3,
                            const int* __restrict__ cellid2, const int* __restrict__ cellid3,
                            int* __restrict__ ccur, const int* __restrict__ coff,
                            int* __restrict__ eidx2, int* __restrict__ eidx3,
                            int* __restrict__ rank2, int* __restrict__ rank3,
                            int E1, int E2, int E3, int N1, int N2) {
    __shared__ int lcnt[128];
    __shared__ int lbase[128];
    int t = threadIdx.x;
    if (t < 128) lcnt[t] = 0;
    __syncthreads();
    long long g = (long long)blockIdx.x * blockDim.x + t;
    long long Etot = (long long)E1 + E2 + E3;
    int lidx = -1, myrank = 0, e = -1, lvl = 0;
    if (g < Etot) {
        if (g < E1) {
            e = (int)g; lvl = 1;
            int dst = ei1[E1 + e];
            int pos = atomicAdd(&cur[dst], 1);
            csr1[row1[dst] + pos] = e;
        } else if (g < (long long)E1 + E2) {
            e = (int)(g - E1); lvl = 2;
            int dst = ei2[E2 + e];
            int pos = atomicAdd(&cur[N1 + dst], 1);
            csr2[row2[dst] + pos] = e;
            lidx = cellid2[e];
            myrank = atomicAdd(&lcnt[lidx], 1);
        } else {
            e = (int)(g - E1 - E2); lvl = 3;
            int dst = ei3[E3 + e];
            int pos = atomicAdd(&cur[N1 + N2 + dst], 1);
            csr3[row3[dst] + pos] = e;
            lidx = 64 + cellid3[e];
            myrank = atomicAdd(&lcnt[lidx], 1);
        }
    }
    __syncthreads();
    if (t < 128) lbase[t] = (lcnt[t] > 0) ? atomicAdd(&ccur[t], lcnt[t]) : 0;
    __syncthreads();
    if (lidx >= 0) {
        int slot = coff[lidx] + lbase[lidx] + myrank;
        if (lvl == 2) { eidx2[slot] = e; rank2[e] = slot; }
        else          { eidx3[slot] = e; rank3[e] = slot; }
    }
}

// ---------- cell conv: per-workgroup W block in LDS, register-tiled edge-GEMM ----------

__global__ __launch_bounds__(256, 2) void conv_cell_kernel(
        const float* __restrict__ x, const int* __restrict__ ei, const float* __restrict__ pseudo,
        const int* __restrict__ eidx_pad, const float* __restrict__ W,
        float* __restrict__ y_pad, int E) {
    __shared__ float Wlds[8 * 1024];   // [c][i][o]  32 KB
    __shared__ float xjT[32 * 256];    // [i][slot]  32 KB
    __shared__ float w8l[8 * 256];     // [c][slot]   8 KB
    __shared__ int einfo[256];

    int t = threadIdx.x;
    int base = blockIdx.x * 256;
    int e = eidx_pad[base + t];
    einfo[t] = e;
    __syncthreads();
    int e0 = einfo[0];
    if (e0 < 0) return;

    {
        float ps0[3] = {pseudo[(size_t)e0 * 3], pseudo[(size_t)e0 * 3 + 1], pseudo[(size_t)e0 * 3 + 2]};
        int k0[3]; float f0[3];
        spline_k0f(ps0, k0, f0);
        int c = t >> 5, ib = t & 31;
        int id0 = k0[0] + ((c >> 0) & 1);
        int id1 = k0[1] + ((c >> 1) & 1);
        int id2 = k0[2] + ((c >> 2) & 1);
        int flat = (id0 * KS + id1) * KS + id2;
        const float4* Wg = (const float4*)(W + (size_t)flat * 1024 + ib * 32);
        float4* Wd = (float4*)&Wlds[c * 1024 + ib * 32];
        #pragma unroll
        for (int j = 0; j < 8; j++) Wd[j] = Wg[j];
    }

    if (e >= 0) {
        int src = ei[e];
        const float4* xr = (const float4*)(x + (size_t)src * 32);
        float4 v[8];
        #pragma unroll
        for (int j = 0; j < 8; j++) v[j] = xr[j];
        const float* vf = (const float*)v;
        #pragma unroll
        for (int i = 0; i < 32; i++) xjT[i * 256 + t] = vf[i];
        float ps[3] = {pseudo[(size_t)e * 3], pseudo[(size_t)e * 3 + 1], pseudo[(size_t)e * 3 + 2]};
        float w[8]; int flat[8];
        spline_basis(ps, w, flat);
        #pragma unroll
        for (int c = 0; c < 8; c++) w8l[c * 256 + t] = w[c];
    } else {
        #pragma unroll
        for (int i = 0; i < 32; i++) xjT[i * 256 + t] = 0.0f;
        #pragma unroll
        for (int c = 0; c < 8; c++) w8l[c * 256 + t] = 0.0f;
    }
    __syncthreads();

    int eg = t & 63, og = t >> 6;
    int es = eg * 4, o0 = og * 8;
    float acc[4][8];
    #pragma unroll
    for (int j = 0; j < 4; j++)
        #pragma unroll
        for (int k = 0; k < 8; k++) acc[j][k] = 0.0f;

    for (int c = 0; c < 8; c++) {
        float4 wc = *(const float4*)&w8l[c * 256 + es];
        const float* wcf = (const float*)&wc;
        #pragma unroll
        for (int i = 0; i < 32; i++) {
            float4 xv = *(const float4*)&xjT[i * 256 + es];
            float4 wa = *(const float4*)&Wlds[c * 1024 + i * 32 + o0];
            float4 wb = *(const float4*)&Wlds[c * 1024 + i * 32 + o0 + 4];
            const float* xvf = (const float*)&xv;
            const float* waf = (const float*)&wa;
            const float* wbf = (const float*)&wb;
            #pragma unroll
            for (int j = 0; j < 4; j++) {
                float tv = xvf[j] * wcf[j];
                #pragma unroll
                for (int k = 0; k < 4; k++) acc[j][k] += tv * waf[k];
                #pragma unroll
                for (int k = 0; k < 4; k++) acc[j][4 + k] += tv * wbf[k];
            }
        }
    }

    #pragma unroll
    for (int j = 0; j < 4; j++) {
        if (einfo[es + j] >= 0) {
            float* yr = y_pad + (size_t)(base + es + j) * 32 + o0;
            *(float4*)yr       = *(const float4*)&acc[j][0];
            *(float4*)(yr + 4) = *(const float4*)&acc[j][4];
        }
    }
}

// ---------- gather finalize ----------

__global__ void gather_fin_kernel(const float* __restrict__ y_pad, const int* __restrict__ rank,
                                  const int* __restrict__ row_start, const int* __restrict__ csr,
                                  const float* __restrict__ x, const float* __restrict__ root,
                                  const float* __restrict__ b, float* __restrict__ out, int n) {
    int tid = blockIdx.x * blockDim.x + threadIdx.x;
    int nd = tid >> 5, o = tid & 31;
    if (nd >= n) return;
    int beg = row_start[nd], end = row_start[nd + 1];
    float acc = 0.0f;
    for (int idx = beg; idx < end; idx++) {
        int r = rank[csr[idx]];
        acc += y_pad[(size_t)r * 32 + o];
    }
    acc /= fmaxf((float)(end - beg), 1.0f);
    const float* __restrict__ xr = x + (size_t)nd * 32;
    float rsum = 0.0f;
    #pragma unroll
    for (int i = 0; i < 32; i++) rsum += xr[i] * root[i * 32 + o];
    float v = acc + rsum + b[o];
    out[(size_t)nd * 32 + o] = (v > 0.0f) ? v : expm1f(v);
}

// ---------- conv1 (cin=1) node-centric ----------

__global__ void conv1_node_kernel(const float* __restrict__ x, const int* __restrict__ ei,
                                  const float* __restrict__ pseudo,
                                  const int* __restrict__ row_start, const int* __restrict__ csr,
                                  const float* __restrict__ W, const float* __restrict__ root,
                                  const float* __restrict__ b, float* __restrict__ out, int n) {
    int tid = blockIdx.x * blockDim.x + threadIdx.x;
    int nd = tid >> 5, o = tid & 31;
    if (nd >= n) return;
    int beg = row_start[nd], end = row_start[nd + 1];
    float acc = 0.0f;
    for (int idx = beg; idx < end; idx++) {
        int e = csr[idx];
        int src = ei[e];
        float ps[3] = {pseudo[e * 3], pseudo[e * 3 + 1], pseudo[e * 3 + 2]};
        float w[8]; int flat[8];
        spline_basis(ps, w, flat);
        float s = 0.0f;
        #pragma unroll
        for (int c = 0; c < 8; c++) s += w[c] * W[flat[c] * 32 + o];
        acc += s * x[src];
    }
    float v = acc / fmaxf((float)(end - beg), 1.0f) + x[nd] * root[o] + b[o];
    out[(size_t)nd * 32 + o] = (v > 0.0f) ? v : expm1f(v);
}

// ---------- FC + log_softmax ----------

__global__ void fc_kernel(const float* __restrict__ h, const float* __restrict__ fw,
                          const float* __restrict__ fb, float* __restrict__ out, int B) {
    int b = blockIdx.x * blockDim.x + threadIdx.x;
    if (b >= B) return;
    float logit[10];
    #pragma unroll
    for (int j = 0; j < 10; j++) logit[j] = fb[j];
    const float* hb = h + (size_t)b * 256;
    for (int t = 0; t < 256; t++) {
        float hv = hb[t];
        const float* fwt = fw + t * 10;
        #pragma unroll
        for (int j = 0; j < 10; j++) logit[j] += hv * fwt[j];
    }
    float m = logit[0];
    #pragma unroll
    for (int j = 1; j < 10; j++) m = fmaxf(m, logit[j]);
    float s = 0.0f;
    #pragma unroll
    for (int j = 0; j < 10; j++) s += expf(logit[j] - m);
    float lse = logf(s) + m;
    #pragma unroll
    for (int j = 0; j < 10; j++) out[(size_t)b * 10 + j] = logit[j] - lse;
}

// ---------- launch ----------

static inline int cdiv(long long a, int b) { return (int)((a + b - 1) / b); }

extern "C" void kernel_launch(void* const* d_in, const int* in_sizes, int n_in,
                              void* d_out, int out_size, void* d_ws, size_t ws_size,
                              hipStream_t stream) {
    const int N0 = 131072, N1 = 65536, N2 = 32768, N3 = 16384, B8 = 16384;
    const int B = B8 / 8;

    const float* x      = (const float*)d_in[0];
    const int*   cl0    = (const int*)d_in[1];
    const int*   ei1    = (const int*)d_in[2];
    const float* ps1    = (const float*)d_in[3];
    const int*   cl1    = (const int*)d_in[4];
    const int*   ei2    = (const int*)d_in[5];
    const float* ps2    = (const float*)d_in[6];
    const int*   cl2    = (const int*)d_in[7];
    const int*   ei3    = (const int*)d_in[8];
    const float* ps3    = (const float*)d_in[9];
    const int*   cl3    = (const int*)d_in[10];
    const float* W1     = (const float*)d_in[11];
    const float* root1  = (const float*)d_in[12];
    const float* b1     = (const float*)d_in[13];
    const float* W2     = (const float*)d_in[14];
    const float* root2  = (const float*)d_in[15];
    const float* b2     = (const float*)d_in[16];
    const float* W3     = (const float*)d_in[17];
    const float* root3  = (const float*)d_in[18];
    const float* b3     = (const float*)d_in[19];
    const float* fc_w   = (const float*)d_in[20];
    const float* fc_b   = (const float*)d_in[21];
    float* out = (float*)d_out;

    const int E1 = in_sizes[2] / 2;
    const int E2 = in_sizes[5] / 2;
    const int E3 = in_sizes[8] / 2;
    const long long Etot = (long long)E1 + E2 + E3;
    const int Ntot = N1 + N2 + N3;

    const int grid2 = cdiv((long long)E2 + 64 * 255, 256);
    const int grid3 = cdiv((long long)E3 + 64 * 255, 256);
    const int pad2 = grid2 * 256, pad3 = grid3 * 256;
    const int padmax = pad2 > pad3 ? pad2 : pad3;

    // ---- workspace layout ----
    char* wp = (char*)d_ws;
    float* p0  = (float*)wp;               wp += (size_t)N1 * 4;
    float* h1  = (float*)wp;               wp += (size_t)N1 * 32 * 4;
    float* p1  = (float*)wp;               wp += (size_t)N2 * 32 * 4;
    float* h2  = (float*)wp;               wp += (size_t)N2 * 32 * 4;
    float* p2  = (float*)wp;               wp += (size_t)N3 * 32 * 4;
    float* h3  = (float*)wp;               wp += (size_t)N3 * 32 * 4;
    float* p3  = (float*)wp;               wp += (size_t)B8 * 32 * 4;
    // zeroed-together region: [cnt | cur | ccnt | ccur]
    int* cnt   = (int*)wp;                 wp += (size_t)Ntot * 4;
    int* cur   = (int*)wp;                 wp += (size_t)Ntot * 4;
    int* ccnt  = (int*)wp;                 wp += 128 * 4;
    int* ccur  = (int*)wp;                 wp += 128 * 4;
    size_t zero_bytes = (size_t)(wp - (char*)cnt);
    int* coff  = (int*)wp;                 wp += 128 * 4;
    int* row1  = (int*)wp;                 wp += (size_t)(N1 + 1) * 4;
    int* row2  = (int*)wp;                 wp += (size_t)(N2 + 1) * 4;
    int* row3  = (int*)wp;                 wp += (size_t)(N3 + 1) * 4;
    int* bsum  = (int*)wp;                 wp += 128 * 4;
    int* csr1  = (int*)wp;                 wp += (size_t)E1 * 4;
    int* csr2  = (int*)wp;                 wp += (size_t)E2 * 4;
    int* csr3  = (int*)wp;                 wp += (size_t)E3 * 4;
    int* rank2 = (int*)wp;                 wp += (size_t)E2 * 4;
    int* rank3 = (int*)wp;                 wp += (size_t)E3 * 4;
    int* cellid2 = (int*)wp;               wp += (size_t)E2 * 4;
    int* cellid3 = (int*)wp;               wp += (size_t)E3 * 4;
    int* eidx2 = (int*)wp;                 wp += (size_t)pad2 * 4;
    int* eidx3 = (int*)wp;                 wp += (size_t)pad3 * 4;
    float* y_pad = (float*)wp;             // padmax*32 floats; enc overlaid (lifetimes disjoint)
    unsigned* enc = (unsigned*)y_pad;

    const int T = 256;
    const int nb1 = N1 / 1024, nb12 = (N1 + N2) / 1024, nb = Ntot / 1024;

    // ========== indexing phase (input-only; all levels fused) ==========
    hipMemsetAsync(cnt, 0, zero_bytes, stream);
    hipMemsetAsync(eidx2, 0xFF, ((size_t)pad2 + pad3) * 4, stream);
    index_hist_all<<<cdiv(Etot, 1024), 1024, 0, stream>>>(
        ei1, ei2, ei3, ps2, ps3, cnt, ccnt, cellid2, cellid3, E1, E2, E3, N1, N2);
    scan_blocks_kernel<<<nb, 1024, 0, stream>>>(cnt, row1, row2, row3, bsum, N1, N2);
    scan_sums_kernel<<<1, 128, 0, stream>>>(bsum, ccnt, coff, nb, nb1, nb12);
    scan_add_kernel<<<nb, 1024, 0, stream>>>(row1, row2, row3, bsum, N1, N2, N3, E1, E2, E3);
    scatter_all<<<cdiv(Etot, 1024), 1024, 0, stream>>>(
        ei1, ei2, ei3, cur, row1, row2, row3, csr1, csr2, csr3,
        cellid2, cellid3, ccur, coff, eidx2, eidx3, rank2, rank3, E1, E2, E3, N1, N2);

    // ========== pipeline ==========
    // pool0: x [N0,1] -> p0 [N1]
    hipMemsetAsync(enc, 0, (size_t)N1 * 4, stream);
    pool_enc_kernel<<<cdiv(N0, T), T, 0, stream>>>(x, cl0, enc, N0, 1);
    decode_kernel<<<cdiv(N1, T), T, 0, stream>>>(enc, p0, N1);

    // conv1: p0 -> h1 [N1,32]
    conv1_node_kernel<<<cdiv((long long)N1 * 32, T), T, 0, stream>>>(
        p0, ei1, ps1, row1, csr1, W1, root1, b1, h1, N1);

    // pool1: h1 -> p1 [N2,32]
    hipMemsetAsync(enc, 0, (size_t)N2 * 32 * 4, stream);
    pool_enc_kernel<<<cdiv((long long)N1 * 32, T), T, 0, stream>>>(h1, cl1, enc, N1, 32);
    decode_kernel<<<cdiv((long long)N2 * 32, T), T, 0, stream>>>(enc, p1, N2 * 32);

    // conv2: p1 -> h2 [N2,32]
    conv_cell_kernel<<<grid2, 256, 0, stream>>>(p1, ei2, ps2, eidx2, W2, y_pad, E2);
    gather_fin_kernel<<<cdiv((long long)N2 * 32, T), T, 0, stream>>>(
        y_pad, rank2, row2, csr2, p1, root2, b2, h2, N2);

    // pool2: h2 -> p2 [N3,32]
    hipMemsetAsync(enc, 0, (size_t)N3 * 32 * 4, stream);
    pool_enc_kernel<<<cdiv((long long)N2 * 32, T), T, 0, stream>>>(h2, cl2, enc, N2, 32);
    decode_kernel<<<cdiv((long long)N3 * 32, T), T, 0, stream>>>(enc, p2, N3 * 32);

    // conv3: p2 -> h3 [N3,32]
    conv_cell_kernel<<<grid3, 256, 0, stream>>>(p2, ei3, ps3, eidx3, W3, y_pad, E3);
    gather_fin_kernel<<<cdiv((long long)N3 * 32, T), T, 0, stream>>>(
        y_pad, rank3, row3, csr3, p2, root3, b3, h3, N3);

    // pool3: h3 -> p3 [B8,32]
    hipMemsetAsync(enc, 0, (size_t)B8 * 32 * 4, stream);
    pool_enc_kernel<<<cdiv((long long)N3 * 32, T), T, 0, stream>>>(h3, cl3, enc, N3, 32);
    decode_kernel<<<cdiv((long long)B8 * 32, T), T, 0, stream>>>(enc, p3, B8 * 32);

    // FC + log_softmax
    fc_kernel<<<cdiv(B, T), T, 0, stream>>>(p3, fc_w, fc_b, out, B);
}

// Round 6
// 1058.440 us; speedup vs baseline: 4.9149x; 1.0614x over previous
//
#include <hip/hip_runtime.h>
#include <math.h>

#define KS 5
#define K3 125

// problem sizes (fixed)
#define N0c 131072
#define N1c 65536
#define N2c 32768
#define N3c 16384
#define B8c 16384

// ---------- helpers ----------

__device__ __forceinline__ void spline_k0f(const float ps[3], int k0[3], float f[3]) {
    #pragma unroll
    for (int d = 0; d < 3; d++) {
        float v = ps[d] * (float)(KS - 1);
        float kf = floorf(v);
        kf = fminf(fmaxf(kf, 0.0f), (float)(KS - 2));
        k0[d] = (int)kf;
        f[d] = v - kf;
    }
}

__device__ __forceinline__ void spline_basis(const float ps[3], float w[8], int flat[8]) {
    float f[3]; int k0[3];
    spline_k0f(ps, k0, f);
    #pragma unroll
    for (int c = 0; c < 8; c++) {
        float wc = 1.0f; int id[3];
        #pragma unroll
        for (int d = 0; d < 3; d++) {
            int b = (c >> d) & 1;
            wc *= b ? f[d] : (1.0f - f[d]);
            id[d] = k0[d] + b;
        }
        w[c] = wc;
        flat[c] = (id[0] * KS + id[1]) * KS + id[2];
    }
}

__device__ __forceinline__ int cell_of(const float* __restrict__ pseudo, int e) {
    float ps[3] = {pseudo[(size_t)e * 3], pseudo[(size_t)e * 3 + 1], pseudo[(size_t)e * 3 + 2]};
    int k0[3]; float f[3];
    spline_k0f(ps, k0, f);
    return (k0[0] * 4 + k0[1]) * 4 + k0[2];
}

// bin-space segment boundaries (bins = dst1,dst2,dst3,cl0,cl1,cl2,cl3)
// sizes: N1,N2,N3, N1,N2,N3,B8 ; cumulative:
#define SB1 65536
#define SB2 98304
#define SB3 114688
#define SB4 180224
#define SB5 212992
#define SB6 229376
#define SBT 245760

__device__ __forceinline__ int seg_of(int i) {
    return (i < SB1) ? 0 : (i < SB2) ? 1 : (i < SB3) ? 2 :
           (i < SB4) ? 3 : (i < SB5) ? 4 : (i < SB6) ? 5 : 6;
}

// ---------- fused indexing over edges (3 levels) + cluster arrays (4 levels) ----------
// items: [0,E1) e1 | [E1,E1+E2) e2 | [..,Etot) e3 | then cl0(N0), cl1(N1), cl2(N2), cl3(N3)
// cnt bins: dst1(N1) | dst2(N2) | dst3(N3) | cl0bins(N1) | cl1bins(N2) | cl2bins(N3) | cl3bins(B8)

__global__ void index_hist_all(const int* __restrict__ ei1, const int* __restrict__ ei2,
                               const int* __restrict__ ei3,
                               const float* __restrict__ ps2, const float* __restrict__ ps3,
                               const int* __restrict__ cl0, const int* __restrict__ cl1,
                               const int* __restrict__ cl2, const int* __restrict__ cl3,
                               int* __restrict__ cnt, int* __restrict__ ccnt,
                               int* __restrict__ cellid2, int* __restrict__ cellid3,
                               int E1, int E2, int E3) {
    __shared__ int lcnt[128];
    int t = threadIdx.x;
    if (t < 128) lcnt[t] = 0;
    __syncthreads();
    long long g = (long long)blockIdx.x * blockDim.x + t;
    long long Etot = (long long)E1 + E2 + E3;
    long long IT = Etot + N0c + N1c + N2c + N3c;
    if (g < IT) {
        if (g < E1) {
            int e = (int)g;
            atomicAdd(&cnt[ei1[E1 + e]], 1);
        } else if (g < (long long)E1 + E2) {
            int e = (int)(g - E1);
            atomicAdd(&cnt[SB1 + ei2[E2 + e]], 1);
            int c = cell_of(ps2, e);
            cellid2[e] = c;
            atomicAdd(&lcnt[c], 1);
        } else if (g < Etot) {
            int e = (int)(g - E1 - E2);
            atomicAdd(&cnt[SB2 + ei3[E3 + e]], 1);
            int c = cell_of(ps3, e);
            cellid3[e] = c;
            atomicAdd(&lcnt[64 + c], 1);
        } else if (g < Etot + N0c) {
            int i = (int)(g - Etot);
            atomicAdd(&cnt[SB3 + cl0[i]], 1);
        } else if (g < Etot + N0c + N1c) {
            int i = (int)(g - Etot - N0c);
            atomicAdd(&cnt[SB4 + cl1[i]], 1);
        } else if (g < Etot + N0c + N1c + N2c) {
            int i = (int)(g - Etot - N0c - N1c);
            atomicAdd(&cnt[SB5 + cl2[i]], 1);
        } else {
            int i = (int)(g - Etot - N0c - N1c - N2c);
            atomicAdd(&cnt[SB6 + cl3[i]], 1);
        }
    }
    __syncthreads();
    if (t < 128 && lcnt[t] > 0) atomicAdd(&ccnt[t], lcnt[t]);
}

// ---------- hierarchical segmented scan: cnt[SBT] -> rows[SBT+7] (7 segments, each +1 end slot) ----------

__global__ void scan_blocks_kernel(const int* __restrict__ cnt, int* __restrict__ rows,
                                   int* __restrict__ bsum) {
    __shared__ int sdata[1024];
    int t = threadIdx.x;
    int i = blockIdx.x * 1024 + t;
    int v = cnt[i];
    sdata[t] = v;
    __syncthreads();
    for (int off = 1; off < 1024; off <<= 1) {
        int add = (t >= off) ? sdata[t - off] : 0;
        __syncthreads();
        sdata[t] += add;
        __syncthreads();
    }
    rows[i + seg_of(i)] = sdata[t] - v;   // exclusive within block
    if (t == 1023) bsum[blockIdx.x] = sdata[1023];
}

// 240 block sums, segment resets at block indices 64,96,112,176,208,224
__global__ void scan_sums_kernel(int* __restrict__ bsum, const int* __restrict__ ccnt,
                                 int* __restrict__ coff, int nb) {
    __shared__ int sdata[256];
    __shared__ int sseg[256];
    int t = threadIdx.x;
    int v = (t < nb) ? bsum[t] : 0;
    int seg = (t < 64) ? 0 : (t < 96) ? 1 : (t < 112) ? 2 :
              (t < 176) ? 3 : (t < 208) ? 4 : (t < 224) ? 5 : 6;
    sdata[t] = v; sseg[t] = seg;
    __syncthreads();
    for (int off = 1; off < 256; off <<= 1) {
        int add = (t >= off && sseg[t - off] == seg) ? sdata[t - off] : 0;
        __syncthreads();
        sdata[t] += add;
        __syncthreads();
    }
    if (t < nb) bsum[t] = sdata[t] - v;   // segment-local exclusive base per block
    if (t == 0) {
        int acc = 0;
        for (int c = 0; c < 64; c++) { coff[c] = acc; acc += ((ccnt[c] + 255) / 256) * 256; }
    }
    if (t == 1) {
        int acc = 0;
        for (int c = 0; c < 64; c++) { coff[64 + c] = acc; acc += ((ccnt[64 + c] + 255) / 256) * 256; }
    }
}

__global__ void scan_add_kernel(int* __restrict__ rows, const int* __restrict__ bsum,
                                int E1, int E2, int E3) {
    int t = threadIdx.x;
    int i = blockIdx.x * 1024 + t;
    rows[i + seg_of(i)] += bsum[blockIdx.x];
    if (blockIdx.x == 0) {
        if (t == 0) rows[SB1 + 0] = E1;       // row1 end
        if (t == 1) rows[SB2 + 1] = E2;       // row2 end
        if (t == 2) rows[SB3 + 2] = E3;       // row3 end
        if (t == 3) rows[SB4 + 3] = N0c;      // crow0 end
        if (t == 4) rows[SB5 + 4] = N1c;      // crow1 end
        if (t == 5) rows[SB6 + 5] = N2c;      // crow2 end
        if (t == 6) rows[SBT + 6] = N3c;      // crow3 end
    }
}

// ---------- fused scatter: csr1, dpos2/3 (csr position per edge), cell buckets, cluster member lists ----------

__global__ void scatter_all(const int* __restrict__ ei1, const int* __restrict__ ei2,
                            const int* __restrict__ ei3,
                            const int* __restrict__ cl0, const int* __restrict__ cl1,
                            const int* __restrict__ cl2, const int* __restrict__ cl3,
                            int* __restrict__ cur, const int* __restrict__ rows,
                            int* __restrict__ csr1, int* __restrict__ dpos2, int* __restrict__ dpos3,
                            int* __restrict__ mem0, int* __restrict__ mem1,
                            int* __restrict__ mem2, int* __restrict__ mem3,
                            const int* __restrict__ cellid2, const int* __restrict__ cellid3,
                            int* __restrict__ ccur, const int* __restrict__ coff,
                            int* __restrict__ eidx2, int* __restrict__ eidx3,
                            int E1, int E2, int E3) {
    const int* row1  = rows;
    const int* row2  = rows + SB1 + 1;
    const int* row3  = rows + SB2 + 2;
    const int* crow0 = rows + SB3 + 3;
    const int* crow1 = rows + SB4 + 4;
    const int* crow2 = rows + SB5 + 5;
    const int* crow3 = rows + SB6 + 6;

    __shared__ int lcnt[128];
    __shared__ int lbase[128];
    int t = threadIdx.x;
    if (t < 128) lcnt[t] = 0;
    __syncthreads();
    long long g = (long long)blockIdx.x * blockDim.x + t;
    long long Etot = (long long)E1 + E2 + E3;
    long long IT = Etot + N0c + N1c + N2c + N3c;
    int lidx = -1, myrank = 0, e = -1, lvl = 0;
    if (g < IT) {
        if (g < E1) {
            e = (int)g;
            int dst = ei1[E1 + e];
            int pos = atomicAdd(&cur[dst], 1);
            csr1[row1[dst] + pos] = e;
        } else if (g < (long long)E1 + E2) {
            e = (int)(g - E1); lvl = 2;
            int dst = ei2[E2 + e];
            int pos = atomicAdd(&cur[SB1 + dst], 1);
            dpos2[e] = row2[dst] + pos;
            lidx = cellid2[e];
            myrank = atomicAdd(&lcnt[lidx], 1);
        } else if (g < Etot) {
            e = (int)(g - E1 - E2); lvl = 3;
            int dst = ei3[E3 + e];
            int pos = atomicAdd(&cur[SB2 + dst], 1);
            dpos3[e] = row3[dst] + pos;
            lidx = 64 + cellid3[e];
            myrank = atomicAdd(&lcnt[lidx], 1);
        } else if (g < Etot + N0c) {
            int i = (int)(g - Etot);
            int b = cl0[i];
            int pos = atomicAdd(&cur[SB3 + b], 1);
            mem0[crow0[b] + pos] = i;
        } else if (g < Etot + N0c + N1c) {
            int i = (int)(g - Etot - N0c);
            int b = cl1[i];
            int pos = atomicAdd(&cur[SB4 + b], 1);
            mem1[crow1[b] + pos] = i;
        } else if (g < Etot + N0c + N1c + N2c) {
            int i = (int)(g - Etot - N0c - N1c);
            int b = cl2[i];
            int pos = atomicAdd(&cur[SB5 + b], 1);
            mem2[crow2[b] + pos] = i;
        } else {
            int i = (int)(g - Etot - N0c - N1c - N2c);
            int b = cl3[i];
            int pos = atomicAdd(&cur[SB6 + b], 1);
            mem3[crow3[b] + pos] = i;
        }
    }
    __syncthreads();
    if (t < 128) lbase[t] = (lcnt[t] > 0) ? atomicAdd(&ccur[t], lcnt[t]) : 0;
    __syncthreads();
    if (lidx >= 0) {
        int slot = coff[lidx] + lbase[lidx] + myrank;
        if (lvl == 2) eidx2[slot] = e;
        else          eidx3[slot] = e;
    }
}

// ---------- pooling: segment-max gather via cluster CSR ----------

__global__ void pool1ch_kernel(const float* __restrict__ in, const int* __restrict__ crow,
                               const int* __restrict__ mem, float* __restrict__ out, int n) {
    int nd = blockIdx.x * blockDim.x + threadIdx.x;
    if (nd >= n) return;
    int beg = crow[nd], end = crow[nd + 1];
    float v = -INFINITY;
    for (int p = beg; p < end; p++) v = fmaxf(v, in[mem[p]]);
    out[nd] = (beg == end) ? 0.0f : v;
}

__global__ void pool32ch_kernel(const float* __restrict__ in, const int* __restrict__ crow,
                                const int* __restrict__ mem, float* __restrict__ out, int n) {
    int tid = blockIdx.x * blockDim.x + threadIdx.x;
    int nd = tid >> 5, o = tid & 31;
    if (nd >= n) return;
    int beg = crow[nd], end = crow[nd + 1];
    float v = -INFINITY;
    for (int p = beg; p < end; p++) v = fmaxf(v, in[(size_t)mem[p] * 32 + o]);
    out[(size_t)nd * 32 + o] = (beg == end) ? 0.0f : v;
}

// ---------- cell conv: W block in LDS, register-tiled edge-GEMM, CSR-ordered output ----------

__global__ __launch_bounds__(256, 2) void conv_cell_kernel(
        const float* __restrict__ x, const int* __restrict__ ei, const float* __restrict__ pseudo,
        const int* __restrict__ eidx_pad, const int* __restrict__ dpos,
        const float* __restrict__ W, float* __restrict__ y, int E) {
    __shared__ float Wlds[8 * 1024];   // [c][i][o]  32 KB
    __shared__ float xjT[32 * 256];    // [i][slot]  32 KB
    __shared__ float w8l[8 * 256];     // [c][slot]   8 KB
    __shared__ int einfo[256];
    __shared__ int dinfo[256];

    int t = threadIdx.x;
    int base = blockIdx.x * 256;
    int e = eidx_pad[base + t];
    einfo[t] = e;
    dinfo[t] = (e >= 0) ? dpos[e] : -1;
    __syncthreads();
    int e0 = einfo[0];
    if (e0 < 0) return;

    {
        float ps0[3] = {pseudo[(size_t)e0 * 3], pseudo[(size_t)e0 * 3 + 1], pseudo[(size_t)e0 * 3 + 2]};
        int k0[3]; float f0[3];
        spline_k0f(ps0, k0, f0);
        int c = t >> 5, ib = t & 31;
        int id0 = k0[0] + ((c >> 0) & 1);
        int id1 = k0[1] + ((c >> 1) & 1);
        int id2 = k0[2] + ((c >> 2) & 1);
        int flat = (id0 * KS + id1) * KS + id2;
        const float4* Wg = (const float4*)(W + (size_t)flat * 1024 + ib * 32);
        float4* Wd = (float4*)&Wlds[c * 1024 + ib * 32];
        #pragma unroll
        for (int j = 0; j < 8; j++) Wd[j] = Wg[j];
    }

    if (e >= 0) {
        int src = ei[e];
        const float4* xr = (const float4*)(x + (size_t)src * 32);
        float4 v[8];
        #pragma unroll
        for (int j = 0; j < 8; j++) v[j] = xr[j];
        const float* vf = (const float*)v;
        #pragma unroll
        for (int i = 0; i < 32; i++) xjT[i * 256 + t] = vf[i];
        float ps[3] = {pseudo[(size_t)e * 3], pseudo[(size_t)e * 3 + 1], pseudo[(size_t)e * 3 + 2]};
        float w[8]; int flat[8];
        spline_basis(ps, w, flat);
        #pragma unroll
        for (int c = 0; c < 8; c++) w8l[c * 256 + t] = w[c];
    } else {
        #pragma unroll
        for (int i = 0; i < 32; i++) xjT[i * 256 + t] = 0.0f;
        #pragma unroll
        for (int c = 0; c < 8; c++) w8l[c * 256 + t] = 0.0f;
    }
    __syncthreads();

    int eg = t & 63, og = t >> 6;
    int es = eg * 4, o0 = og * 8;

    // per-edge corner weights in registers [c][j]
    float wreg[8][4];
    #pragma unroll
    for (int c = 0; c < 8; c++) {
        float4 w4 = *(const float4*)&w8l[c * 256 + es];
        wreg[c][0] = w4.x; wreg[c][1] = w4.y; wreg[c][2] = w4.z; wreg[c][3] = w4.w;
    }

    float acc[4][8];
    #pragma unroll
    for (int j = 0; j < 4; j++)
        #pragma unroll
        for (int k = 0; k < 8; k++) acc[j][k] = 0.0f;

    // i outer (xjT read once per i), c inner
    #pragma unroll 2
    for (int i = 0; i < 32; i++) {
        float4 xv = *(const float4*)&xjT[i * 256 + es];
        const float* xvf = (const float*)&xv;
        #pragma unroll
        for (int c = 0; c < 8; c++) {
            float4 wa = *(const float4*)&Wlds[c * 1024 + i * 32 + o0];
            float4 wb = *(const float4*)&Wlds[c * 1024 + i * 32 + o0 + 4];
            const float* waf = (const float*)&wa;
            const float* wbf = (const float*)&wb;
            #pragma unroll
            for (int j = 0; j < 4; j++) {
                float tv = xvf[j] * wreg[c][j];
                #pragma unroll
                for (int k = 0; k < 4; k++) acc[j][k] += tv * waf[k];
                #pragma unroll
                for (int k = 0; k < 4; k++) acc[j][4 + k] += tv * wbf[k];
            }
        }
    }

    // write per-edge partials at CSR position (full 128B rows, aligned)
    #pragma unroll
    for (int j = 0; j < 4; j++) {
        int d = dinfo[es + j];
        if (d >= 0) {
            float* yr = y + (size_t)d * 32 + o0;
            *(float4*)yr       = *(const float4*)&acc[j][0];
            *(float4*)(yr + 4) = *(const float4*)&acc[j][4];
        }
    }
}

// ---------- gather finalize: streaming row-range sum + mean + root + bias + ELU ----------

__global__ void gather_fin_kernel(const float* __restrict__ y, const int* __restrict__ row_start,
                                  const float* __restrict__ x, const float* __restrict__ root,
                                  const float* __restrict__ b, float* __restrict__ out, int n) {
    int tid = blockIdx.x * blockDim.x + threadIdx.x;
    int nd = tid >> 5, o = tid & 31;
    if (nd >= n) return;
    int beg = row_start[nd], end = row_start[nd + 1];
    float acc = 0.0f;
    for (int p = beg; p < end; p++) acc += y[(size_t)p * 32 + o];
    acc /= fmaxf((float)(end - beg), 1.0f);
    const float* __restrict__ xr = x + (size_t)nd * 32;
    float rsum = 0.0f;
    #pragma unroll
    for (int i = 0; i < 32; i++) rsum += xr[i] * root[i * 32 + o];
    float v = acc + rsum + b[o];
    out[(size_t)nd * 32 + o] = (v > 0.0f) ? v : expm1f(v);
}

// ---------- conv1 (cin=1) node-centric ----------

__global__ void conv1_node_kernel(const float* __restrict__ x, const int* __restrict__ ei,
                                  const float* __restrict__ pseudo,
                                  const int* __restrict__ row_start, const int* __restrict__ csr,
                                  const float* __restrict__ W, const float* __restrict__ root,
                                  const float* __restrict__ b, float* __restrict__ out, int n) {
    int tid = blockIdx.x * blockDim.x + threadIdx.x;
    int nd = tid >> 5, o = tid & 31;
    if (nd >= n) return;
    int beg = row_start[nd], end = row_start[nd + 1];
    float acc = 0.0f;
    for (int idx = beg; idx < end; idx++) {
        int e = csr[idx];
        int src = ei[e];
        float ps[3] = {pseudo[e * 3], pseudo[e * 3 + 1], pseudo[e * 3 + 2]};
        float w[8]; int flat[8];
        spline_basis(ps, w, flat);
        float s = 0.0f;
        #pragma unroll
        for (int c = 0; c < 8; c++) s += w[c] * W[flat[c] * 32 + o];
        acc += s * x[src];
    }
    float v = acc / fmaxf((float)(end - beg), 1.0f) + x[nd] * root[o] + b[o];
    out[(size_t)nd * 32 + o] = (v > 0.0f) ? v : expm1f(v);
}

// ---------- FC + log_softmax ----------

__global__ void fc_kernel(const float* __restrict__ h, const float* __restrict__ fw,
                          const float* __restrict__ fb, float* __restrict__ out, int B) {
    int b = blockIdx.x * blockDim.x + threadIdx.x;
    if (b >= B) return;
    float logit[10];
    #pragma unroll
    for (int j = 0; j < 10; j++) logit[j] = fb[j];
    const float* hb = h + (size_t)b * 256;
    for (int t = 0; t < 256; t++) {
        float hv = hb[t];
        const float* fwt = fw + t * 10;
        #pragma unroll
        for (int j = 0; j < 10; j++) logit[j] += hv * fwt[j];
    }
    float m = logit[0];
    #pragma unroll
    for (int j = 1; j < 10; j++) m = fmaxf(m, logit[j]);
    float s = 0.0f;
    #pragma unroll
    for (int j = 0; j < 10; j++) s += expf(logit[j] - m);
    float lse = logf(s) + m;
    #pragma unroll
    for (int j = 0; j < 10; j++) out[(size_t)b * 10 + j] = logit[j] - lse;
}

// ---------- launch ----------

static inline int cdiv(long long a, int b) { return (int)((a + b - 1) / b); }

extern "C" void kernel_launch(void* const* d_in, const int* in_sizes, int n_in,
                              void* d_out, int out_size, void* d_ws, size_t ws_size,
                              hipStream_t stream) {
    const int N1 = N1c, N2 = N2c, N3 = N3c, B8 = B8c;
    const int B = B8 / 8;

    const float* x      = (const float*)d_in[0];
    const int*   cl0    = (const int*)d_in[1];
    const int*   ei1    = (const int*)d_in[2];
    const float* ps1    = (const float*)d_in[3];
    const int*   cl1    = (const int*)d_in[4];
    const int*   ei2    = (const int*)d_in[5];
    const float* ps2    = (const float*)d_in[6];
    const int*   cl2    = (const int*)d_in[7];
    const int*   ei3    = (const int*)d_in[8];
    const float* ps3    = (const float*)d_in[9];
    const int*   cl3    = (const int*)d_in[10];
    const float* W1     = (const float*)d_in[11];
    const float* root1  = (const float*)d_in[12];
    const float* b1     = (const float*)d_in[13];
    const float* W2     = (const float*)d_in[14];
    const float* root2  = (const float*)d_in[15];
    const float* b2     = (const float*)d_in[16];
    const float* W3     = (const float*)d_in[17];
    const float* root3  = (const float*)d_in[18];
    const float* b3     = (const float*)d_in[19];
    const float* fc_w   = (const float*)d_in[20];
    const float* fc_b   = (const float*)d_in[21];
    float* out = (float*)d_out;

    const int E1 = in_sizes[2] / 2;
    const int E2 = in_sizes[5] / 2;
    const int E3 = in_sizes[8] / 2;
    const long long Etot = (long long)E1 + E2 + E3;
    const long long IT = Etot + N0c + N1c + N2c + N3c;

    const int grid2 = cdiv((long long)E2 + 64 * 255, 256);
    const int grid3 = cdiv((long long)E3 + 64 * 255, 256);
    const int pad2 = grid2 * 256, pad3 = grid3 * 256;
    const int ymax = (E2 > E3 ? E2 : E3);

    // ---- workspace layout ----
    char* wp = (char*)d_ws;
    float* p0  = (float*)wp;               wp += (size_t)N1 * 4;
    float* h1  = (float*)wp;               wp += (size_t)N1 * 32 * 4;
    float* p1  = (float*)wp;               wp += (size_t)N2 * 32 * 4;
    float* h2  = (float*)wp;               wp += (size_t)N2 * 32 * 4;
    float* p2  = (float*)wp;               wp += (size_t)N3 * 32 * 4;
    float* h3  = (float*)wp;               wp += (size_t)N3 * 32 * 4;
    float* p3  = (float*)wp;               wp += (size_t)B8 * 32 * 4;
    // zeroed-together region: [cnt | cur | ccnt | ccur]
    int* cnt   = (int*)wp;                 wp += (size_t)SBT * 4;
    int* cur   = (int*)wp;                 wp += (size_t)SBT * 4;
    int* ccnt  = (int*)wp;                 wp += 128 * 4;
    int* ccur  = (int*)wp;                 wp += 128 * 4;
    size_t zero_bytes = (size_t)(wp - (char*)cnt);
    int* coff  = (int*)wp;                 wp += 128 * 4;
    int* rows  = (int*)wp;                 wp += (size_t)(SBT + 7) * 4;
    int* bsum  = (int*)wp;                 wp += 256 * 4;
    int* csr1  = (int*)wp;                 wp += (size_t)E1 * 4;
    int* dpos2 = (int*)wp;                 wp += (size_t)E2 * 4;
    int* dpos3 = (int*)wp;                 wp += (size_t)E3 * 4;
    int* cellid2 = (int*)wp;               wp += (size_t)E2 * 4;
    int* cellid3 = (int*)wp;               wp += (size_t)E3 * 4;
    int* mem0  = (int*)wp;                 wp += (size_t)N0c * 4;
    int* mem1  = (int*)wp;                 wp += (size_t)N1c * 4;
    int* mem2  = (int*)wp;                 wp += (size_t)N2c * 4;
    int* mem3  = (int*)wp;                 wp += (size_t)N3c * 4;
    int* eidx2 = (int*)wp;                 wp += (size_t)pad2 * 4;
    int* eidx3 = (int*)wp;                 wp += (size_t)pad3 * 4;
    float* y   = (float*)wp;               // ymax*32 floats

    // rows sub-pointers (each segment has size+1 entries)
    int* row1  = rows;
    int* row2  = rows + SB1 + 1;
    int* row3  = rows + SB2 + 2;
    int* crow0 = rows + SB3 + 3;
    int* crow1 = rows + SB4 + 4;
    int* crow2 = rows + SB5 + 5;
    int* crow3 = rows + SB6 + 6;

    const int T = 256;
    const int nb = SBT / 1024;   // 240

    // ========== indexing phase (input-only; edges + clusters fused) ==========
    hipMemsetAsync(cnt, 0, zero_bytes, stream);
    hipMemsetAsync(eidx2, 0xFF, ((size_t)pad2 + pad3) * 4, stream);
    index_hist_all<<<cdiv(IT, 1024), 1024, 0, stream>>>(
        ei1, ei2, ei3, ps2, ps3, cl0, cl1, cl2, cl3, cnt, ccnt, cellid2, cellid3, E1, E2, E3);
    scan_blocks_kernel<<<nb, 1024, 0, stream>>>(cnt, rows, bsum);
    scan_sums_kernel<<<1, 256, 0, stream>>>(bsum, ccnt, coff, nb);
    scan_add_kernel<<<nb, 1024, 0, stream>>>(rows, bsum, E1, E2, E3);
    scatter_all<<<cdiv(IT, 1024), 1024, 0, stream>>>(
        ei1, ei2, ei3, cl0, cl1, cl2, cl3, cur, rows,
        csr1, dpos2, dpos3, mem0, mem1, mem2, mem3,
        cellid2, cellid3, ccur, coff, eidx2, eidx3, E1, E2, E3);

    // ========== pipeline ==========
    // pool0: x [N0,1] -> p0 [N1]
    pool1ch_kernel<<<cdiv(N1, T), T, 0, stream>>>(x, crow0, mem0, p0, N1);

    // conv1: p0 -> h1 [N1,32]
    conv1_node_kernel<<<cdiv((long long)N1 * 32, T), T, 0, stream>>>(
        p0, ei1, ps1, row1, csr1, W1, root1, b1, h1, N1);

    // pool1: h1 -> p1 [N2,32]
    pool32ch_kernel<<<cdiv((long long)N2 * 32, T), T, 0, stream>>>(h1, crow1, mem1, p1, N2);

    // conv2: p1 -> h2 [N2,32]
    conv_cell_kernel<<<grid2, 256, 0, stream>>>(p1, ei2, ps2, eidx2, dpos2, W2, y, E2);
    gather_fin_kernel<<<cdiv((long long)N2 * 32, T), T, 0, stream>>>(
        y, row2, p1, root2, b2, h2, N2);

    // pool2: h2 -> p2 [N3,32]
    pool32ch_kernel<<<cdiv((long long)N3 * 32, T), T, 0, stream>>>(h2, crow2, mem2, p2, N3);

    // conv3: p2 -> h3 [N3,32]
    conv_cell_kernel<<<grid3, 256, 0, stream>>>(p2, ei3, ps3, eidx3, dpos3, W3, y, E3);
    gather_fin_kernel<<<cdiv((long long)N3 * 32, T), T, 0, stream>>>(
        y, row3, p2, root3, b3, h3, N3);

    // pool3: h3 -> p3 [B8,32]
    pool32ch_kernel<<<cdiv((long long)B8 * 32, T), T, 0, stream>>>(h3, crow3, mem3, p3, B8);

    // FC + log_softmax
    fc_kernel<<<cdiv(B, T), T, 0, stream>>>(p3, fc_w, fc_b, out, B);
}

// Round 7
// 836.430 us; speedup vs baseline: 6.2195x; 1.2654x over previous
//
#include <hip/hip_runtime.h>
#include <math.h>

#define KS 5
#define K3 125

// problem sizes (fixed)
#define N0c 131072
#define N1c 65536
#define N2c 32768
#define N3c 16384
#define B8c 16384

typedef _Float16 hf8_t __attribute__((ext_vector_type(8)));
typedef float f32x4_t __attribute__((ext_vector_type(4)));

// ---------- helpers ----------

__device__ __forceinline__ void spline_k0f(const float ps[3], int k0[3], float f[3]) {
    #pragma unroll
    for (int d = 0; d < 3; d++) {
        float v = ps[d] * (float)(KS - 1);
        float kf = floorf(v);
        kf = fminf(fmaxf(kf, 0.0f), (float)(KS - 2));
        k0[d] = (int)kf;
        f[d] = v - kf;
    }
}

__device__ __forceinline__ void spline_basis(const float ps[3], float w[8], int flat[8]) {
    float f[3]; int k0[3];
    spline_k0f(ps, k0, f);
    #pragma unroll
    for (int c = 0; c < 8; c++) {
        float wc = 1.0f; int id[3];
        #pragma unroll
        for (int d = 0; d < 3; d++) {
            int b = (c >> d) & 1;
            wc *= b ? f[d] : (1.0f - f[d]);
            id[d] = k0[d] + b;
        }
        w[c] = wc;
        flat[c] = (id[0] * KS + id[1]) * KS + id[2];
    }
}

__device__ __forceinline__ int cell_of(const float* __restrict__ pseudo, int e) {
    float ps[3] = {pseudo[(size_t)e * 3], pseudo[(size_t)e * 3 + 1], pseudo[(size_t)e * 3 + 2]};
    int k0[3]; float f[3];
    spline_k0f(ps, k0, f);
    return (k0[0] * 4 + k0[1]) * 4 + k0[2];
}

// bin-space segment boundaries (bins = dst1,dst2,dst3,cl0,cl1,cl2,cl3)
#define SB1 65536
#define SB2 98304
#define SB3 114688
#define SB4 180224
#define SB5 212992
#define SB6 229376
#define SBT 245760

__device__ __forceinline__ int seg_of(int i) {
    return (i < SB1) ? 0 : (i < SB2) ? 1 : (i < SB3) ? 2 :
           (i < SB4) ? 3 : (i < SB5) ? 4 : (i < SB6) ? 5 : 6;
}

// ---------- W transpose: [bin][i][o] -> [bin][o][i] (for conflict-free LDS staging) ----------

__global__ void wtrans_kernel(const float* __restrict__ W2, const float* __restrict__ W3,
                              float* __restrict__ WT2, float* __restrict__ WT3) {
    int tid = blockIdx.x * blockDim.x + threadIdx.x;
    const int total = K3 * 1024;
    if (tid >= total) return;
    int bin = tid >> 10, r = tid & 1023, i = r >> 5, o = r & 31;
    WT2[bin * 1024 + o * 32 + i] = W2[tid];
    WT3[bin * 1024 + o * 32 + i] = W3[tid];
}

// ---------- fused indexing ----------

__global__ void index_hist_all(const int* __restrict__ ei1, const int* __restrict__ ei2,
                               const int* __restrict__ ei3,
                               const float* __restrict__ ps2, const float* __restrict__ ps3,
                               const int* __restrict__ cl0, const int* __restrict__ cl1,
                               const int* __restrict__ cl2, const int* __restrict__ cl3,
                               int* __restrict__ cnt, int* __restrict__ ccnt,
                               int* __restrict__ cellid2, int* __restrict__ cellid3,
                               int E1, int E2, int E3) {
    __shared__ int lcnt[128];
    int t = threadIdx.x;
    if (t < 128) lcnt[t] = 0;
    __syncthreads();
    long long g = (long long)blockIdx.x * blockDim.x + t;
    long long Etot = (long long)E1 + E2 + E3;
    long long IT = Etot + N0c + N1c + N2c + N3c;
    if (g < IT) {
        if (g < E1) {
            int e = (int)g;
            atomicAdd(&cnt[ei1[E1 + e]], 1);
        } else if (g < (long long)E1 + E2) {
            int e = (int)(g - E1);
            atomicAdd(&cnt[SB1 + ei2[E2 + e]], 1);
            int c = cell_of(ps2, e);
            cellid2[e] = c;
            atomicAdd(&lcnt[c], 1);
        } else if (g < Etot) {
            int e = (int)(g - E1 - E2);
            atomicAdd(&cnt[SB2 + ei3[E3 + e]], 1);
            int c = cell_of(ps3, e);
            cellid3[e] = c;
            atomicAdd(&lcnt[64 + c], 1);
        } else if (g < Etot + N0c) {
            int i = (int)(g - Etot);
            atomicAdd(&cnt[SB3 + cl0[i]], 1);
        } else if (g < Etot + N0c + N1c) {
            int i = (int)(g - Etot - N0c);
            atomicAdd(&cnt[SB4 + cl1[i]], 1);
        } else if (g < Etot + N0c + N1c + N2c) {
            int i = (int)(g - Etot - N0c - N1c);
            atomicAdd(&cnt[SB5 + cl2[i]], 1);
        } else {
            int i = (int)(g - Etot - N0c - N1c - N2c);
            atomicAdd(&cnt[SB6 + cl3[i]], 1);
        }
    }
    __syncthreads();
    if (t < 128 && lcnt[t] > 0) atomicAdd(&ccnt[t], lcnt[t]);
}

// ---------- hierarchical segmented scan ----------

__global__ void scan_blocks_kernel(const int* __restrict__ cnt, int* __restrict__ rows,
                                   int* __restrict__ bsum) {
    __shared__ int sdata[1024];
    int t = threadIdx.x;
    int i = blockIdx.x * 1024 + t;
    int v = cnt[i];
    sdata[t] = v;
    __syncthreads();
    for (int off = 1; off < 1024; off <<= 1) {
        int add = (t >= off) ? sdata[t - off] : 0;
        __syncthreads();
        sdata[t] += add;
        __syncthreads();
    }
    rows[i + seg_of(i)] = sdata[t] - v;
    if (t == 1023) bsum[blockIdx.x] = sdata[1023];
}

__global__ void scan_sums_kernel(int* __restrict__ bsum, const int* __restrict__ ccnt,
                                 int* __restrict__ coff, int nb) {
    __shared__ int sdata[256];
    __shared__ int sseg[256];
    int t = threadIdx.x;
    int v = (t < nb) ? bsum[t] : 0;
    int seg = (t < 64) ? 0 : (t < 96) ? 1 : (t < 112) ? 2 :
              (t < 176) ? 3 : (t < 208) ? 4 : (t < 224) ? 5 : 6;
    sdata[t] = v; sseg[t] = seg;
    __syncthreads();
    for (int off = 1; off < 256; off <<= 1) {
        int add = (t >= off && sseg[t - off] == seg) ? sdata[t - off] : 0;
        __syncthreads();
        sdata[t] += add;
        __syncthreads();
    }
    if (t < nb) bsum[t] = sdata[t] - v;
    if (t == 0) {
        int acc = 0;
        for (int c = 0; c < 64; c++) { coff[c] = acc; acc += ((ccnt[c] + 255) / 256) * 256; }
    }
    if (t == 1) {
        int acc = 0;
        for (int c = 0; c < 64; c++) { coff[64 + c] = acc; acc += ((ccnt[64 + c] + 255) / 256) * 256; }
    }
}

__global__ void scan_add_kernel(int* __restrict__ rows, const int* __restrict__ bsum,
                                int E1, int E2, int E3) {
    int t = threadIdx.x;
    int i = blockIdx.x * 1024 + t;
    rows[i + seg_of(i)] += bsum[blockIdx.x];
    if (blockIdx.x == 0) {
        if (t == 0) rows[SB1 + 0] = E1;
        if (t == 1) rows[SB2 + 1] = E2;
        if (t == 2) rows[SB3 + 2] = E3;
        if (t == 3) rows[SB4 + 3] = N0c;
        if (t == 4) rows[SB5 + 4] = N1c;
        if (t == 5) rows[SB6 + 5] = N2c;
        if (t == 6) rows[SBT + 6] = N3c;
    }
}

// ---------- fused scatter ----------

__global__ void scatter_all(const int* __restrict__ ei1, const int* __restrict__ ei2,
                            const int* __restrict__ ei3,
                            const int* __restrict__ cl0, const int* __restrict__ cl1,
                            const int* __restrict__ cl2, const int* __restrict__ cl3,
                            int* __restrict__ cur, const int* __restrict__ rows,
                            int* __restrict__ csr1, int* __restrict__ dpos2, int* __restrict__ dpos3,
                            int* __restrict__ mem0, int* __restrict__ mem1,
                            int* __restrict__ mem2, int* __restrict__ mem3,
                            const int* __restrict__ cellid2, const int* __restrict__ cellid3,
                            int* __restrict__ ccur, const int* __restrict__ coff,
                            int* __restrict__ eidx2, int* __restrict__ eidx3,
                            int E1, int E2, int E3) {
    const int* row1  = rows;
    const int* row2  = rows + SB1 + 1;
    const int* row3  = rows + SB2 + 2;
    const int* crow0 = rows + SB3 + 3;
    const int* crow1 = rows + SB4 + 4;
    const int* crow2 = rows + SB5 + 5;
    const int* crow3 = rows + SB6 + 6;

    __shared__ int lcnt[128];
    __shared__ int lbase[128];
    int t = threadIdx.x;
    if (t < 128) lcnt[t] = 0;
    __syncthreads();
    long long g = (long long)blockIdx.x * blockDim.x + t;
    long long Etot = (long long)E1 + E2 + E3;
    long long IT = Etot + N0c + N1c + N2c + N3c;
    int lidx = -1, myrank = 0, e = -1, lvl = 0;
    if (g < IT) {
        if (g < E1) {
            e = (int)g;
            int dst = ei1[E1 + e];
            int pos = atomicAdd(&cur[dst], 1);
            csr1[row1[dst] + pos] = e;
        } else if (g < (long long)E1 + E2) {
            e = (int)(g - E1); lvl = 2;
            int dst = ei2[E2 + e];
            int pos = atomicAdd(&cur[SB1 + dst], 1);
            dpos2[e] = row2[dst] + pos;
            lidx = cellid2[e];
            myrank = atomicAdd(&lcnt[lidx], 1);
        } else if (g < Etot) {
            e = (int)(g - E1 - E2); lvl = 3;
            int dst = ei3[E3 + e];
            int pos = atomicAdd(&cur[SB2 + dst], 1);
            dpos3[e] = row3[dst] + pos;
            lidx = 64 + cellid3[e];
            myrank = atomicAdd(&lcnt[lidx], 1);
        } else if (g < Etot + N0c) {
            int i = (int)(g - Etot);
            int b = cl0[i];
            int pos = atomicAdd(&cur[SB3 + b], 1);
            mem0[crow0[b] + pos] = i;
        } else if (g < Etot + N0c + N1c) {
            int i = (int)(g - Etot - N0c);
            int b = cl1[i];
            int pos = atomicAdd(&cur[SB4 + b], 1);
            mem1[crow1[b] + pos] = i;
        } else if (g < Etot + N0c + N1c + N2c) {
            int i = (int)(g - Etot - N0c - N1c);
            int b = cl2[i];
            int pos = atomicAdd(&cur[SB5 + b], 1);
            mem2[crow2[b] + pos] = i;
        } else {
            int i = (int)(g - Etot - N0c - N1c - N2c);
            int b = cl3[i];
            int pos = atomicAdd(&cur[SB6 + b], 1);
            mem3[crow3[b] + pos] = i;
        }
    }
    __syncthreads();
    if (t < 128) lbase[t] = (lcnt[t] > 0) ? atomicAdd(&ccur[t], lcnt[t]) : 0;
    __syncthreads();
    if (lidx >= 0) {
        int slot = coff[lidx] + lbase[lidx] + myrank;
        if (lvl == 2) eidx2[slot] = e;
        else          eidx3[slot] = e;
    }
}

// ---------- pooling: segment-max gather via cluster CSR ----------

__global__ void pool1ch_kernel(const float* __restrict__ in, const int* __restrict__ crow,
                               const int* __restrict__ mem, float* __restrict__ out, int n) {
    int nd = blockIdx.x * blockDim.x + threadIdx.x;
    if (nd >= n) return;
    int beg = crow[nd], end = crow[nd + 1];
    float v = -INFINITY;
    for (int p = beg; p < end; p++) v = fmaxf(v, in[mem[p]]);
    out[nd] = (beg == end) ? 0.0f : v;
}

__global__ void pool32ch_kernel(const float* __restrict__ in, const int* __restrict__ crow,
                                const int* __restrict__ mem, float* __restrict__ out, int n) {
    int tid = blockIdx.x * blockDim.x + threadIdx.x;
    int nd = tid >> 5, o = tid & 31;
    if (nd >= n) return;
    int beg = crow[nd], end = crow[nd + 1];
    float v = -INFINITY;
    for (int p = beg; p < end; p++) v = fmaxf(v, in[(size_t)mem[p] * 32 + o]);
    out[(size_t)nd * 32 + o] = (beg == end) ? 0.0f : v;
}

// ---------- cell conv via MFMA fp16: per-block 256x32x256 GEMM ----------
// block = 256 thr (4 waves), TILE = 256 edges (one cell). Per wave: 64 edges x 32 outs.
// A[e][k], k=(c,i): A = w_ec * x_ei (fp16). B[k][o] = Wcell[c][i][o] (fp16, staged o-major).
// mfma_f32_16x16x32_f16: A-frag lane: m=lane&15, k=quad*8+j; B-frag: n=lane&15, k=quad*8+j;
// D: row(m)=quad*4+reg, col(n)=lane&15.

__global__ __launch_bounds__(256, 4) void conv_cell_mfma(
        const float* __restrict__ x, const int* __restrict__ ei, const float* __restrict__ pseudo,
        const int* __restrict__ eidx_pad, const int* __restrict__ dpos,
        const float* __restrict__ WT, _Float16* __restrict__ y, int E) {
    __shared__ _Float16 Wl[8 * 1024];   // [c][o][i]  16 KB
    __shared__ _Float16 xh[256 * 32];   // [e][i]     16 KB
    __shared__ _Float16 wc8[8 * 256];   // [c][e]      4 KB
    __shared__ int dinfo[256];

    int t = threadIdx.x;
    int base = blockIdx.x * 256;
    int e = eidx_pad[base + t];
    dinfo[t] = (e >= 0) ? dpos[e] : -1;
    int e0 = eidx_pad[base];
    if (e0 < 0) return;   // fully-padded trailing block (uniform)

    // stage W for this cell's 8 corners: thread (c = t>>5, o = t&31) copies one o-row
    {
        float ps0[3] = {pseudo[(size_t)e0 * 3], pseudo[(size_t)e0 * 3 + 1], pseudo[(size_t)e0 * 3 + 2]};
        int k0[3]; float f0[3];
        spline_k0f(ps0, k0, f0);
        int c = t >> 5, o = t & 31;
        int id0 = k0[0] + ((c >> 0) & 1);
        int id1 = k0[1] + ((c >> 1) & 1);
        int id2 = k0[2] + ((c >> 2) & 1);
        int flat = (id0 * KS + id1) * KS + id2;
        const float4* src4 = (const float4*)(WT + (size_t)flat * 1024 + o * 32);
        _Float16* dst = &Wl[c * 1024 + o * 32];
        #pragma unroll
        for (int j = 0; j < 8; j++) {
            float4 v = src4[j];
            dst[j * 4 + 0] = (_Float16)v.x;
            dst[j * 4 + 1] = (_Float16)v.y;
            dst[j * 4 + 2] = (_Float16)v.z;
            dst[j * 4 + 3] = (_Float16)v.w;
        }
    }

    // stage x (fp16) + per-edge corner weights
    if (e >= 0) {
        int src = ei[e];
        const float4* xr = (const float4*)(x + (size_t)src * 32);
        _Float16* xd = &xh[t * 32];
        #pragma unroll
        for (int j = 0; j < 8; j++) {
            float4 v = xr[j];
            xd[j * 4 + 0] = (_Float16)v.x;
            xd[j * 4 + 1] = (_Float16)v.y;
            xd[j * 4 + 2] = (_Float16)v.z;
            xd[j * 4 + 3] = (_Float16)v.w;
        }
        float ps[3] = {pseudo[(size_t)e * 3], pseudo[(size_t)e * 3 + 1], pseudo[(size_t)e * 3 + 2]};
        float w[8]; int flat[8];
        spline_basis(ps, w, flat);
        #pragma unroll
        for (int c = 0; c < 8; c++) wc8[c * 256 + t] = (_Float16)w[c];
    } else {
        _Float16* xd = &xh[t * 32];
        #pragma unroll
        for (int j = 0; j < 32; j++) xd[j] = (_Float16)0.0f;
        #pragma unroll
        for (int c = 0; c < 8; c++) wc8[c * 256 + t] = (_Float16)0.0f;
    }
    __syncthreads();

    int wv = t >> 6, lane = t & 63;
    int quad = lane >> 4, mrow = lane & 15;

    // x frags (independent of corner): one b128 per edge-tile
    hf8_t xf[4];
    #pragma unroll
    for (int mt = 0; mt < 4; mt++) {
        int em = wv * 64 + mt * 16 + mrow;
        xf[mt] = *(const hf8_t*)&xh[em * 32 + quad * 8];
    }

    f32x4_t acc[4][2];
    #pragma unroll
    for (int mt = 0; mt < 4; mt++) {
        acc[mt][0] = (f32x4_t)0.0f;
        acc[mt][1] = (f32x4_t)0.0f;
    }

    #pragma unroll
    for (int c = 0; c < 8; c++) {
        hf8_t b0 = *(const hf8_t*)&Wl[c * 1024 + mrow * 32 + quad * 8];
        hf8_t b1 = *(const hf8_t*)&Wl[c * 1024 + (16 + mrow) * 32 + quad * 8];
        #pragma unroll
        for (int mt = 0; mt < 4; mt++) {
            int em = wv * 64 + mt * 16 + mrow;
            _Float16 wcv = wc8[c * 256 + em];
            hf8_t af = xf[mt] * wcv;
            acc[mt][0] = __builtin_amdgcn_mfma_f32_16x16x32_f16(af, b0, acc[mt][0], 0, 0, 0);
            acc[mt][1] = __builtin_amdgcn_mfma_f32_16x16x32_f16(af, b1, acc[mt][1], 0, 0, 0);
        }
    }

    // epilogue: D row m = quad*4+reg (edge), col n = mrow (out); store fp16 at CSR position
    #pragma unroll
    for (int mt = 0; mt < 4; mt++) {
        #pragma unroll
        for (int reg = 0; reg < 4; reg++) {
            int el = wv * 64 + mt * 16 + quad * 4 + reg;
            int d = dinfo[el];
            if (d >= 0) {
                y[(size_t)d * 32 + mrow]      = (_Float16)acc[mt][0][reg];
                y[(size_t)d * 32 + 16 + mrow] = (_Float16)acc[mt][1][reg];
            }
        }
    }
}

// ---------- gather finalize: streaming fp16 row-range sum + mean + root + bias + ELU ----------

__global__ void gather_fin_kernel(const _Float16* __restrict__ y, const int* __restrict__ row_start,
                                  const float* __restrict__ x, const float* __restrict__ root,
                                  const float* __restrict__ b, float* __restrict__ out, int n) {
    int tid = blockIdx.x * blockDim.x + threadIdx.x;
    int nd = tid >> 5, o = tid & 31;
    if (nd >= n) return;
    int beg = row_start[nd], end = row_start[nd + 1];
    float acc = 0.0f;
    for (int p = beg; p < end; p++) acc += (float)y[(size_t)p * 32 + o];
    acc /= fmaxf((float)(end - beg), 1.0f);
    const float* __restrict__ xr = x + (size_t)nd * 32;
    float rsum = 0.0f;
    #pragma unroll
    for (int i = 0; i < 32; i++) rsum += xr[i] * root[i * 32 + o];
    float v = acc + rsum + b[o];
    out[(size_t)nd * 32 + o] = (v > 0.0f) ? v : expm1f(v);
}

// ---------- conv1 (cin=1) node-centric ----------

__global__ void conv1_node_kernel(const float* __restrict__ x, const int* __restrict__ ei,
                                  const float* __restrict__ pseudo,
                                  const int* __restrict__ row_start, const int* __restrict__ csr,
                                  const float* __restrict__ W, const float* __restrict__ root,
                                  const float* __restrict__ b, float* __restrict__ out, int n) {
    int tid = blockIdx.x * blockDim.x + threadIdx.x;
    int nd = tid >> 5, o = tid & 31;
    if (nd >= n) return;
    int beg = row_start[nd], end = row_start[nd + 1];
    float acc = 0.0f;
    for (int idx = beg; idx < end; idx++) {
        int e = csr[idx];
        int src = ei[e];
        float ps[3] = {pseudo[e * 3], pseudo[e * 3 + 1], pseudo[e * 3 + 2]};
        float w[8]; int flat[8];
        spline_basis(ps, w, flat);
        float s = 0.0f;
        #pragma unroll
        for (int c = 0; c < 8; c++) s += w[c] * W[flat[c] * 32 + o];
        acc += s * x[src];
    }
    float v = acc / fmaxf((float)(end - beg), 1.0f) + x[nd] * root[o] + b[o];
    out[(size_t)nd * 32 + o] = (v > 0.0f) ? v : expm1f(v);
}

// ---------- FC + log_softmax: 32 lanes per row, shuffle reduce ----------

__global__ void fc_kernel(const float* __restrict__ h, const float* __restrict__ fw,
                          const float* __restrict__ fb, float* __restrict__ out, int B) {
    int tid = blockIdx.x * blockDim.x + threadIdx.x;
    int row = tid >> 5, lane = tid & 31;
    if (row >= B) return;
    const float* hb = h + (size_t)row * 256;
    float lg[10];
    #pragma unroll
    for (int j = 0; j < 10; j++) lg[j] = 0.0f;
    for (int tt = lane; tt < 256; tt += 32) {
        float hv = hb[tt];
        const float* fr = fw + tt * 10;
        #pragma unroll
        for (int j = 0; j < 10; j++) lg[j] += hv * fr[j];
    }
    #pragma unroll
    for (int off = 16; off > 0; off >>= 1)
        #pragma unroll
        for (int j = 0; j < 10; j++) lg[j] += __shfl_down(lg[j], off, 32);
    if (lane == 0) {
        #pragma unroll
        for (int j = 0; j < 10; j++) lg[j] += fb[j];
        float m = lg[0];
        #pragma unroll
        for (int j = 1; j < 10; j++) m = fmaxf(m, lg[j]);
        float s = 0.0f;
        #pragma unroll
        for (int j = 0; j < 10; j++) s += expf(lg[j] - m);
        float lse = logf(s) + m;
        #pragma unroll
        for (int j = 0; j < 10; j++) out[(size_t)row * 10 + j] = lg[j] - lse;
    }
}

// ---------- launch ----------

static inline int cdiv(long long a, int b) { return (int)((a + b - 1) / b); }

extern "C" void kernel_launch(void* const* d_in, const int* in_sizes, int n_in,
                              void* d_out, int out_size, void* d_ws, size_t ws_size,
                              hipStream_t stream) {
    const int N1 = N1c, N2 = N2c, N3 = N3c, B8 = B8c;
    const int B = B8 / 8;

    const float* x      = (const float*)d_in[0];
    const int*   cl0    = (const int*)d_in[1];
    const int*   ei1    = (const int*)d_in[2];
    const float* ps1    = (const float*)d_in[3];
    const int*   cl1    = (const int*)d_in[4];
    const int*   ei2    = (const int*)d_in[5];
    const float* ps2    = (const float*)d_in[6];
    const int*   cl2    = (const int*)d_in[7];
    const int*   ei3    = (const int*)d_in[8];
    const float* ps3    = (const float*)d_in[9];
    const int*   cl3    = (const int*)d_in[10];
    const float* W1     = (const float*)d_in[11];
    const float* root1  = (const float*)d_in[12];
    const float* b1     = (const float*)d_in[13];
    const float* W2     = (const float*)d_in[14];
    const float* root2  = (const float*)d_in[15];
    const float* b2     = (const float*)d_in[16];
    const float* W3     = (const float*)d_in[17];
    const float* root3  = (const float*)d_in[18];
    const float* b3     = (const float*)d_in[19];
    const float* fc_w   = (const float*)d_in[20];
    const float* fc_b   = (const float*)d_in[21];
    float* out = (float*)d_out;

    const int E1 = in_sizes[2] / 2;
    const int E2 = in_sizes[5] / 2;
    const int E3 = in_sizes[8] / 2;
    const long long Etot = (long long)E1 + E2 + E3;
    const long long IT = Etot + N0c + N1c + N2c + N3c;

    const int grid2 = cdiv((long long)E2 + 64 * 255, 256);
    const int grid3 = cdiv((long long)E3 + 64 * 255, 256);
    const int pad2 = grid2 * 256, pad3 = grid3 * 256;
    const int ymax = (E2 > E3 ? E2 : E3);

    // ---- workspace layout ----
    char* wp = (char*)d_ws;
    float* p0  = (float*)wp;               wp += (size_t)N1 * 4;
    float* h1  = (float*)wp;               wp += (size_t)N1 * 32 * 4;
    float* p1  = (float*)wp;               wp += (size_t)N2 * 32 * 4;
    float* h2  = (float*)wp;               wp += (size_t)N2 * 32 * 4;
    float* p2  = (float*)wp;               wp += (size_t)N3 * 32 * 4;
    float* h3  = (float*)wp;               wp += (size_t)N3 * 32 * 4;
    float* p3  = (float*)wp;               wp += (size_t)B8 * 32 * 4;
    // zeroed-together region: [cnt | cur | ccnt | ccur]
    int* cnt   = (int*)wp;                 wp += (size_t)SBT * 4;
    int* cur   = (int*)wp;                 wp += (size_t)SBT * 4;
    int* ccnt  = (int*)wp;                 wp += 128 * 4;
    int* ccur  = (int*)wp;                 wp += 128 * 4;
    size_t zero_bytes = (size_t)(wp - (char*)cnt);
    int* coff  = (int*)wp;                 wp += 128 * 4;
    int* rows  = (int*)wp;                 wp += (size_t)(SBT + 7) * 4;
    int* bsum  = (int*)wp;                 wp += 256 * 4;
    int* csr1  = (int*)wp;                 wp += (size_t)E1 * 4;
    int* dpos2 = (int*)wp;                 wp += (size_t)E2 * 4;
    int* dpos3 = (int*)wp;                 wp += (size_t)E3 * 4;
    int* cellid2 = (int*)wp;               wp += (size_t)E2 * 4;
    int* cellid3 = (int*)wp;               wp += (size_t)E3 * 4;
    int* mem0  = (int*)wp;                 wp += (size_t)N0c * 4;
    int* mem1  = (int*)wp;                 wp += (size_t)N1c * 4;
    int* mem2  = (int*)wp;                 wp += (size_t)N2c * 4;
    int* mem3  = (int*)wp;                 wp += (size_t)N3c * 4;
    int* eidx2 = (int*)wp;                 wp += (size_t)pad2 * 4;
    int* eidx3 = (int*)wp;                 wp += (size_t)pad3 * 4;
    float* WT2 = (float*)wp;               wp += (size_t)K3 * 1024 * 4;
    float* WT3 = (float*)wp;               wp += (size_t)K3 * 1024 * 4;
    _Float16* yh = (_Float16*)wp;          // ymax*32 halves

    int* row1  = rows;
    int* row2  = rows + SB1 + 1;
    int* row3  = rows + SB2 + 2;
    int* crow0 = rows + SB3 + 3;
    int* crow1 = rows + SB4 + 4;
    int* crow2 = rows + SB5 + 5;
    int* crow3 = rows + SB6 + 6;

    const int T = 256;
    const int nb = SBT / 1024;   // 240

    // ========== indexing phase (input-only) ==========
    hipMemsetAsync(cnt, 0, zero_bytes, stream);
    hipMemsetAsync(eidx2, 0xFF, ((size_t)pad2 + pad3) * 4, stream);
    wtrans_kernel<<<cdiv((long long)K3 * 1024, T), T, 0, stream>>>(W2, W3, WT2, WT3);
    index_hist_all<<<cdiv(IT, 1024), 1024, 0, stream>>>(
        ei1, ei2, ei3, ps2, ps3, cl0, cl1, cl2, cl3, cnt, ccnt, cellid2, cellid3, E1, E2, E3);
    scan_blocks_kernel<<<nb, 1024, 0, stream>>>(cnt, rows, bsum);
    scan_sums_kernel<<<1, 256, 0, stream>>>(bsum, ccnt, coff, nb);
    scan_add_kernel<<<nb, 1024, 0, stream>>>(rows, bsum, E1, E2, E3);
    scatter_all<<<cdiv(IT, 1024), 1024, 0, stream>>>(
        ei1, ei2, ei3, cl0, cl1, cl2, cl3, cur, rows,
        csr1, dpos2, dpos3, mem0, mem1, mem2, mem3,
        cellid2, cellid3, ccur, coff, eidx2, eidx3, E1, E2, E3);

    // ========== pipeline ==========
    pool1ch_kernel<<<cdiv(N1, T), T, 0, stream>>>(x, crow0, mem0, p0, N1);

    conv1_node_kernel<<<cdiv((long long)N1 * 32, T), T, 0, stream>>>(
        p0, ei1, ps1, row1, csr1, W1, root1, b1, h1, N1);

    pool32ch_kernel<<<cdiv((long long)N2 * 32, T), T, 0, stream>>>(h1, crow1, mem1, p1, N2);

    conv_cell_mfma<<<grid2, 256, 0, stream>>>(p1, ei2, ps2, eidx2, dpos2, WT2, yh, E2);
    gather_fin_kernel<<<cdiv((long long)N2 * 32, T), T, 0, stream>>>(
        yh, row2, p1, root2, b2, h2, N2);

    pool32ch_kernel<<<cdiv((long long)N3 * 32, T), T, 0, stream>>>(h2, crow2, mem2, p2, N3);

    conv_cell_mfma<<<grid3, 256, 0, stream>>>(p2, ei3, ps3, eidx3, dpos3, WT3, yh, E3);
    gather_fin_kernel<<<cdiv((long long)N3 * 32, T), T, 0, stream>>>(
        yh, row3, p2, root3, b3, h3, N3);

    pool32ch_kernel<<<cdiv((long long)B8 * 32, T), T, 0, stream>>>(h3, crow3, mem3, p3, B8);

    fc_kernel<<<cdiv((long long)B * 32, T), T, 0, stream>>>(p3, fc_w, fc_b, out, B);
}

// Round 8
// 789.616 us; speedup vs baseline: 6.5882x; 1.0593x over previous
//
#include <hip/hip_runtime.h>
#include <math.h>

#define KS 5
#define K3 125

// problem sizes (fixed)
#define N0c 131072
#define N1c 65536
#define N2c 32768
#define N3c 16384
#define B8c 16384

typedef _Float16 hf8_t __attribute__((ext_vector_type(8)));
typedef float f32x4_t __attribute__((ext_vector_type(4)));

union wpack_u { _Float16 h[8]; uint4 u; };

// ---------- helpers ----------

__device__ __forceinline__ void spline_k0f(const float ps[3], int k0[3], float f[3]) {
    #pragma unroll
    for (int d = 0; d < 3; d++) {
        float v = ps[d] * (float)(KS - 1);
        float kf = floorf(v);
        kf = fminf(fmaxf(kf, 0.0f), (float)(KS - 2));
        k0[d] = (int)kf;
        f[d] = v - kf;
    }
}

__device__ __forceinline__ void spline_basis(const float ps[3], float w[8], int k0[3]) {
    float f[3];
    spline_k0f(ps, k0, f);
    #pragma unroll
    for (int c = 0; c < 8; c++) {
        float wc = 1.0f;
        #pragma unroll
        for (int d = 0; d < 3; d++) {
            int b = (c >> d) & 1;
            wc *= b ? f[d] : (1.0f - f[d]);
        }
        w[c] = wc;
    }
}

__device__ __forceinline__ int cell_of(const float* __restrict__ pseudo, int e) {
    float ps[3] = {pseudo[(size_t)e * 3], pseudo[(size_t)e * 3 + 1], pseudo[(size_t)e * 3 + 2]};
    int k0[3]; float f[3];
    spline_k0f(ps, k0, f);
    return (k0[0] * 4 + k0[1]) * 4 + k0[2];
}

// bin-space segment boundaries (bins = dst1,dst2,dst3,cl0,cl1,cl2,cl3)
#define SB1 65536
#define SB2 98304
#define SB3 114688
#define SB4 180224
#define SB5 212992
#define SB6 229376
#define SBT 245760

__device__ __forceinline__ int seg_of(int i) {
    return (i < SB1) ? 0 : (i < SB2) ? 1 : (i < SB3) ? 2 :
           (i < SB4) ? 3 : (i < SB5) ? 4 : (i < SB6) ? 5 : 6;
}

// ---------- W transpose: [bin][i][o] -> [bin][o][i] ----------

__global__ void wtrans_kernel(const float* __restrict__ W2, const float* __restrict__ W3,
                              float* __restrict__ WT2, float* __restrict__ WT3) {
    int tid = blockIdx.x * blockDim.x + threadIdx.x;
    const int total = K3 * 1024;
    if (tid >= total) return;
    int bin = tid >> 10, r = tid & 1023, i = r >> 5, o = r & 31;
    WT2[bin * 1024 + o * 32 + i] = W2[tid];
    WT3[bin * 1024 + o * 32 + i] = W3[tid];
}

// ---------- fused indexing ----------

__global__ void index_hist_all(const int* __restrict__ ei1, const int* __restrict__ ei2,
                               const int* __restrict__ ei3,
                               const float* __restrict__ ps2, const float* __restrict__ ps3,
                               const int* __restrict__ cl0, const int* __restrict__ cl1,
                               const int* __restrict__ cl2, const int* __restrict__ cl3,
                               int* __restrict__ cnt, int* __restrict__ ccnt,
                               int* __restrict__ cellid2, int* __restrict__ cellid3,
                               int E1, int E2, int E3) {
    __shared__ int lcnt[128];
    int t = threadIdx.x;
    if (t < 128) lcnt[t] = 0;
    __syncthreads();
    long long g = (long long)blockIdx.x * blockDim.x + t;
    long long Etot = (long long)E1 + E2 + E3;
    long long IT = Etot + N0c + N1c + N2c + N3c;
    if (g < IT) {
        if (g < E1) {
            int e = (int)g;
            atomicAdd(&cnt[ei1[E1 + e]], 1);
        } else if (g < (long long)E1 + E2) {
            int e = (int)(g - E1);
            atomicAdd(&cnt[SB1 + ei2[E2 + e]], 1);
            int c = cell_of(ps2, e);
            cellid2[e] = c;
            atomicAdd(&lcnt[c], 1);
        } else if (g < Etot) {
            int e = (int)(g - E1 - E2);
            atomicAdd(&cnt[SB2 + ei3[E3 + e]], 1);
            int c = cell_of(ps3, e);
            cellid3[e] = c;
            atomicAdd(&lcnt[64 + c], 1);
        } else if (g < Etot + N0c) {
            int i = (int)(g - Etot);
            atomicAdd(&cnt[SB3 + cl0[i]], 1);
        } else if (g < Etot + N0c + N1c) {
            int i = (int)(g - Etot - N0c);
            atomicAdd(&cnt[SB4 + cl1[i]], 1);
        } else if (g < Etot + N0c + N1c + N2c) {
            int i = (int)(g - Etot - N0c - N1c);
            atomicAdd(&cnt[SB5 + cl2[i]], 1);
        } else {
            int i = (int)(g - Etot - N0c - N1c - N2c);
            atomicAdd(&cnt[SB6 + cl3[i]], 1);
        }
    }
    __syncthreads();
    if (t < 128 && lcnt[t] > 0) atomicAdd(&ccnt[t], lcnt[t]);
}

// ---------- hierarchical segmented scan ----------

__global__ void scan_blocks_kernel(const int* __restrict__ cnt, int* __restrict__ rows,
                                   int* __restrict__ bsum) {
    __shared__ int sdata[1024];
    int t = threadIdx.x;
    int i = blockIdx.x * 1024 + t;
    int v = cnt[i];
    sdata[t] = v;
    __syncthreads();
    for (int off = 1; off < 1024; off <<= 1) {
        int add = (t >= off) ? sdata[t - off] : 0;
        __syncthreads();
        sdata[t] += add;
        __syncthreads();
    }
    rows[i + seg_of(i)] = sdata[t] - v;
    if (t == 1023) bsum[blockIdx.x] = sdata[1023];
}

__global__ void scan_sums_kernel(int* __restrict__ bsum, const int* __restrict__ ccnt,
                                 int* __restrict__ coff, int* __restrict__ blockcell2,
                                 int* __restrict__ blockcell3, int nb) {
    __shared__ int sdata[256];
    __shared__ int sseg[256];
    int t = threadIdx.x;
    int v = (t < nb) ? bsum[t] : 0;
    int seg = (t < 64) ? 0 : (t < 96) ? 1 : (t < 112) ? 2 :
              (t < 176) ? 3 : (t < 208) ? 4 : (t < 224) ? 5 : 6;
    sdata[t] = v; sseg[t] = seg;
    __syncthreads();
    for (int off = 1; off < 256; off <<= 1) {
        int add = (t >= off && sseg[t - off] == seg) ? sdata[t - off] : 0;
        __syncthreads();
        sdata[t] += add;
        __syncthreads();
    }
    if (t < nb) bsum[t] = sdata[t] - v;
    if (t == 0) {
        int acc = 0;
        for (int c = 0; c < 64; c++) {
            coff[c] = acc;
            int nbk = (ccnt[c] + 255) >> 8;
            for (int k = 0; k < nbk; k++) blockcell2[(acc >> 8) + k] = c;
            acc += nbk << 8;
        }
    }
    if (t == 1) {
        int acc = 0;
        for (int c = 0; c < 64; c++) {
            coff[64 + c] = acc;
            int nbk = (ccnt[64 + c] + 255) >> 8;
            for (int k = 0; k < nbk; k++) blockcell3[(acc >> 8) + k] = c;
            acc += nbk << 8;
        }
    }
}

__global__ void scan_add_kernel(int* __restrict__ rows, const int* __restrict__ bsum,
                                int E1, int E2, int E3) {
    int t = threadIdx.x;
    int i = blockIdx.x * 1024 + t;
    rows[i + seg_of(i)] += bsum[blockIdx.x];
    if (blockIdx.x == 0) {
        if (t == 0) rows[SB1 + 0] = E1;
        if (t == 1) rows[SB2 + 1] = E2;
        if (t == 2) rows[SB3 + 2] = E3;
        if (t == 3) rows[SB4 + 3] = N0c;
        if (t == 4) rows[SB5 + 4] = N1c;
        if (t == 5) rows[SB6 + 5] = N2c;
        if (t == 6) rows[SBT + 6] = N3c;
    }
}

// ---------- fused scatter + payload materialization ----------
// lvl1: wpay1(u4)+meta1(u32: src|cell<<16) at CSR position.
// lvl2/3: wpay(u4)+mpay(int2: src,dpos) at padded bucket slot.

__global__ void scatter_all(const int* __restrict__ ei1, const int* __restrict__ ei2,
                            const int* __restrict__ ei3,
                            const float* __restrict__ ps1, const float* __restrict__ ps2,
                            const float* __restrict__ ps3,
                            const int* __restrict__ cl0, const int* __restrict__ cl1,
                            const int* __restrict__ cl2, const int* __restrict__ cl3,
                            int* __restrict__ cur, const int* __restrict__ rows,
                            uint4* __restrict__ wpay1, unsigned* __restrict__ meta1,
                            uint4* __restrict__ wpay2, int2* __restrict__ mpay2,
                            uint4* __restrict__ wpay3, int2* __restrict__ mpay3,
                            int* __restrict__ mem0, int* __restrict__ mem1,
                            int* __restrict__ mem2, int* __restrict__ mem3,
                            const int* __restrict__ cellid2, const int* __restrict__ cellid3,
                            int* __restrict__ ccur, const int* __restrict__ coff,
                            int E1, int E2, int E3) {
    const int* row1  = rows;
    const int* row2  = rows + SB1 + 1;
    const int* row3  = rows + SB2 + 2;
    const int* crow0 = rows + SB3 + 3;
    const int* crow1 = rows + SB4 + 4;
    const int* crow2 = rows + SB5 + 5;
    const int* crow3 = rows + SB6 + 6;

    __shared__ int lcnt[128];
    __shared__ int lbase[128];
    int t = threadIdx.x;
    if (t < 128) lcnt[t] = 0;
    __syncthreads();
    long long g = (long long)blockIdx.x * blockDim.x + t;
    long long Etot = (long long)E1 + E2 + E3;
    long long IT = Etot + N0c + N1c + N2c + N3c;
    int lidx = -1, myrank = 0, lvl = 0;
    int psrc = 0, pdpos = 0;
    wpack_u pk;
    if (g < IT) {
        if (g < E1) {
            int e = (int)g;
            int dst = ei1[E1 + e];
            int pos = atomicAdd(&cur[dst], 1);
            int p = row1[dst] + pos;
            float ps[3] = {ps1[(size_t)e * 3], ps1[(size_t)e * 3 + 1], ps1[(size_t)e * 3 + 2]};
            float w[8]; int k0[3];
            spline_basis(ps, w, k0);
            #pragma unroll
            for (int c = 0; c < 8; c++) pk.h[c] = (_Float16)w[c];
            wpay1[p] = pk.u;
            int cell = (k0[0] * 4 + k0[1]) * 4 + k0[2];
            meta1[p] = (unsigned)ei1[e] | ((unsigned)cell << 16);
        } else if (g < (long long)E1 + E2) {
            int e = (int)(g - E1); lvl = 2;
            int dst = ei2[E2 + e];
            int pos = atomicAdd(&cur[SB1 + dst], 1);
            pdpos = row2[dst] + pos;
            psrc = ei2[e];
            float ps[3] = {ps2[(size_t)e * 3], ps2[(size_t)e * 3 + 1], ps2[(size_t)e * 3 + 2]};
            float w[8]; int k0[3];
            spline_basis(ps, w, k0);
            #pragma unroll
            for (int c = 0; c < 8; c++) pk.h[c] = (_Float16)w[c];
            lidx = cellid2[e];
            myrank = atomicAdd(&lcnt[lidx], 1);
        } else if (g < Etot) {
            int e = (int)(g - E1 - E2); lvl = 3;
            int dst = ei3[E3 + e];
            int pos = atomicAdd(&cur[SB2 + dst], 1);
            pdpos = row3[dst] + pos;
            psrc = ei3[e];
            float ps[3] = {ps3[(size_t)e * 3], ps3[(size_t)e * 3 + 1], ps3[(size_t)e * 3 + 2]};
            float w[8]; int k0[3];
            spline_basis(ps, w, k0);
            #pragma unroll
            for (int c = 0; c < 8; c++) pk.h[c] = (_Float16)w[c];
            lidx = 64 + cellid3[e];
            myrank = atomicAdd(&lcnt[lidx], 1);
        } else if (g < Etot + N0c) {
            int i = (int)(g - Etot);
            int b = cl0[i];
            int pos = atomicAdd(&cur[SB3 + b], 1);
            mem0[crow0[b] + pos] = i;
        } else if (g < Etot + N0c + N1c) {
            int i = (int)(g - Etot - N0c);
            int b = cl1[i];
            int pos = atomicAdd(&cur[SB4 + b], 1);
            mem1[crow1[b] + pos] = i;
        } else if (g < Etot + N0c + N1c + N2c) {
            int i = (int)(g - Etot - N0c - N1c);
            int b = cl2[i];
            int pos = atomicAdd(&cur[SB5 + b], 1);
            mem2[crow2[b] + pos] = i;
        } else {
            int i = (int)(g - Etot - N0c - N1c - N2c);
            int b = cl3[i];
            int pos = atomicAdd(&cur[SB6 + b], 1);
            mem3[crow3[b] + pos] = i;
        }
    }
    __syncthreads();
    if (t < 128) lbase[t] = (lcnt[t] > 0) ? atomicAdd(&ccur[t], lcnt[t]) : 0;
    __syncthreads();
    if (lidx >= 0) {
        int slot = coff[lidx] + lbase[lidx] + myrank;
        if (lvl == 2) { wpay2[slot] = pk.u; mpay2[slot] = make_int2(psrc, pdpos); }
        else          { wpay3[slot] = pk.u; mpay3[slot] = make_int2(psrc, pdpos); }
    }
}

// ---------- pooling: segment-max gather via cluster CSR ----------

__global__ void pool1ch_kernel(const float* __restrict__ in, const int* __restrict__ crow,
                               const int* __restrict__ mem, float* __restrict__ out, int n) {
    int nd = blockIdx.x * blockDim.x + threadIdx.x;
    if (nd >= n) return;
    int beg = crow[nd], end = crow[nd + 1];
    float v = -INFINITY;
    for (int p = beg; p < end; p++) v = fmaxf(v, in[mem[p]]);
    out[nd] = (beg == end) ? 0.0f : v;
}

__global__ void pool32ch_kernel(const float* __restrict__ in, const int* __restrict__ crow,
                                const int* __restrict__ mem, float* __restrict__ out, int n) {
    int tid = blockIdx.x * blockDim.x + threadIdx.x;
    int nd = tid >> 5, o = tid & 31;
    if (nd >= n) return;
    int beg = crow[nd], end = crow[nd + 1];
    float v = -INFINITY;
    for (int p = beg; p < end; p++) v = fmaxf(v, in[(size_t)mem[p] * 32 + o]);
    out[(size_t)nd * 32 + o] = (beg == end) ? 0.0f : v;
}

// ---------- cell conv via MFMA fp16 with streamed payload ----------

__global__ __launch_bounds__(256, 4) void conv_cell_mfma(
        const float* __restrict__ x, const uint4* __restrict__ wpay, const int2* __restrict__ mpay,
        const int* __restrict__ blockcell, const float* __restrict__ WT,
        _Float16* __restrict__ y, int E) {
    __shared__ _Float16 Wl[8 * 1024];   // [c][o][i]  16 KB
    __shared__ _Float16 xh[256 * 32];   // [e][i]     16 KB
    __shared__ uint4 wcl[256];          // w8 per edge  4 KB
    __shared__ int dinfo[256];

    int cell = blockcell[blockIdx.x];
    if (cell < 0) return;   // fully-padded trailing block

    int t = threadIdx.x;
    int base = blockIdx.x * 256;
    int2 m = mpay[base + t];
    dinfo[t] = m.y;
    wcl[t] = wpay[base + t];
    int src = (m.y < 0) ? 0 : m.x;

    // stage W for this cell's 8 corners from o-major WT
    {
        int kx = cell >> 4, ky = (cell >> 2) & 3, kz = cell & 3;
        int c = t >> 5, o = t & 31;
        int id0 = kx + ((c >> 0) & 1);
        int id1 = ky + ((c >> 1) & 1);
        int id2 = kz + ((c >> 2) & 1);
        int flat = (id0 * KS + id1) * KS + id2;
        const float4* src4 = (const float4*)(WT + (size_t)flat * 1024 + o * 32);
        _Float16* dst = &Wl[c * 1024 + o * 32];
        #pragma unroll
        for (int j = 0; j < 8; j++) {
            float4 v = src4[j];
            dst[j * 4 + 0] = (_Float16)v.x;
            dst[j * 4 + 1] = (_Float16)v.y;
            dst[j * 4 + 2] = (_Float16)v.z;
            dst[j * 4 + 3] = (_Float16)v.w;
        }
    }

    // stage x (fp16)
    {
        const float4* xr = (const float4*)(x + (size_t)src * 32);
        _Float16* xd = &xh[t * 32];
        #pragma unroll
        for (int j = 0; j < 8; j++) {
            float4 v = xr[j];
            xd[j * 4 + 0] = (_Float16)v.x;
            xd[j * 4 + 1] = (_Float16)v.y;
            xd[j * 4 + 2] = (_Float16)v.z;
            xd[j * 4 + 3] = (_Float16)v.w;
        }
    }
    __syncthreads();

    int wv = t >> 6, lane = t & 63;
    int quad = lane >> 4, mrow = lane & 15;
    const _Float16* whal = (const _Float16*)wcl;

    hf8_t xf[4];
    #pragma unroll
    for (int mt = 0; mt < 4; mt++) {
        int em = wv * 64 + mt * 16 + mrow;
        xf[mt] = *(const hf8_t*)&xh[em * 32 + quad * 8];
    }

    f32x4_t acc[4][2];
    #pragma unroll
    for (int mt = 0; mt < 4; mt++) {
        acc[mt][0] = (f32x4_t)0.0f;
        acc[mt][1] = (f32x4_t)0.0f;
    }

    #pragma unroll
    for (int c = 0; c < 8; c++) {
        hf8_t b0 = *(const hf8_t*)&Wl[c * 1024 + mrow * 32 + quad * 8];
        hf8_t b1 = *(const hf8_t*)&Wl[c * 1024 + (16 + mrow) * 32 + quad * 8];
        #pragma unroll
        for (int mt = 0; mt < 4; mt++) {
            int em = wv * 64 + mt * 16 + mrow;
            _Float16 wcv = whal[em * 8 + c];
            hf8_t af = xf[mt] * wcv;
            acc[mt][0] = __builtin_amdgcn_mfma_f32_16x16x32_f16(af, b0, acc[mt][0], 0, 0, 0);
            acc[mt][1] = __builtin_amdgcn_mfma_f32_16x16x32_f16(af, b1, acc[mt][1], 0, 0, 0);
        }
    }

    #pragma unroll
    for (int mt = 0; mt < 4; mt++) {
        #pragma unroll
        for (int reg = 0; reg < 4; reg++) {
            int el = wv * 64 + mt * 16 + quad * 4 + reg;
            int d = dinfo[el];
            if (d >= 0) {
                y[(size_t)d * 32 + mrow]      = (_Float16)acc[mt][0][reg];
                y[(size_t)d * 32 + 16 + mrow] = (_Float16)acc[mt][1][reg];
            }
        }
    }
}

// ---------- gather finalize ----------

__global__ void gather_fin_kernel(const _Float16* __restrict__ y, const int* __restrict__ row_start,
                                  const float* __restrict__ x, const float* __restrict__ root,
                                  const float* __restrict__ b, float* __restrict__ out, int n) {
    int tid = blockIdx.x * blockDim.x + threadIdx.x;
    int nd = tid >> 5, o = tid & 31;
    if (nd >= n) return;
    int beg = row_start[nd], end = row_start[nd + 1];
    float acc = 0.0f;
    for (int p = beg; p < end; p++) acc += (float)y[(size_t)p * 32 + o];
    acc /= fmaxf((float)(end - beg), 1.0f);
    const float* __restrict__ xr = x + (size_t)nd * 32;
    float rsum = 0.0f;
    #pragma unroll
    for (int i = 0; i < 32; i++) rsum += xr[i] * root[i * 32 + o];
    float v = acc + rsum + b[o];
    out[(size_t)nd * 32 + o] = (v > 0.0f) ? v : expm1f(v);
}

// ---------- conv1 (cin=1) node-centric, streamed payload, W1 in LDS ----------

__global__ __launch_bounds__(256) void conv1_node_kernel(
        const float* __restrict__ x, const unsigned* __restrict__ meta1,
        const uint4* __restrict__ wpay1, const int* __restrict__ row_start,
        const float* __restrict__ W, const float* __restrict__ root,
        const float* __restrict__ b, float* __restrict__ out, int n) {
    __shared__ float Wl[K3 * 32];   // 16 KB
    for (int i = threadIdx.x; i < K3 * 32; i += 256) Wl[i] = W[i];
    __syncthreads();

    int tid = blockIdx.x * blockDim.x + threadIdx.x;
    int nd = tid >> 5, o = tid & 31;
    if (nd >= n) return;
    int beg = row_start[nd], end = row_start[nd + 1];
    float acc = 0.0f;
    for (int idx = beg; idx < end; idx++) {
        unsigned meta = meta1[idx];
        wpack_u pk; pk.u = wpay1[idx];
        int src = meta & 0xFFFF;
        int cell = meta >> 16;
        int f = ((cell >> 4) * 5 + ((cell >> 2) & 3)) * 5 + (cell & 3);
        const float* Wf = &Wl[f * 32 + o];
        float s = (float)pk.h[0] * Wf[0]        + (float)pk.h[1] * Wf[25 * 32]
                + (float)pk.h[2] * Wf[5 * 32]   + (float)pk.h[3] * Wf[30 * 32]
                + (float)pk.h[4] * Wf[1 * 32]   + (float)pk.h[5] * Wf[26 * 32]
                + (float)pk.h[6] * Wf[6 * 32]   + (float)pk.h[7] * Wf[31 * 32];
        acc += x[src] * s;
    }
    float v = acc / fmaxf((float)(end - beg), 1.0f) + x[nd] * root[o] + b[o];
    out[(size_t)nd * 32 + o] = (v > 0.0f) ? v : expm1f(v);
}

// ---------- FC + log_softmax: 32 lanes per row, shuffle reduce ----------

__global__ void fc_kernel(const float* __restrict__ h, const float* __restrict__ fw,
                          const float* __restrict__ fb, float* __restrict__ out, int B) {
    int tid = blockIdx.x * blockDim.x + threadIdx.x;
    int row = tid >> 5, lane = tid & 31;
    if (row >= B) return;
    const float* hb = h + (size_t)row * 256;
    float lg[10];
    #pragma unroll
    for (int j = 0; j < 10; j++) lg[j] = 0.0f;
    for (int tt = lane; tt < 256; tt += 32) {
        float hv = hb[tt];
        const float* fr = fw + tt * 10;
        #pragma unroll
        for (int j = 0; j < 10; j++) lg[j] += hv * fr[j];
    }
    #pragma unroll
    for (int off = 16; off > 0; off >>= 1)
        #pragma unroll
        for (int j = 0; j < 10; j++) lg[j] += __shfl_down(lg[j], off, 32);
    if (lane == 0) {
        #pragma unroll
        for (int j = 0; j < 10; j++) lg[j] += fb[j];
        float m = lg[0];
        #pragma unroll
        for (int j = 1; j < 10; j++) m = fmaxf(m, lg[j]);
        float s = 0.0f;
        #pragma unroll
        for (int j = 0; j < 10; j++) s += expf(lg[j] - m);
        float lse = logf(s) + m;
        #pragma unroll
        for (int j = 0; j < 10; j++) out[(size_t)row * 10 + j] = lg[j] - lse;
    }
}

// ---------- launch ----------

static inline int cdiv(long long a, int b) { return (int)((a + b - 1) / b); }

extern "C" void kernel_launch(void* const* d_in, const int* in_sizes, int n_in,
                              void* d_out, int out_size, void* d_ws, size_t ws_size,
                              hipStream_t stream) {
    const int N1 = N1c, N2 = N2c, N3 = N3c, B8 = B8c;
    const int B = B8 / 8;

    const float* x      = (const float*)d_in[0];
    const int*   cl0    = (const int*)d_in[1];
    const int*   ei1    = (const int*)d_in[2];
    const float* ps1    = (const float*)d_in[3];
    const int*   cl1    = (const int*)d_in[4];
    const int*   ei2    = (const int*)d_in[5];
    const float* ps2    = (const float*)d_in[6];
    const int*   cl2    = (const int*)d_in[7];
    const int*   ei3    = (const int*)d_in[8];
    const float* ps3    = (const float*)d_in[9];
    const int*   cl3    = (const int*)d_in[10];
    const float* W1     = (const float*)d_in[11];
    const float* root1  = (const float*)d_in[12];
    const float* b1     = (const float*)d_in[13];
    const float* W2     = (const float*)d_in[14];
    const float* root2  = (const float*)d_in[15];
    const float* b2     = (const float*)d_in[16];
    const float* W3     = (const float*)d_in[17];
    const float* root3  = (const float*)d_in[18];
    const float* b3     = (const float*)d_in[19];
    const float* fc_w   = (const float*)d_in[20];
    const float* fc_b   = (const float*)d_in[21];
    float* out = (float*)d_out;

    const int E1 = in_sizes[2] / 2;
    const int E2 = in_sizes[5] / 2;
    const int E3 = in_sizes[8] / 2;
    const long long Etot = (long long)E1 + E2 + E3;
    const long long IT = Etot + N0c + N1c + N2c + N3c;

    const int grid2 = cdiv((long long)E2 + 64 * 255, 256);
    const int grid3 = cdiv((long long)E3 + 64 * 255, 256);
    const int pad2 = grid2 * 256, pad3 = grid3 * 256;
    const int ymax = (E2 > E3 ? E2 : E3);

    // ---- workspace layout ----
    char* wp = (char*)d_ws;
    float* p0  = (float*)wp;               wp += (size_t)N1 * 4;
    float* h1  = (float*)wp;               wp += (size_t)N1 * 32 * 4;
    float* p1  = (float*)wp;               wp += (size_t)N2 * 32 * 4;
    float* h2  = (float*)wp;               wp += (size_t)N2 * 32 * 4;
    float* p2  = (float*)wp;               wp += (size_t)N3 * 32 * 4;
    float* h3  = (float*)wp;               wp += (size_t)N3 * 32 * 4;
    float* p3  = (float*)wp;               wp += (size_t)B8 * 32 * 4;
    // zeroed-together region: [cnt | cur | ccnt | ccur]
    int* cnt   = (int*)wp;                 wp += (size_t)SBT * 4;
    int* cur   = (int*)wp;                 wp += (size_t)SBT * 4;
    int* ccnt  = (int*)wp;                 wp += 128 * 4;
    int* ccur  = (int*)wp;                 wp += 128 * 4;
    size_t zero_bytes = (size_t)(wp - (char*)cnt);
    int* coff  = (int*)wp;                 wp += 128 * 4;
    int* rows  = (int*)wp;                 wp += (size_t)(SBT + 7) * 4;
    int* bsum  = (int*)wp;                 wp += 256 * 4;
    int* cellid2 = (int*)wp;               wp += (size_t)E2 * 4;
    int* cellid3 = (int*)wp;               wp += (size_t)E3 * 4;
    int* mem0  = (int*)wp;                 wp += (size_t)N0c * 4;
    int* mem1  = (int*)wp;                 wp += (size_t)N1c * 4;
    int* mem2  = (int*)wp;                 wp += (size_t)N2c * 4;
    int* mem3  = (int*)wp;                 wp += (size_t)N3c * 4;
    uint4* wpay1 = (uint4*)wp;             wp += (size_t)E1 * 16;
    unsigned* meta1 = (unsigned*)wp;       wp += (size_t)E1 * 4;
    uint4* wpay2 = (uint4*)wp;             wp += (size_t)pad2 * 16;
    uint4* wpay3 = (uint4*)wp;             wp += (size_t)pad3 * 16;
    int2* mpay2 = (int2*)wp;               wp += (size_t)pad2 * 8;
    int2* mpay3 = (int2*)wp;               wp += (size_t)pad3 * 8;   // contiguous with mpay2
    int* blockcell2 = (int*)wp;            wp += (size_t)grid2 * 4;
    int* blockcell3 = (int*)wp;            wp += (size_t)grid3 * 4;  // contiguous with blockcell2
    float* WT2 = (float*)wp;               wp += (size_t)K3 * 1024 * 4;
    float* WT3 = (float*)wp;               wp += (size_t)K3 * 1024 * 4;
    _Float16* yh = (_Float16*)wp;          // ymax*32 halves

    int* row1  = rows;
    int* row2  = rows + SB1 + 1;
    int* row3  = rows + SB2 + 2;
    int* crow0 = rows + SB3 + 3;
    int* crow1 = rows + SB4 + 4;
    int* crow2 = rows + SB5 + 5;
    int* crow3 = rows + SB6 + 6;

    const int T = 256;
    const int nb = SBT / 1024;   // 240

    // ========== indexing phase (input-only) ==========
    hipMemsetAsync(cnt, 0, zero_bytes, stream);
    hipMemsetAsync(mpay2, 0xFF, ((size_t)pad2 + pad3) * 8, stream);
    hipMemsetAsync(blockcell2, 0xFF, ((size_t)grid2 + grid3) * 4, stream);
    wtrans_kernel<<<cdiv((long long)K3 * 1024, T), T, 0, stream>>>(W2, W3, WT2, WT3);
    index_hist_all<<<cdiv(IT, 1024), 1024, 0, stream>>>(
        ei1, ei2, ei3, ps2, ps3, cl0, cl1, cl2, cl3, cnt, ccnt, cellid2, cellid3, E1, E2, E3);
    scan_blocks_kernel<<<nb, 1024, 0, stream>>>(cnt, rows, bsum);
    scan_sums_kernel<<<1, 256, 0, stream>>>(bsum, ccnt, coff, blockcell2, blockcell3, nb);
    scan_add_kernel<<<nb, 1024, 0, stream>>>(rows, bsum, E1, E2, E3);
    scatter_all<<<cdiv(IT, 1024), 1024, 0, stream>>>(
        ei1, ei2, ei3, ps1, ps2, ps3, cl0, cl1, cl2, cl3, cur, rows,
        wpay1, meta1, wpay2, mpay2, wpay3, mpay3,
        mem0, mem1, mem2, mem3, cellid2, cellid3, ccur, coff, E1, E2, E3);

    // ========== pipeline ==========
    pool1ch_kernel<<<cdiv(N1, T), T, 0, stream>>>(x, crow0, mem0, p0, N1);

    conv1_node_kernel<<<cdiv((long long)N1 * 32, T), T, 0, stream>>>(
        p0, meta1, wpay1, row1, W1, root1, b1, h1, N1);

    pool32ch_kernel<<<cdiv((long long)N2 * 32, T), T, 0, stream>>>(h1, crow1, mem1, p1, N2);

    conv_cell_mfma<<<grid2, 256, 0, stream>>>(p1, wpay2, mpay2, blockcell2, WT2, yh, E2);
    gather_fin_kernel<<<cdiv((long long)N2 * 32, T), T, 0, stream>>>(
        yh, row2, p1, root2, b2, h2, N2);

    pool32ch_kernel<<<cdiv((long long)N3 * 32, T), T, 0, stream>>>(h2, crow2, mem2, p2, N3);

    conv_cell_mfma<<<grid3, 256, 0, stream>>>(p2, wpay3, mpay3, blockcell3, WT3, yh, E3);
    gather_fin_kernel<<<cdiv((long long)N3 * 32, T), T, 0, stream>>>(
        yh, row3, p2, root3, b3, h3, N3);

    pool32ch_kernel<<<cdiv((long long)B8 * 32, T), T, 0, stream>>>(h3, crow3, mem3, p3, B8);

    fc_kernel<<<cdiv((long long)B * 32, T), T, 0, stream>>>(p3, fc_w, fc_b, out, B);
}

// Round 9
// 740.536 us; speedup vs baseline: 7.0249x; 1.0663x over previous
//
#include <hip/hip_runtime.h>
#include <math.h>

#define KS 5
#define K3 125

// problem sizes (fixed)
#define N0c 131072
#define N1c 65536
#define N2c 32768
#define N3c 16384
#define B8c 16384

typedef _Float16 hf8_t __attribute__((ext_vector_type(8)));
typedef float f32x4_t __attribute__((ext_vector_type(4)));

union wpack_u { _Float16 h[8]; uint4 u; };

// ---------- helpers ----------
// quantized pseudo: q = rint(ps*65536) clamped to 65535; v = q/16384 in [0,4];
// k0 = q>>14 (0..3), f = (q&16383)/16384.  Exactly reproduces clamp/floor semantics.

__device__ __forceinline__ unsigned qz16(float ps) {
    float t = rintf(ps * 65536.0f);
    t = fminf(fmaxf(t, 0.0f), 65535.0f);
    return (unsigned)t;
}

__device__ __forceinline__ int cell_of_q(const float* __restrict__ pseudo, int e) {
    unsigned q0 = qz16(pseudo[(size_t)e * 3]);
    unsigned q1 = qz16(pseudo[(size_t)e * 3 + 1]);
    unsigned q2 = qz16(pseudo[(size_t)e * 3 + 2]);
    return (int)(((q0 >> 14) << 4) | ((q1 >> 14) << 2) | (q2 >> 14));
}

// bin-space segment boundaries (bins = dst1,dst2,dst3,cl0,cl1,cl2,cl3)
#define SB1 65536
#define SB2 98304
#define SB3 114688
#define SB4 180224
#define SB5 212992
#define SB6 229376
#define SBT 245760

__device__ __forceinline__ int seg_of(int i) {
    return (i < SB1) ? 0 : (i < SB2) ? 1 : (i < SB3) ? 2 :
           (i < SB4) ? 3 : (i < SB5) ? 4 : (i < SB6) ? 5 : 6;
}

// ---------- W transpose + fp16: [bin][i][o] f32 -> [bin][o][i] fp16 ----------

__global__ void wtrans_kernel(const float* __restrict__ W2, const float* __restrict__ W3,
                              _Float16* __restrict__ WT2, _Float16* __restrict__ WT3) {
    int tid = blockIdx.x * blockDim.x + threadIdx.x;
    const int total = K3 * 1024;
    if (tid >= total) return;
    int bin = tid >> 10, r = tid & 1023, i = r >> 5, o = r & 31;
    WT2[bin * 1024 + o * 32 + i] = (_Float16)W2[tid];
    WT3[bin * 1024 + o * 32 + i] = (_Float16)W3[tid];
}

// ---------- fused indexing ----------

__global__ void index_hist_all(const int* __restrict__ ei1, const int* __restrict__ ei2,
                               const int* __restrict__ ei3,
                               const float* __restrict__ ps2, const float* __restrict__ ps3,
                               const int* __restrict__ cl0, const int* __restrict__ cl1,
                               const int* __restrict__ cl2, const int* __restrict__ cl3,
                               int* __restrict__ cnt, int* __restrict__ ccnt,
                               int E1, int E2, int E3) {
    __shared__ int lcnt[128];
    int t = threadIdx.x;
    if (t < 128) lcnt[t] = 0;
    __syncthreads();
    long long g = (long long)blockIdx.x * blockDim.x + t;
    long long Etot = (long long)E1 + E2 + E3;
    long long IT = Etot + N0c + N1c + N2c + N3c;
    if (g < IT) {
        if (g < E1) {
            int e = (int)g;
            atomicAdd(&cnt[ei1[E1 + e]], 1);
        } else if (g < (long long)E1 + E2) {
            int e = (int)(g - E1);
            atomicAdd(&cnt[SB1 + ei2[E2 + e]], 1);
            atomicAdd(&lcnt[cell_of_q(ps2, e)], 1);
        } else if (g < Etot) {
            int e = (int)(g - E1 - E2);
            atomicAdd(&cnt[SB2 + ei3[E3 + e]], 1);
            atomicAdd(&lcnt[64 + cell_of_q(ps3, e)], 1);
        } else if (g < Etot + N0c) {
            int i = (int)(g - Etot);
            atomicAdd(&cnt[SB3 + cl0[i]], 1);
        } else if (g < Etot + N0c + N1c) {
            int i = (int)(g - Etot - N0c);
            atomicAdd(&cnt[SB4 + cl1[i]], 1);
        } else if (g < Etot + N0c + N1c + N2c) {
            int i = (int)(g - Etot - N0c - N1c);
            atomicAdd(&cnt[SB5 + cl2[i]], 1);
        } else {
            int i = (int)(g - Etot - N0c - N1c - N2c);
            atomicAdd(&cnt[SB6 + cl3[i]], 1);
        }
    }
    __syncthreads();
    if (t < 128 && lcnt[t] > 0) atomicAdd(&ccnt[t], lcnt[t]);
}

// ---------- hierarchical segmented scan ----------

__global__ void scan_blocks_kernel(const int* __restrict__ cnt, int* __restrict__ rows,
                                   int* __restrict__ bsum) {
    __shared__ int sdata[1024];
    int t = threadIdx.x;
    int i = blockIdx.x * 1024 + t;
    int v = cnt[i];
    sdata[t] = v;
    __syncthreads();
    for (int off = 1; off < 1024; off <<= 1) {
        int add = (t >= off) ? sdata[t - off] : 0;
        __syncthreads();
        sdata[t] += add;
        __syncthreads();
    }
    rows[i + seg_of(i)] = sdata[t] - v;
    if (t == 1023) bsum[blockIdx.x] = sdata[1023];
}

__global__ void scan_sums_kernel(int* __restrict__ bsum, const int* __restrict__ ccnt,
                                 int* __restrict__ coff, int* __restrict__ blockcell2,
                                 int* __restrict__ blockcell3, int nb) {
    __shared__ int sdata[256];
    __shared__ int sseg[256];
    int t = threadIdx.x;
    int v = (t < nb) ? bsum[t] : 0;
    int seg = (t < 64) ? 0 : (t < 96) ? 1 : (t < 112) ? 2 :
              (t < 176) ? 3 : (t < 208) ? 4 : (t < 224) ? 5 : 6;
    sdata[t] = v; sseg[t] = seg;
    __syncthreads();
    for (int off = 1; off < 256; off <<= 1) {
        int add = (t >= off && sseg[t - off] == seg) ? sdata[t - off] : 0;
        __syncthreads();
        sdata[t] += add;
        __syncthreads();
    }
    if (t < nb) bsum[t] = sdata[t] - v;
    if (t == 0) {
        int acc = 0;
        for (int c = 0; c < 64; c++) {
            coff[c] = acc;
            int nbk = (ccnt[c] + 255) >> 8;
            for (int k = 0; k < nbk; k++) blockcell2[(acc >> 8) + k] = c;
            acc += nbk << 8;
        }
    }
    if (t == 1) {
        int acc = 0;
        for (int c = 0; c < 64; c++) {
            coff[64 + c] = acc;
            int nbk = (ccnt[64 + c] + 255) >> 8;
            for (int k = 0; k < nbk; k++) blockcell3[(acc >> 8) + k] = c;
            acc += nbk << 8;
        }
    }
}

__global__ void scan_add_kernel(int* __restrict__ rows, const int* __restrict__ bsum,
                                int E1, int E2, int E3) {
    int t = threadIdx.x;
    int i = blockIdx.x * 1024 + t;
    rows[i + seg_of(i)] += bsum[blockIdx.x];
    if (blockIdx.x == 0) {
        if (t == 0) rows[SB1 + 0] = E1;
        if (t == 1) rows[SB2 + 1] = E2;
        if (t == 2) rows[SB3 + 2] = E3;
        if (t == 3) rows[SB4 + 3] = N0c;
        if (t == 4) rows[SB5 + 4] = N1c;
        if (t == 5) rows[SB6 + 5] = N2c;
        if (t == 6) rows[SBT + 6] = N3c;
    }
}

// ---------- fused scatter + compact quantized payloads ----------
// lvl1: pay1[p] = {q0|q1<<16, q2|src<<16} (8B) at CSR position p.
// lvl2/3: vpay[slot] = same 8B; dpos[slot] = CSR position (4B).

__global__ void scatter_all(const int* __restrict__ ei1, const int* __restrict__ ei2,
                            const int* __restrict__ ei3,
                            const float* __restrict__ ps1, const float* __restrict__ ps2,
                            const float* __restrict__ ps3,
                            const int* __restrict__ cl0, const int* __restrict__ cl1,
                            const int* __restrict__ cl2, const int* __restrict__ cl3,
                            int* __restrict__ cur, const int* __restrict__ rows,
                            uint2* __restrict__ pay1,
                            uint2* __restrict__ vpay2, int* __restrict__ dpos2,
                            uint2* __restrict__ vpay3, int* __restrict__ dpos3,
                            int* __restrict__ mem0, int* __restrict__ mem1,
                            int* __restrict__ mem2, int* __restrict__ mem3,
                            int* __restrict__ ccur, const int* __restrict__ coff,
                            int E1, int E2, int E3) {
    const int* row1  = rows;
    const int* row2  = rows + SB1 + 1;
    const int* row3  = rows + SB2 + 2;
    const int* crow0 = rows + SB3 + 3;
    const int* crow1 = rows + SB4 + 4;
    const int* crow2 = rows + SB5 + 5;
    const int* crow3 = rows + SB6 + 6;

    __shared__ int lcnt[128];
    __shared__ int lbase[128];
    int t = threadIdx.x;
    if (t < 128) lcnt[t] = 0;
    __syncthreads();
    long long g = (long long)blockIdx.x * blockDim.x + t;
    long long Etot = (long long)E1 + E2 + E3;
    long long IT = Etot + N0c + N1c + N2c + N3c;
    int lidx = -1, myrank = 0, lvl = 0, pdpos = 0;
    uint2 vq;
    if (g < IT) {
        if (g < E1) {
            int e = (int)g;
            int dst = ei1[E1 + e];
            int pos = atomicAdd(&cur[dst], 1);
            int p = row1[dst] + pos;
            unsigned q0 = qz16(ps1[(size_t)e * 3]);
            unsigned q1 = qz16(ps1[(size_t)e * 3 + 1]);
            unsigned q2 = qz16(ps1[(size_t)e * 3 + 2]);
            pay1[p] = make_uint2(q0 | (q1 << 16), q2 | ((unsigned)ei1[e] << 16));
        } else if (g < (long long)E1 + E2) {
            int e = (int)(g - E1); lvl = 2;
            int dst = ei2[E2 + e];
            int pos = atomicAdd(&cur[SB1 + dst], 1);
            pdpos = row2[dst] + pos;
            unsigned q0 = qz16(ps2[(size_t)e * 3]);
            unsigned q1 = qz16(ps2[(size_t)e * 3 + 1]);
            unsigned q2 = qz16(ps2[(size_t)e * 3 + 2]);
            vq = make_uint2(q0 | (q1 << 16), q2 | ((unsigned)ei2[e] << 16));
            lidx = (int)(((q0 >> 14) << 4) | ((q1 >> 14) << 2) | (q2 >> 14));
            myrank = atomicAdd(&lcnt[lidx], 1);
        } else if (g < Etot) {
            int e = (int)(g - E1 - E2); lvl = 3;
            int dst = ei3[E3 + e];
            int pos = atomicAdd(&cur[SB2 + dst], 1);
            pdpos = row3[dst] + pos;
            unsigned q0 = qz16(ps3[(size_t)e * 3]);
            unsigned q1 = qz16(ps3[(size_t)e * 3 + 1]);
            unsigned q2 = qz16(ps3[(size_t)e * 3 + 2]);
            vq = make_uint2(q0 | (q1 << 16), q2 | ((unsigned)ei3[e] << 16));
            lidx = 64 + (int)(((q0 >> 14) << 4) | ((q1 >> 14) << 2) | (q2 >> 14));
            myrank = atomicAdd(&lcnt[lidx], 1);
        } else if (g < Etot + N0c) {
            int i = (int)(g - Etot);
            int b = cl0[i];
            int pos = atomicAdd(&cur[SB3 + b], 1);
            mem0[crow0[b] + pos] = i;
        } else if (g < Etot + N0c + N1c) {
            int i = (int)(g - Etot - N0c);
            int b = cl1[i];
            int pos = atomicAdd(&cur[SB4 + b], 1);
            mem1[crow1[b] + pos] = i;
        } else if (g < Etot + N0c + N1c + N2c) {
            int i = (int)(g - Etot - N0c - N1c);
            int b = cl2[i];
            int pos = atomicAdd(&cur[SB5 + b], 1);
            mem2[crow2[b] + pos] = i;
        } else {
            int i = (int)(g - Etot - N0c - N1c - N2c);
            int b = cl3[i];
            int pos = atomicAdd(&cur[SB6 + b], 1);
            mem3[crow3[b] + pos] = i;
        }
    }
    __syncthreads();
    if (t < 128) lbase[t] = (lcnt[t] > 0) ? atomicAdd(&ccur[t], lcnt[t]) : 0;
    __syncthreads();
    if (lidx >= 0) {
        int slot = coff[lidx] + lbase[lidx] + myrank;
        if (lvl == 2) { vpay2[slot] = vq; dpos2[slot] = pdpos; }
        else          { vpay3[slot] = vq; dpos3[slot] = pdpos; }
    }
}

// ---------- pooling ----------

__global__ void pool1ch_kernel(const float* __restrict__ in, const int* __restrict__ crow,
                               const int* __restrict__ mem, float* __restrict__ out, int n) {
    int nd = blockIdx.x * blockDim.x + threadIdx.x;
    if (nd >= n) return;
    int beg = crow[nd], end = crow[nd + 1];
    float v = -INFINITY;
    for (int p = beg; p < end; p++) v = fmaxf(v, in[mem[p]]);
    out[nd] = (beg == end) ? 0.0f : v;
}

__global__ void pool32ch_kernel(const float* __restrict__ in, const int* __restrict__ crow,
                                const int* __restrict__ mem, float* __restrict__ out, int n) {
    int tid = blockIdx.x * blockDim.x + threadIdx.x;
    int nd = tid >> 5, o = tid & 31;
    if (nd >= n) return;
    int beg = crow[nd], end = crow[nd + 1];
    float v = -INFINITY;
    for (int p = beg; p < end; p++) v = fmaxf(v, in[(size_t)mem[p] * 32 + o]);
    out[(size_t)nd * 32 + o] = (beg == end) ? 0.0f : v;
}

// ---------- cell conv via MFMA fp16, quantized payload ----------

__global__ __launch_bounds__(256, 4) void conv_cell_mfma(
        const float* __restrict__ x, const uint2* __restrict__ vpay, const int* __restrict__ dposA,
        const int* __restrict__ blockcell, const _Float16* __restrict__ WT,
        _Float16* __restrict__ y, int E) {
    __shared__ _Float16 Wl[8 * 1024];   // [c][o][i]  16 KB
    __shared__ _Float16 xh[256 * 32];   // [e][i]     16 KB
    __shared__ uint4 wcl[256];          // w8 per edge  4 KB
    __shared__ int dinfo[256];

    int cell = blockcell[blockIdx.x];
    if (cell < 0) return;   // fully-padded trailing block

    int t = threadIdx.x;
    int base = blockIdx.x * 256;
    uint2 vq = vpay[base + t];
    int d = dposA[base + t];
    dinfo[t] = d;
    int src = (d < 0) ? 0 : (int)(vq.y >> 16);

    // per-edge corner weights from quantized pseudo
    {
        const float inv = 1.0f / 16384.0f;
        float fx = (float)(vq.x & 16383u) * inv;
        float fy = (float)((vq.x >> 16) & 16383u) * inv;
        float fz = (float)(vq.y & 16383u) * inv;
        float gx0 = 1.0f - fx, gy0 = 1.0f - fy, gz0 = 1.0f - fz;
        wpack_u pk;
        pk.h[0] = (_Float16)(gx0 * gy0 * gz0);
        pk.h[1] = (_Float16)(fx  * gy0 * gz0);
        pk.h[2] = (_Float16)(gx0 * fy  * gz0);
        pk.h[3] = (_Float16)(fx  * fy  * gz0);
        pk.h[4] = (_Float16)(gx0 * gy0 * fz );
        pk.h[5] = (_Float16)(fx  * gy0 * fz );
        pk.h[6] = (_Float16)(gx0 * fy  * fz );
        pk.h[7] = (_Float16)(fx  * fy  * fz );
        wcl[t] = pk.u;
    }

    // stage W (fp16, already o-major) for this cell's 8 corners
    {
        int kx = cell >> 4, ky = (cell >> 2) & 3, kz = cell & 3;
        int c = t >> 5, o = t & 31;
        int id0 = kx + ((c >> 0) & 1);
        int id1 = ky + ((c >> 1) & 1);
        int id2 = kz + ((c >> 2) & 1);
        int flat = (id0 * KS + id1) * KS + id2;
        const uint4* s4 = (const uint4*)(WT + (size_t)flat * 1024 + o * 32);
        uint4* dst = (uint4*)&Wl[c * 1024 + o * 32];
        #pragma unroll
        for (int j = 0; j < 4; j++) dst[j] = s4[j];
    }

    // stage x (fp16)
    {
        const float4* xr = (const float4*)(x + (size_t)src * 32);
        _Float16* xd = &xh[t * 32];
        #pragma unroll
        for (int j = 0; j < 8; j++) {
            float4 v = xr[j];
            xd[j * 4 + 0] = (_Float16)v.x;
            xd[j * 4 + 1] = (_Float16)v.y;
            xd[j * 4 + 2] = (_Float16)v.z;
            xd[j * 4 + 3] = (_Float16)v.w;
        }
    }
    __syncthreads();

    int wv = t >> 6, lane = t & 63;
    int quad = lane >> 4, mrow = lane & 15;
    const _Float16* whal = (const _Float16*)wcl;

    hf8_t xf[4];
    #pragma unroll
    for (int mt = 0; mt < 4; mt++) {
        int em = wv * 64 + mt * 16 + mrow;
        xf[mt] = *(const hf8_t*)&xh[em * 32 + quad * 8];
    }

    f32x4_t acc[4][2];
    #pragma unroll
    for (int mt = 0; mt < 4; mt++) {
        acc[mt][0] = (f32x4_t)0.0f;
        acc[mt][1] = (f32x4_t)0.0f;
    }

    #pragma unroll
    for (int c = 0; c < 8; c++) {
        hf8_t b0 = *(const hf8_t*)&Wl[c * 1024 + mrow * 32 + quad * 8];
        hf8_t b1 = *(const hf8_t*)&Wl[c * 1024 + (16 + mrow) * 32 + quad * 8];
        #pragma unroll
        for (int mt = 0; mt < 4; mt++) {
            int em = wv * 64 + mt * 16 + mrow;
            _Float16 wcv = whal[em * 8 + c];
            hf8_t af = xf[mt] * wcv;
            acc[mt][0] = __builtin_amdgcn_mfma_f32_16x16x32_f16(af, b0, acc[mt][0], 0, 0, 0);
            acc[mt][1] = __builtin_amdgcn_mfma_f32_16x16x32_f16(af, b1, acc[mt][1], 0, 0, 0);
        }
    }

    #pragma unroll
    for (int mt = 0; mt < 4; mt++) {
        #pragma unroll
        for (int reg = 0; reg < 4; reg++) {
            int el = wv * 64 + mt * 16 + quad * 4 + reg;
            int dd = dinfo[el];
            if (dd >= 0) {
                y[(size_t)dd * 32 + mrow]      = (_Float16)acc[mt][0][reg];
                y[(size_t)dd * 32 + 16 + mrow] = (_Float16)acc[mt][1][reg];
            }
        }
    }
}

// ---------- gather finalize ----------

__global__ void gather_fin_kernel(const _Float16* __restrict__ y, const int* __restrict__ row_start,
                                  const float* __restrict__ x, const float* __restrict__ root,
                                  const float* __restrict__ b, float* __restrict__ out, int n) {
    int tid = blockIdx.x * blockDim.x + threadIdx.x;
    int nd = tid >> 5, o = tid & 31;
    if (nd >= n) return;
    int beg = row_start[nd], end = row_start[nd + 1];
    float acc = 0.0f;
    for (int p = beg; p < end; p++) acc += (float)y[(size_t)p * 32 + o];
    acc /= fmaxf((float)(end - beg), 1.0f);
    const float* __restrict__ xr = x + (size_t)nd * 32;
    float rsum = 0.0f;
    #pragma unroll
    for (int i = 0; i < 32; i++) rsum += xr[i] * root[i * 32 + o];
    float v = acc + rsum + b[o];
    out[(size_t)nd * 32 + o] = (v > 0.0f) ? v : expm1f(v);
}

// ---------- conv1 (cin=1) node-centric: 8B quantized payload, o-major W1 in LDS ----------

__global__ __launch_bounds__(256) void conv1_node_kernel(
        const float* __restrict__ x, const uint2* __restrict__ pay1,
        const int* __restrict__ row_start, const float* __restrict__ W,
        const float* __restrict__ root, const float* __restrict__ b,
        float* __restrict__ out, int n) {
    __shared__ float Wl[32 * K3];   // [o][bin], stride 125 -> bank-permuted, 15.6 KB
    for (int i = threadIdx.x; i < K3 * 32; i += 256) {
        int bin = i >> 5, o = i & 31;
        Wl[o * K3 + bin] = W[i];
    }
    __syncthreads();

    int tid = blockIdx.x * blockDim.x + threadIdx.x;
    int nd = tid >> 5, o = tid & 31;
    if (nd >= n) return;
    int beg = row_start[nd], end = row_start[nd + 1];
    const float inv = 1.0f / 16384.0f;
    const float* Wo = &Wl[o * K3];
    float acc = 0.0f;
    for (int idx = beg; idx < end; idx++) {
        uint2 pq = pay1[idx];
        int k0 = (int)((pq.x & 0xFFFFu) >> 14);
        int k1 = (int)(pq.x >> 30);
        int k2 = (int)((pq.y & 0xFFFFu) >> 14);
        float fx = (float)(pq.x & 16383u) * inv;
        float fy = (float)((pq.x >> 16) & 16383u) * inv;
        float fz = (float)(pq.y & 16383u) * inv;
        int src = (int)(pq.y >> 16);
        int f0 = (k0 * 5 + k1) * 5 + k2;
        const float* Wf = Wo + f0;
        float gx0 = 1.0f - fx, gy0 = 1.0f - fy, gz0 = 1.0f - fz;
        float a00 = gx0 * Wf[0] + fx * Wf[25];
        float a01 = gx0 * Wf[5] + fx * Wf[30];
        float a10 = gx0 * Wf[1] + fx * Wf[26];
        float a11 = gx0 * Wf[6] + fx * Wf[31];
        float s = gz0 * (gy0 * a00 + fy * a01) + fz * (gy0 * a10 + fy * a11);
        acc += x[src] * s;
    }
    float v = acc / fmaxf((float)(end - beg), 1.0f) + x[nd] * root[o] + b[o];
    out[(size_t)nd * 32 + o] = (v > 0.0f) ? v : expm1f(v);
}

// ---------- FC + log_softmax ----------

__global__ void fc_kernel(const float* __restrict__ h, const float* __restrict__ fw,
                          const float* __restrict__ fb, float* __restrict__ out, int B) {
    int tid = blockIdx.x * blockDim.x + threadIdx.x;
    int row = tid >> 5, lane = tid & 31;
    if (row >= B) return;
    const float* hb = h + (size_t)row * 256;
    float lg[10];
    #pragma unroll
    for (int j = 0; j < 10; j++) lg[j] = 0.0f;
    for (int tt = lane; tt < 256; tt += 32) {
        float hv = hb[tt];
        const float* fr = fw + tt * 10;
        #pragma unroll
        for (int j = 0; j < 10; j++) lg[j] += hv * fr[j];
    }
    #pragma unroll
    for (int off = 16; off > 0; off >>= 1)
        #pragma unroll
        for (int j = 0; j < 10; j++) lg[j] += __shfl_down(lg[j], off, 32);
    if (lane == 0) {
        #pragma unroll
        for (int j = 0; j < 10; j++) lg[j] += fb[j];
        float m = lg[0];
        #pragma unroll
        for (int j = 1; j < 10; j++) m = fmaxf(m, lg[j]);
        float s = 0.0f;
        #pragma unroll
        for (int j = 0; j < 10; j++) s += expf(lg[j] - m);
        float lse = logf(s) + m;
        #pragma unroll
        for (int j = 0; j < 10; j++) out[(size_t)row * 10 + j] = lg[j] - lse;
    }
}

// ---------- launch ----------

static inline int cdiv(long long a, int b) { return (int)((a + b - 1) / b); }

extern "C" void kernel_launch(void* const* d_in, const int* in_sizes, int n_in,
                              void* d_out, int out_size, void* d_ws, size_t ws_size,
                              hipStream_t stream) {
    const int N1 = N1c, N2 = N2c, N3 = N3c, B8 = B8c;
    const int B = B8 / 8;

    const float* x      = (const float*)d_in[0];
    const int*   cl0    = (const int*)d_in[1];
    const int*   ei1    = (const int*)d_in[2];
    const float* ps1    = (const float*)d_in[3];
    const int*   cl1    = (const int*)d_in[4];
    const int*   ei2    = (const int*)d_in[5];
    const float* ps2    = (const float*)d_in[6];
    const int*   cl2    = (const int*)d_in[7];
    const int*   ei3    = (const int*)d_in[8];
    const float* ps3    = (const float*)d_in[9];
    const int*   cl3    = (const int*)d_in[10];
    const float* W1     = (const float*)d_in[11];
    const float* root1  = (const float*)d_in[12];
    const float* b1     = (const float*)d_in[13];
    const float* W2     = (const float*)d_in[14];
    const float* root2  = (const float*)d_in[15];
    const float* b2     = (const float*)d_in[16];
    const float* W3     = (const float*)d_in[17];
    const float* root3  = (const float*)d_in[18];
    const float* b3     = (const float*)d_in[19];
    const float* fc_w   = (const float*)d_in[20];
    const float* fc_b   = (const float*)d_in[21];
    float* out = (float*)d_out;

    const int E1 = in_sizes[2] / 2;
    const int E2 = in_sizes[5] / 2;
    const int E3 = in_sizes[8] / 2;
    const long long Etot = (long long)E1 + E2 + E3;
    const long long IT = Etot + N0c + N1c + N2c + N3c;

    const int grid2 = cdiv((long long)E2 + 64 * 255, 256);
    const int grid3 = cdiv((long long)E3 + 64 * 255, 256);
    const int pad2 = grid2 * 256, pad3 = grid3 * 256;
    const int ymax = (E2 > E3 ? E2 : E3);

    // ---- workspace layout ----
    char* wp = (char*)d_ws;
    float* p0  = (float*)wp;               wp += (size_t)N1 * 4;
    float* h1  = (float*)wp;               wp += (size_t)N1 * 32 * 4;
    float* p1  = (float*)wp;               wp += (size_t)N2 * 32 * 4;
    float* h2  = (float*)wp;               wp += (size_t)N2 * 32 * 4;
    float* p2  = (float*)wp;               wp += (size_t)N3 * 32 * 4;
    float* h3  = (float*)wp;               wp += (size_t)N3 * 32 * 4;
    float* p3  = (float*)wp;               wp += (size_t)B8 * 32 * 4;
    // zeroed-together region: [cnt | cur | ccnt | ccur]
    int* cnt   = (int*)wp;                 wp += (size_t)SBT * 4;
    int* cur   = (int*)wp;                 wp += (size_t)SBT * 4;
    int* ccnt  = (int*)wp;                 wp += 128 * 4;
    int* ccur  = (int*)wp;                 wp += 128 * 4;
    size_t zero_bytes = (size_t)(wp - (char*)cnt);
    int* coff  = (int*)wp;                 wp += 128 * 4;
    int* rows  = (int*)wp;                 wp += (size_t)(SBT + 7) * 4;
    int* bsum  = (int*)wp;                 wp += 256 * 4;
    int* mem0  = (int*)wp;                 wp += (size_t)N0c * 4;
    int* mem1  = (int*)wp;                 wp += (size_t)N1c * 4;
    int* mem2  = (int*)wp;                 wp += (size_t)N2c * 4;
    int* mem3  = (int*)wp;                 wp += (size_t)N3c * 4;
    uint2* pay1  = (uint2*)wp;             wp += (size_t)E1 * 8;
    uint2* vpay2 = (uint2*)wp;             wp += (size_t)pad2 * 8;
    uint2* vpay3 = (uint2*)wp;             wp += (size_t)pad3 * 8;
    int* dpos2 = (int*)wp;                 wp += (size_t)pad2 * 4;
    int* dpos3 = (int*)wp;                 wp += (size_t)pad3 * 4;   // contiguous with dpos2
    int* blockcell2 = (int*)wp;            wp += (size_t)grid2 * 4;
    int* blockcell3 = (int*)wp;            wp += (size_t)grid3 * 4;  // contiguous with blockcell2
    _Float16* WT2 = (_Float16*)wp;         wp += (size_t)K3 * 1024 * 2;
    _Float16* WT3 = (_Float16*)wp;         wp += (size_t)K3 * 1024 * 2;
    _Float16* yh = (_Float16*)wp;          // ymax*32 halves

    int* row1  = rows;
    int* row2  = rows + SB1 + 1;
    int* row3  = rows + SB2 + 2;
    int* crow0 = rows + SB3 + 3;
    int* crow1 = rows + SB4 + 4;
    int* crow2 = rows + SB5 + 5;
    int* crow3 = rows + SB6 + 6;

    const int T = 256;
    const int nb = SBT / 1024;   // 240

    // ========== indexing phase (input-only) ==========
    hipMemsetAsync(cnt, 0, zero_bytes, stream);
    hipMemsetAsync(dpos2, 0xFF, ((size_t)pad2 + pad3) * 4, stream);
    hipMemsetAsync(blockcell2, 0xFF, ((size_t)grid2 + grid3) * 4, stream);
    wtrans_kernel<<<cdiv((long long)K3 * 1024, T), T, 0, stream>>>(W2, W3, WT2, WT3);
    index_hist_all<<<cdiv(IT, 1024), 1024, 0, stream>>>(
        ei1, ei2, ei3, ps2, ps3, cl0, cl1, cl2, cl3, cnt, ccnt, E1, E2, E3);
    scan_blocks_kernel<<<nb, 1024, 0, stream>>>(cnt, rows, bsum);
    scan_sums_kernel<<<1, 256, 0, stream>>>(bsum, ccnt, coff, blockcell2, blockcell3, nb);
    scan_add_kernel<<<nb, 1024, 0, stream>>>(rows, bsum, E1, E2, E3);
    scatter_all<<<cdiv(IT, 1024), 1024, 0, stream>>>(
        ei1, ei2, ei3, ps1, ps2, ps3, cl0, cl1, cl2, cl3, cur, rows,
        pay1, vpay2, dpos2, vpay3, dpos3,
        mem0, mem1, mem2, mem3, ccur, coff, E1, E2, E3);

    // ========== pipeline ==========
    pool1ch_kernel<<<cdiv(N1, T), T, 0, stream>>>(x, crow0, mem0, p0, N1);

    conv1_node_kernel<<<cdiv((long long)N1 * 32, T), T, 0, stream>>>(
        p0, pay1, row1, W1, root1, b1, h1, N1);

    pool32ch_kernel<<<cdiv((long long)N2 * 32, T), T, 0, stream>>>(h1, crow1, mem1, p1, N2);

    conv_cell_mfma<<<grid2, 256, 0, stream>>>(p1, vpay2, dpos2, blockcell2, WT2, yh, E2);
    gather_fin_kernel<<<cdiv((long long)N2 * 32, T), T, 0, stream>>>(
        yh, row2, p1, root2, b2, h2, N2);

    pool32ch_kernel<<<cdiv((long long)N3 * 32, T), T, 0, stream>>>(h2, crow2, mem2, p2, N3);

    conv_cell_mfma<<<grid3, 256, 0, stream>>>(p2, vpay3, dpos3, blockcell3, WT3, yh, E3);
    gather_fin_kernel<<<cdiv((long long)N3 * 32, T), T, 0, stream>>>(
        yh, row3, p2, root3, b3, h3, N3);

    pool32ch_kernel<<<cdiv((long long)B8 * 32, T), T, 0, stream>>>(h3, crow3, mem3, p3, B8);

    fc_kernel<<<cdiv((long long)B * 32, T), T, 0, stream>>>(p3, fc_w, fc_b, out, B);
}

// Round 10
// 703.525 us; speedup vs baseline: 7.3944x; 1.0526x over previous
//
#include <hip/hip_runtime.h>
#include <math.h>

#define KS 5
#define K3 125

// problem sizes (fixed)
#define N0c 131072
#define N1c 65536
#define N2c 32768
#define N3c 16384
#define B8c 16384

typedef _Float16 hf8_t __attribute__((ext_vector_type(8)));
typedef float f32x4_t __attribute__((ext_vector_type(4)));

union wpack_u { _Float16 h[8]; uint4 u; };

// ---------- helpers ----------
// quantized pseudo: q = rint(ps*65536) clamped to 65535; k0 = q>>14 (0..3), f = (q&16383)/16384.

__device__ __forceinline__ unsigned qz16(float ps) {
    float t = rintf(ps * 65536.0f);
    t = fminf(fmaxf(t, 0.0f), 65535.0f);
    return (unsigned)t;
}

__device__ __forceinline__ int cell_of_q(const float* __restrict__ pseudo, int e) {
    unsigned q0 = qz16(pseudo[(size_t)e * 3]);
    unsigned q1 = qz16(pseudo[(size_t)e * 3 + 1]);
    unsigned q2 = qz16(pseudo[(size_t)e * 3 + 2]);
    return (int)(((q0 >> 14) << 4) | ((q1 >> 14) << 2) | (q2 >> 14));
}

// bin-space segment boundaries (bins = dst1,dst2,dst3,cl0,cl1,cl2,cl3)
#define SB1 65536
#define SB2 98304
#define SB3 114688
#define SB4 180224
#define SB5 212992
#define SB6 229376
#define SBT 245760

__device__ __forceinline__ int seg_of(int i) {
    return (i < SB1) ? 0 : (i < SB2) ? 1 : (i < SB3) ? 2 :
           (i < SB4) ? 3 : (i < SB5) ? 4 : (i < SB6) ? 5 : 6;
}

// ---------- W transpose + fp16: [bin][i][o] f32 -> [bin][o][i] fp16 ----------

__global__ void wtrans_kernel(const float* __restrict__ W2, const float* __restrict__ W3,
                              _Float16* __restrict__ WT2, _Float16* __restrict__ WT3) {
    int tid = blockIdx.x * blockDim.x + threadIdx.x;
    const int total = K3 * 1024;
    if (tid >= total) return;
    int bin = tid >> 10, r = tid & 1023, i = r >> 5, o = r & 31;
    WT2[bin * 1024 + o * 32 + i] = (_Float16)W2[tid];
    WT3[bin * 1024 + o * 32 + i] = (_Float16)W3[tid];
}

// ---------- fused indexing ----------

__global__ void index_hist_all(const int* __restrict__ ei1, const int* __restrict__ ei2,
                               const int* __restrict__ ei3,
                               const float* __restrict__ ps2, const float* __restrict__ ps3,
                               const int* __restrict__ cl0, const int* __restrict__ cl1,
                               const int* __restrict__ cl2, const int* __restrict__ cl3,
                               int* __restrict__ cnt, int* __restrict__ ccnt,
                               int E1, int E2, int E3) {
    __shared__ int lcnt[128];
    int t = threadIdx.x;
    if (t < 128) lcnt[t] = 0;
    __syncthreads();
    long long g = (long long)blockIdx.x * blockDim.x + t;
    long long Etot = (long long)E1 + E2 + E3;
    long long IT = Etot + N0c + N1c + N2c + N3c;
    if (g < IT) {
        if (g < E1) {
            int e = (int)g;
            atomicAdd(&cnt[ei1[E1 + e]], 1);
        } else if (g < (long long)E1 + E2) {
            int e = (int)(g - E1);
            atomicAdd(&cnt[SB1 + ei2[E2 + e]], 1);
            atomicAdd(&lcnt[cell_of_q(ps2, e)], 1);
        } else if (g < Etot) {
            int e = (int)(g - E1 - E2);
            atomicAdd(&cnt[SB2 + ei3[E3 + e]], 1);
            atomicAdd(&lcnt[64 + cell_of_q(ps3, e)], 1);
        } else if (g < Etot + N0c) {
            int i = (int)(g - Etot);
            atomicAdd(&cnt[SB3 + cl0[i]], 1);
        } else if (g < Etot + N0c + N1c) {
            int i = (int)(g - Etot - N0c);
            atomicAdd(&cnt[SB4 + cl1[i]], 1);
        } else if (g < Etot + N0c + N1c + N2c) {
            int i = (int)(g - Etot - N0c - N1c);
            atomicAdd(&cnt[SB5 + cl2[i]], 1);
        } else {
            int i = (int)(g - Etot - N0c - N1c - N2c);
            atomicAdd(&cnt[SB6 + cl3[i]], 1);
        }
    }
    __syncthreads();
    if (t < 128 && lcnt[t] > 0) atomicAdd(&ccnt[t], lcnt[t]);
}

// ---------- hierarchical segmented scan ----------

__global__ void scan_blocks_kernel(const int* __restrict__ cnt, int* __restrict__ rows,
                                   int* __restrict__ bsum) {
    __shared__ int sdata[1024];
    int t = threadIdx.x;
    int i = blockIdx.x * 1024 + t;
    int v = cnt[i];
    sdata[t] = v;
    __syncthreads();
    for (int off = 1; off < 1024; off <<= 1) {
        int add = (t >= off) ? sdata[t - off] : 0;
        __syncthreads();
        sdata[t] += add;
        __syncthreads();
    }
    rows[i + seg_of(i)] = sdata[t] - v;
    if (t == 1023) bsum[blockIdx.x] = sdata[1023];
}

__global__ void scan_sums_kernel(int* __restrict__ bsum, const int* __restrict__ ccnt,
                                 int* __restrict__ coff, int* __restrict__ blockcell2,
                                 int* __restrict__ blockcell3, int nb) {
    __shared__ int sdata[256];
    __shared__ int sseg[256];
    int t = threadIdx.x;
    int v = (t < nb) ? bsum[t] : 0;
    int seg = (t < 64) ? 0 : (t < 96) ? 1 : (t < 112) ? 2 :
              (t < 176) ? 3 : (t < 208) ? 4 : (t < 224) ? 5 : 6;
    sdata[t] = v; sseg[t] = seg;
    __syncthreads();
    for (int off = 1; off < 256; off <<= 1) {
        int add = (t >= off && sseg[t - off] == seg) ? sdata[t - off] : 0;
        __syncthreads();
        sdata[t] += add;
        __syncthreads();
    }
    if (t < nb) bsum[t] = sdata[t] - v;
    if (t == 0) {
        int acc = 0;
        for (int c = 0; c < 64; c++) {
            coff[c] = acc;
            int nbk = (ccnt[c] + 255) >> 8;
            for (int k = 0; k < nbk; k++) blockcell2[(acc >> 8) + k] = c;
            acc += nbk << 8;
        }
    }
    if (t == 1) {
        int acc = 0;
        for (int c = 0; c < 64; c++) {
            coff[64 + c] = acc;
            int nbk = (ccnt[64 + c] + 255) >> 8;
            for (int k = 0; k < nbk; k++) blockcell3[(acc >> 8) + k] = c;
            acc += nbk << 8;
        }
    }
}

__global__ void scan_add_kernel(int* __restrict__ rows, const int* __restrict__ bsum,
                                int E1, int E2, int E3) {
    int t = threadIdx.x;
    int i = blockIdx.x * 1024 + t;
    rows[i + seg_of(i)] += bsum[blockIdx.x];
    if (blockIdx.x == 0) {
        if (t == 0) rows[SB1 + 0] = E1;
        if (t == 1) rows[SB2 + 1] = E2;
        if (t == 2) rows[SB3 + 2] = E3;
        if (t == 3) rows[SB4 + 3] = N0c;
        if (t == 4) rows[SB5 + 4] = N1c;
        if (t == 5) rows[SB6 + 5] = N2c;
        if (t == 6) rows[SBT + 6] = N3c;
    }
}

// ---------- fused scatter ----------
// lvl1 pass 1: bucket by dst>>9 (128 buckets, bases = row1[bkt*512]); write 16B qtmp record
//              {q0|q1<<16, q2|dst<<16, src, 0} in coalesced per-(block,bucket) runs.
// lvl2/3: vpay(8B)+dpos(4B) at padded cell-bucket slot (coalesced runs).
// LDS agg domains: [0,128)=lvl1 buckets, [128,192)=lvl2 cells, [192,256)=lvl3 cells.

__global__ void scatter_all(const int* __restrict__ ei1, const int* __restrict__ ei2,
                            const int* __restrict__ ei3,
                            const float* __restrict__ ps1, const float* __restrict__ ps2,
                            const float* __restrict__ ps3,
                            const int* __restrict__ cl0, const int* __restrict__ cl1,
                            const int* __restrict__ cl2, const int* __restrict__ cl3,
                            int* __restrict__ cur, const int* __restrict__ rows,
                            uint4* __restrict__ qtmp,
                            uint2* __restrict__ vpay2, int* __restrict__ dpos2,
                            uint2* __restrict__ vpay3, int* __restrict__ dpos3,
                            int* __restrict__ mem0, int* __restrict__ mem1,
                            int* __restrict__ mem2, int* __restrict__ mem3,
                            int* __restrict__ ccur, const int* __restrict__ coff,
                            int E1, int E2, int E3) {
    const int* row1  = rows;
    const int* row2  = rows + SB1 + 1;
    const int* row3  = rows + SB2 + 2;
    const int* crow0 = rows + SB3 + 3;
    const int* crow1 = rows + SB4 + 4;
    const int* crow2 = rows + SB5 + 5;
    const int* crow3 = rows + SB6 + 6;

    __shared__ int lcnt[256];
    __shared__ int lbase[256];
    int t = threadIdx.x;
    if (t < 256) lcnt[t] = 0;
    __syncthreads();
    long long g = (long long)blockIdx.x * blockDim.x + t;
    long long Etot = (long long)E1 + E2 + E3;
    long long IT = Etot + N0c + N1c + N2c + N3c;
    int lidx = -1, myrank = 0, lvl = 0, pdpos = 0;
    uint2 vq;
    uint4 rec;
    if (g < IT) {
        if (g < E1) {
            int e = (int)g; lvl = 1;
            int dst = ei1[E1 + e];
            unsigned q0 = qz16(ps1[(size_t)e * 3]);
            unsigned q1 = qz16(ps1[(size_t)e * 3 + 1]);
            unsigned q2 = qz16(ps1[(size_t)e * 3 + 2]);
            rec = make_uint4(q0 | (q1 << 16), q2 | ((unsigned)dst << 16), (unsigned)ei1[e], 0u);
            lidx = dst >> 9;                     // 128 buckets of 512 dst
            myrank = atomicAdd(&lcnt[lidx], 1);
        } else if (g < (long long)E1 + E2) {
            int e = (int)(g - E1); lvl = 2;
            int dst = ei2[E2 + e];
            int pos = atomicAdd(&cur[SB1 + dst], 1);
            pdpos = row2[dst] + pos;
            unsigned q0 = qz16(ps2[(size_t)e * 3]);
            unsigned q1 = qz16(ps2[(size_t)e * 3 + 1]);
            unsigned q2 = qz16(ps2[(size_t)e * 3 + 2]);
            vq = make_uint2(q0 | (q1 << 16), q2 | ((unsigned)ei2[e] << 16));
            lidx = 128 + (int)(((q0 >> 14) << 4) | ((q1 >> 14) << 2) | (q2 >> 14));
            myrank = atomicAdd(&lcnt[lidx], 1);
        } else if (g < Etot) {
            int e = (int)(g - E1 - E2); lvl = 3;
            int dst = ei3[E3 + e];
            int pos = atomicAdd(&cur[SB2 + dst], 1);
            pdpos = row3[dst] + pos;
            unsigned q0 = qz16(ps3[(size_t)e * 3]);
            unsigned q1 = qz16(ps3[(size_t)e * 3 + 1]);
            unsigned q2 = qz16(ps3[(size_t)e * 3 + 2]);
            vq = make_uint2(q0 | (q1 << 16), q2 | ((unsigned)ei3[e] << 16));
            lidx = 192 + (int)(((q0 >> 14) << 4) | ((q1 >> 14) << 2) | (q2 >> 14));
            myrank = atomicAdd(&lcnt[lidx], 1);
        } else if (g < Etot + N0c) {
            int i = (int)(g - Etot);
            int b = cl0[i];
            int pos = atomicAdd(&cur[SB3 + b], 1);
            mem0[crow0[b] + pos] = i;
        } else if (g < Etot + N0c + N1c) {
            int i = (int)(g - Etot - N0c);
            int b = cl1[i];
            int pos = atomicAdd(&cur[SB4 + b], 1);
            mem1[crow1[b] + pos] = i;
        } else if (g < Etot + N0c + N1c + N2c) {
            int i = (int)(g - Etot - N0c - N1c);
            int b = cl2[i];
            int pos = atomicAdd(&cur[SB5 + b], 1);
            mem2[crow2[b] + pos] = i;
        } else {
            int i = (int)(g - Etot - N0c - N1c - N2c);
            int b = cl3[i];
            int pos = atomicAdd(&cur[SB6 + b], 1);
            mem3[crow3[b] + pos] = i;
        }
    }
    __syncthreads();
    if (t < 256) lbase[t] = (lcnt[t] > 0) ? atomicAdd(&ccur[t], lcnt[t]) : 0;
    __syncthreads();
    if (lidx >= 0) {
        if (lvl == 1) {
            int slot = row1[lidx << 9] + lbase[lidx] + myrank;
            qtmp[slot] = rec;
        } else if (lvl == 2) {
            int slot = coff[lidx - 128] + lbase[lidx] + myrank;
            vpay2[slot] = vq; dpos2[slot] = pdpos;
        } else {
            int slot = coff[lidx - 128] + lbase[lidx] + myrank;   // lidx-128 in [64,128)
            vpay3[slot] = vq; dpos3[slot] = pdpos;
        }
    }
}

// ---------- lvl1 pass 2: order bucket by dst via LDS cursors; single block per bucket ----------

__global__ __launch_bounds__(1024) void pay1_pass2(const uint4* __restrict__ qtmp,
                                                   const int* __restrict__ rows,
                                                   uint2* __restrict__ pay1) {
    const int* row1 = rows;
    __shared__ int lcur[512];
    __shared__ int lrow[513];
    int t = threadIdx.x;
    int bkt = blockIdx.x;
    if (t < 512) lcur[t] = 0;
    if (t < 513) lrow[t] = row1[(bkt << 9) + t];
    __syncthreads();
    int start = lrow[0], end = lrow[512];
    for (int i = start + t; i < end; i += 1024) {
        uint4 rec = qtmp[i];
        int dst9 = (int)(rec.y >> 16) & 511;
        int pos = atomicAdd(&lcur[dst9], 1);
        pay1[lrow[dst9] + pos] = make_uint2(rec.x, (rec.y & 0xFFFFu) | (rec.z << 16));
    }
}

// ---------- pooling ----------

__global__ void pool1ch_kernel(const float* __restrict__ in, const int* __restrict__ crow,
                               const int* __restrict__ mem, float* __restrict__ out, int n) {
    int nd = blockIdx.x * blockDim.x + threadIdx.x;
    if (nd >= n) return;
    int beg = crow[nd], end = crow[nd + 1];
    float v = -INFINITY;
    for (int p = beg; p < end; p++) v = fmaxf(v, in[mem[p]]);
    out[nd] = (beg == end) ? 0.0f : v;
}

__global__ void pool32ch_kernel(const float* __restrict__ in, const int* __restrict__ crow,
                                const int* __restrict__ mem, float* __restrict__ out, int n) {
    int tid = blockIdx.x * blockDim.x + threadIdx.x;
    int nd = tid >> 5, o = tid & 31;
    if (nd >= n) return;
    int beg = crow[nd], end = crow[nd + 1];
    float v = -INFINITY;
    for (int p = beg; p < end; p++) v = fmaxf(v, in[(size_t)mem[p] * 32 + o]);
    out[(size_t)nd * 32 + o] = (beg == end) ? 0.0f : v;
}

// ---------- cell conv via MFMA fp16, quantized payload ----------

__global__ __launch_bounds__(256, 4) void conv_cell_mfma(
        const float* __restrict__ x, const uint2* __restrict__ vpay, const int* __restrict__ dposA,
        const int* __restrict__ blockcell, const _Float16* __restrict__ WT,
        _Float16* __restrict__ y, int E) {
    __shared__ _Float16 Wl[8 * 1024];   // [c][o][i]  16 KB
    __shared__ _Float16 xh[256 * 32];   // [e][i]     16 KB
    __shared__ uint4 wcl[256];          // w8 per edge  4 KB
    __shared__ int dinfo[256];

    int cell = blockcell[blockIdx.x];
    if (cell < 0) return;   // fully-padded trailing block

    int t = threadIdx.x;
    int base = blockIdx.x * 256;
    uint2 vq = vpay[base + t];
    int d = dposA[base + t];
    dinfo[t] = d;
    int src = (d < 0) ? 0 : (int)(vq.y >> 16);

    // per-edge corner weights from quantized pseudo
    {
        const float inv = 1.0f / 16384.0f;
        float fx = (float)(vq.x & 16383u) * inv;
        float fy = (float)((vq.x >> 16) & 16383u) * inv;
        float fz = (float)(vq.y & 16383u) * inv;
        float gx0 = 1.0f - fx, gy0 = 1.0f - fy, gz0 = 1.0f - fz;
        wpack_u pk;
        pk.h[0] = (_Float16)(gx0 * gy0 * gz0);
        pk.h[1] = (_Float16)(fx  * gy0 * gz0);
        pk.h[2] = (_Float16)(gx0 * fy  * gz0);
        pk.h[3] = (_Float16)(fx  * fy  * gz0);
        pk.h[4] = (_Float16)(gx0 * gy0 * fz );
        pk.h[5] = (_Float16)(fx  * gy0 * fz );
        pk.h[6] = (_Float16)(gx0 * fy  * fz );
        pk.h[7] = (_Float16)(fx  * fy  * fz );
        wcl[t] = pk.u;
    }

    // stage W (fp16, o-major) for this cell's 8 corners
    {
        int kx = cell >> 4, ky = (cell >> 2) & 3, kz = cell & 3;
        int c = t >> 5, o = t & 31;
        int id0 = kx + ((c >> 0) & 1);
        int id1 = ky + ((c >> 1) & 1);
        int id2 = kz + ((c >> 2) & 1);
        int flat = (id0 * KS + id1) * KS + id2;
        const uint4* s4 = (const uint4*)(WT + (size_t)flat * 1024 + o * 32);
        uint4* dst = (uint4*)&Wl[c * 1024 + o * 32];
        #pragma unroll
        for (int j = 0; j < 4; j++) dst[j] = s4[j];
    }

    // stage x (fp16)
    {
        const float4* xr = (const float4*)(x + (size_t)src * 32);
        _Float16* xd = &xh[t * 32];
        #pragma unroll
        for (int j = 0; j < 8; j++) {
            float4 v = xr[j];
            xd[j * 4 + 0] = (_Float16)v.x;
            xd[j * 4 + 1] = (_Float16)v.y;
            xd[j * 4 + 2] = (_Float16)v.z;
            xd[j * 4 + 3] = (_Float16)v.w;
        }
    }
    __syncthreads();

    int wv = t >> 6, lane = t & 63;
    int quad = lane >> 4, mrow = lane & 15;
    const _Float16* whal = (const _Float16*)wcl;

    hf8_t xf[4];
    #pragma unroll
    for (int mt = 0; mt < 4; mt++) {
        int em = wv * 64 + mt * 16 + mrow;
        xf[mt] = *(const hf8_t*)&xh[em * 32 + quad * 8];
    }

    f32x4_t acc[4][2];
    #pragma unroll
    for (int mt = 0; mt < 4; mt++) {
        acc[mt][0] = (f32x4_t)0.0f;
        acc[mt][1] = (f32x4_t)0.0f;
    }

    #pragma unroll
    for (int c = 0; c < 8; c++) {
        hf8_t b0 = *(const hf8_t*)&Wl[c * 1024 + mrow * 32 + quad * 8];
        hf8_t b1 = *(const hf8_t*)&Wl[c * 1024 + (16 + mrow) * 32 + quad * 8];
        #pragma unroll
        for (int mt = 0; mt < 4; mt++) {
            int em = wv * 64 + mt * 16 + mrow;
            _Float16 wcv = whal[em * 8 + c];
            hf8_t af = xf[mt] * wcv;
            acc[mt][0] = __builtin_amdgcn_mfma_f32_16x16x32_f16(af, b0, acc[mt][0], 0, 0, 0);
            acc[mt][1] = __builtin_amdgcn_mfma_f32_16x16x32_f16(af, b1, acc[mt][1], 0, 0, 0);
        }
    }

    #pragma unroll
    for (int mt = 0; mt < 4; mt++) {
        #pragma unroll
        for (int reg = 0; reg < 4; reg++) {
            int el = wv * 64 + mt * 16 + quad * 4 + reg;
            int dd = dinfo[el];
            if (dd >= 0) {
                y[(size_t)dd * 32 + mrow]      = (_Float16)acc[mt][0][reg];
                y[(size_t)dd * 32 + 16 + mrow] = (_Float16)acc[mt][1][reg];
            }
        }
    }
}

// ---------- gather finalize ----------

__global__ void gather_fin_kernel(const _Float16* __restrict__ y, const int* __restrict__ row_start,
                                  const float* __restrict__ x, const float* __restrict__ root,
                                  const float* __restrict__ b, float* __restrict__ out, int n) {
    int tid = blockIdx.x * blockDim.x + threadIdx.x;
    int nd = tid >> 5, o = tid & 31;
    if (nd >= n) return;
    int beg = row_start[nd], end = row_start[nd + 1];
    float acc = 0.0f;
    for (int p = beg; p < end; p++) acc += (float)y[(size_t)p * 32 + o];
    acc /= fmaxf((float)(end - beg), 1.0f);
    const float* __restrict__ xr = x + (size_t)nd * 32;
    float rsum = 0.0f;
    #pragma unroll
    for (int i = 0; i < 32; i++) rsum += xr[i] * root[i * 32 + o];
    float v = acc + rsum + b[o];
    out[(size_t)nd * 32 + o] = (v > 0.0f) ? v : expm1f(v);
}

// ---------- conv1 (cin=1) node-centric: 8B quantized payload, o-major W1 in LDS ----------

__global__ __launch_bounds__(256) void conv1_node_kernel(
        const float* __restrict__ x, const uint2* __restrict__ pay1,
        const int* __restrict__ row_start, const float* __restrict__ W,
        const float* __restrict__ root, const float* __restrict__ b,
        float* __restrict__ out, int n) {
    __shared__ float Wl[32 * K3];   // [o][bin], stride 125 -> bank-permuted, 15.6 KB
    for (int i = threadIdx.x; i < K3 * 32; i += 256) {
        int bin = i >> 5, o = i & 31;
        Wl[o * K3 + bin] = W[i];
    }
    __syncthreads();

    int tid = blockIdx.x * blockDim.x + threadIdx.x;
    int nd = tid >> 5, o = tid & 31;
    if (nd >= n) return;
    int beg = row_start[nd], end = row_start[nd + 1];
    const float inv = 1.0f / 16384.0f;
    const float* Wo = &Wl[o * K3];
    float acc = 0.0f;
    for (int idx = beg; idx < end; idx++) {
        uint2 pq = pay1[idx];
        int k0 = (int)((pq.x & 0xFFFFu) >> 14);
        int k1 = (int)(pq.x >> 30);
        int k2 = (int)((pq.y & 0xFFFFu) >> 14);
        float fx = (float)(pq.x & 16383u) * inv;
        float fy = (float)((pq.x >> 16) & 16383u) * inv;
        float fz = (float)(pq.y & 16383u) * inv;
        int src = (int)(pq.y >> 16);
        int f0 = (k0 * 5 + k1) * 5 + k2;
        const float* Wf = Wo + f0;
        float gx0 = 1.0f - fx, gy0 = 1.0f - fy, gz0 = 1.0f - fz;
        float a00 = gx0 * Wf[0] + fx * Wf[25];
        float a01 = gx0 * Wf[5] + fx * Wf[30];
        float a10 = gx0 * Wf[1] + fx * Wf[26];
        float a11 = gx0 * Wf[6] + fx * Wf[31];
        float s = gz0 * (gy0 * a00 + fy * a01) + fz * (gy0 * a10 + fy * a11);
        acc += x[src] * s;
    }
    float v = acc / fmaxf((float)(end - beg), 1.0f) + x[nd] * root[o] + b[o];
    out[(size_t)nd * 32 + o] = (v > 0.0f) ? v : expm1f(v);
}

// ---------- FC + log_softmax ----------

__global__ void fc_kernel(const float* __restrict__ h, const float* __restrict__ fw,
                          const float* __restrict__ fb, float* __restrict__ out, int B) {
    int tid = blockIdx.x * blockDim.x + threadIdx.x;
    int row = tid >> 5, lane = tid & 31;
    if (row >= B) return;
    const float* hb = h + (size_t)row * 256;
    float lg[10];
    #pragma unroll
    for (int j = 0; j < 10; j++) lg[j] = 0.0f;
    for (int tt = lane; tt < 256; tt += 32) {
        float hv = hb[tt];
        const float* fr = fw + tt * 10;
        #pragma unroll
        for (int j = 0; j < 10; j++) lg[j] += hv * fr[j];
    }
    #pragma unroll
    for (int off = 16; off > 0; off >>= 1)
        #pragma unroll
        for (int j = 0; j < 10; j++) lg[j] += __shfl_down(lg[j], off, 32);
    if (lane == 0) {
        #pragma unroll
        for (int j = 0; j < 10; j++) lg[j] += fb[j];
        float m = lg[0];
        #pragma unroll
        for (int j = 1; j < 10; j++) m = fmaxf(m, lg[j]);
        float s = 0.0f;
        #pragma unroll
        for (int j = 0; j < 10; j++) s += expf(lg[j] - m);
        float lse = logf(s) + m;
        #pragma unroll
        for (int j = 0; j < 10; j++) out[(size_t)row * 10 + j] = lg[j] - lse;
    }
}

// ---------- launch ----------

static inline int cdiv(long long a, int b) { return (int)((a + b - 1) / b); }

extern "C" void kernel_launch(void* const* d_in, const int* in_sizes, int n_in,
                              void* d_out, int out_size, void* d_ws, size_t ws_size,
                              hipStream_t stream) {
    const int N1 = N1c, N2 = N2c, N3 = N3c, B8 = B8c;
    const int B = B8 / 8;

    const float* x      = (const float*)d_in[0];
    const int*   cl0    = (const int*)d_in[1];
    const int*   ei1    = (const int*)d_in[2];
    const float* ps1    = (const float*)d_in[3];
    const int*   cl1    = (const int*)d_in[4];
    const int*   ei2    = (const int*)d_in[5];
    const float* ps2    = (const float*)d_in[6];
    const int*   cl2    = (const int*)d_in[7];
    const int*   ei3    = (const int*)d_in[8];
    const float* ps3    = (const float*)d_in[9];
    const int*   cl3    = (const int*)d_in[10];
    const float* W1     = (const float*)d_in[11];
    const float* root1  = (const float*)d_in[12];
    const float* b1     = (const float*)d_in[13];
    const float* W2     = (const float*)d_in[14];
    const float* root2  = (const float*)d_in[15];
    const float* b2     = (const float*)d_in[16];
    const float* W3     = (const float*)d_in[17];
    const float* root3  = (const float*)d_in[18];
    const float* b3     = (const float*)d_in[19];
    const float* fc_w   = (const float*)d_in[20];
    const float* fc_b   = (const float*)d_in[21];
    float* out = (float*)d_out;

    const int E1 = in_sizes[2] / 2;
    const int E2 = in_sizes[5] / 2;
    const int E3 = in_sizes[8] / 2;
    const long long Etot = (long long)E1 + E2 + E3;
    const long long IT = Etot + N0c + N1c + N2c + N3c;

    const int grid2 = cdiv((long long)E2 + 64 * 255, 256);
    const int grid3 = cdiv((long long)E3 + 64 * 255, 256);
    const int pad2 = grid2 * 256, pad3 = grid3 * 256;
    const int ymax = (E2 > E3 ? E2 : E3);

    // ---- workspace layout ----
    char* wp = (char*)d_ws;
    float* p0  = (float*)wp;               wp += (size_t)N1 * 4;
    float* h1  = (float*)wp;               wp += (size_t)N1 * 32 * 4;
    float* p1  = (float*)wp;               wp += (size_t)N2 * 32 * 4;
    float* h2  = (float*)wp;               wp += (size_t)N2 * 32 * 4;
    float* p2  = (float*)wp;               wp += (size_t)N3 * 32 * 4;
    float* h3  = (float*)wp;               wp += (size_t)N3 * 32 * 4;
    float* p3  = (float*)wp;               wp += (size_t)B8 * 32 * 4;
    // zeroed-together region: [cnt | cur | ccnt | ccur]
    int* cnt   = (int*)wp;                 wp += (size_t)SBT * 4;
    int* cur   = (int*)wp;                 wp += (size_t)SBT * 4;
    int* ccnt  = (int*)wp;                 wp += 128 * 4;
    int* ccur  = (int*)wp;                 wp += 256 * 4;
    size_t zero_bytes = (size_t)(wp - (char*)cnt);
    int* coff  = (int*)wp;                 wp += 128 * 4;
    int* rows  = (int*)wp;                 wp += (size_t)(SBT + 7) * 4;
    int* bsum  = (int*)wp;                 wp += 256 * 4;
    int* mem0  = (int*)wp;                 wp += (size_t)N0c * 4;
    int* mem1  = (int*)wp;                 wp += (size_t)N1c * 4;
    int* mem2  = (int*)wp;                 wp += (size_t)N2c * 4;
    int* mem3  = (int*)wp;                 wp += (size_t)N3c * 4;
    uint2* pay1  = (uint2*)wp;             wp += (size_t)E1 * 8;
    uint4* qtmp  = (uint4*)wp;             wp += (size_t)E1 * 16;
    uint2* vpay2 = (uint2*)wp;             wp += (size_t)pad2 * 8;
    uint2* vpay3 = (uint2*)wp;             wp += (size_t)pad3 * 8;
    int* dpos2 = (int*)wp;                 wp += (size_t)pad2 * 4;
    int* dpos3 = (int*)wp;                 wp += (size_t)pad3 * 4;   // contiguous with dpos2
    int* blockcell2 = (int*)wp;            wp += (size_t)grid2 * 4;
    int* blockcell3 = (int*)wp;            wp += (size_t)grid3 * 4;  // contiguous with blockcell2
    _Float16* WT2 = (_Float16*)wp;         wp += (size_t)K3 * 1024 * 2;
    _Float16* WT3 = (_Float16*)wp;         wp += (size_t)K3 * 1024 * 2;
    _Float16* yh = (_Float16*)wp;          // ymax*32 halves

    int* row1  = rows;
    int* row2  = rows + SB1 + 1;
    int* row3  = rows + SB2 + 2;
    int* crow0 = rows + SB3 + 3;
    int* crow1 = rows + SB4 + 4;
    int* crow2 = rows + SB5 + 5;
    int* crow3 = rows + SB6 + 6;

    const int T = 256;
    const int nb = SBT / 1024;   // 240

    // ========== indexing phase (input-only) ==========
    hipMemsetAsync(cnt, 0, zero_bytes, stream);
    hipMemsetAsync(dpos2, 0xFF, ((size_t)pad2 + pad3) * 4, stream);
    hipMemsetAsync(blockcell2, 0xFF, ((size_t)grid2 + grid3) * 4, stream);
    wtrans_kernel<<<cdiv((long long)K3 * 1024, T), T, 0, stream>>>(W2, W3, WT2, WT3);
    index_hist_all<<<cdiv(IT, 1024), 1024, 0, stream>>>(
        ei1, ei2, ei3, ps2, ps3, cl0, cl1, cl2, cl3, cnt, ccnt, E1, E2, E3);
    scan_blocks_kernel<<<nb, 1024, 0, stream>>>(cnt, rows, bsum);
    scan_sums_kernel<<<1, 256, 0, stream>>>(bsum, ccnt, coff, blockcell2, blockcell3, nb);
    scan_add_kernel<<<nb, 1024, 0, stream>>>(rows, bsum, E1, E2, E3);
    scatter_all<<<cdiv(IT, 1024), 1024, 0, stream>>>(
        ei1, ei2, ei3, ps1, ps2, ps3, cl0, cl1, cl2, cl3, cur, rows,
        qtmp, vpay2, dpos2, vpay3, dpos3,
        mem0, mem1, mem2, mem3, ccur, coff, E1, E2, E3);
    pay1_pass2<<<128, 1024, 0, stream>>>(qtmp, rows, pay1);

    // ========== pipeline ==========
    pool1ch_kernel<<<cdiv(N1, T), T, 0, stream>>>(x, crow0, mem0, p0, N1);

    conv1_node_kernel<<<cdiv((long long)N1 * 32, T), T, 0, stream>>>(
        p0, pay1, row1, W1, root1, b1, h1, N1);

    pool32ch_kernel<<<cdiv((long long)N2 * 32, T), T, 0, stream>>>(h1, crow1, mem1, p1, N2);

    conv_cell_mfma<<<grid2, 256, 0, stream>>>(p1, vpay2, dpos2, blockcell2, WT2, yh, E2);
    gather_fin_kernel<<<cdiv((long long)N2 * 32, T), T, 0, stream>>>(
        yh, row2, p1, root2, b2, h2, N2);

    pool32ch_kernel<<<cdiv((long long)N3 * 32, T), T, 0, stream>>>(h2, crow2, mem2, p2, N3);

    conv_cell_mfma<<<grid3, 256, 0, stream>>>(p2, vpay3, dpos3, blockcell3, WT3, yh, E3);
    gather_fin_kernel<<<cdiv((long long)N3 * 32, T), T, 0, stream>>>(
        yh, row3, p2, root3, b3, h3, N3);

    pool32ch_kernel<<<cdiv((long long)B8 * 32, T), T, 0, stream>>>(h3, crow3, mem3, p3, B8);

    fc_kernel<<<cdiv((long long)B * 32, T), T, 0, stream>>>(p3, fc_w, fc_b, out, B);
}

// Round 11
// 539.977 us; speedup vs baseline: 9.6340x; 1.3029x over previous
//
#include <hip/hip_runtime.h>
#include <math.h>

#define KS 5
#define K3 125

// problem sizes (fixed)
#define N0c 131072
#define N1c 65536
#define N2c 32768
#define N3c 16384
#define B8c 16384

typedef _Float16 hf8_t __attribute__((ext_vector_type(8)));
typedef float f32x4_t __attribute__((ext_vector_type(4)));

union wpack_u { _Float16 h[8]; uint4 u; };

// ---------- helpers ----------
// quantized pseudo: q = rint(ps*65536) clamped to 65535; k0 = q>>14 (0..3), f = (q&16383)/16384.

__device__ __forceinline__ unsigned qz16(float ps) {
    float t = rintf(ps * 65536.0f);
    t = fminf(fmaxf(t, 0.0f), 65535.0f);
    return (unsigned)t;
}

// rows-space segment boundaries (row1,row2,row3,crow0,crow1,crow2,crow3)
#define SB1 65536
#define SB2 98304
#define SB3 114688
#define SB4 180224
#define SB5 212992
#define SB6 229376
#define SBT 245760

// coarse-bucket space: 512 keys per bucket
#define L2S 128
#define L3S 192
#define C0S 224
#define C1S 352
#define C2S 416
#define C3S 448
#define NBK 480

// ---------- W transpose + fp16: [bin][i][o] f32 -> [bin][o][i] fp16 ----------

__global__ void wtrans_kernel(const float* __restrict__ W2, const float* __restrict__ W3,
                              _Float16* __restrict__ WT2, _Float16* __restrict__ WT3) {
    int tid = blockIdx.x * blockDim.x + threadIdx.x;
    const int total = K3 * 1024;
    if (tid >= total) return;
    int bin = tid >> 10, r = tid & 1023, i = r >> 5, o = r & 31;
    WT2[bin * 1024 + o * 32 + i] = (_Float16)W2[tid];
    WT3[bin * 1024 + o * 32 + i] = (_Float16)W3[tid];
}

// ---------- coarse bucket id for item g ----------

__device__ __forceinline__ int coarse_bkt(long long g,
        const int* __restrict__ ei1, const int* __restrict__ ei2, const int* __restrict__ ei3,
        const int* __restrict__ cl0, const int* __restrict__ cl1,
        const int* __restrict__ cl2, const int* __restrict__ cl3,
        int E1, int E2, int E3) {
    long long Etot = (long long)E1 + E2 + E3;
    if (g < E1)                        return ei1[E1 + (int)g] >> 9;
    if (g < (long long)E1 + E2)        return L2S + (ei2[E2 + (int)(g - E1)] >> 9);
    if (g < Etot)                      return L3S + (ei3[E3 + (int)(g - E1 - E2)] >> 9);
    if (g < Etot + N0c)                return C0S + (cl0[(int)(g - Etot)] >> 9);
    if (g < Etot + N0c + N1c)          return C1S + (cl1[(int)(g - Etot - N0c)] >> 9);
    if (g < Etot + N0c + N1c + N2c)    return C2S + (cl2[(int)(g - Etot - N0c - N1c)] >> 9);
    return C3S + (cl3[(int)(g - Etot - N0c - N1c - N2c)] >> 9);
}

// ---------- phase A: coarse histogram (480 bins, LDS-privatized) ----------

__global__ __launch_bounds__(1024) void coarse_hist(
        const int* __restrict__ ei1, const int* __restrict__ ei2, const int* __restrict__ ei3,
        const int* __restrict__ cl0, const int* __restrict__ cl1,
        const int* __restrict__ cl2, const int* __restrict__ cl3,
        int* __restrict__ bcnt, int E1, int E2, int E3, int CH, long long IT) {
    __shared__ int l[NBK];
    int t = threadIdx.x;
    for (int i = t; i < NBK; i += 1024) l[i] = 0;
    __syncthreads();
    long long start = (long long)blockIdx.x * CH;
    long long end = start + CH; if (end > IT) end = IT;
    for (long long g = start + t; g < end; g += 1024)
        atomicAdd(&l[coarse_bkt(g, ei1, ei2, ei3, cl0, cl1, cl2, cl3, E1, E2, E3)], 1);
    __syncthreads();
    for (int i = t; i < NBK; i += 1024) if (l[i]) atomicAdd(&bcnt[i], l[i]);
}

// ---------- phase B: segmented scan of 480 bucket counts -> bbase; write row terminals ----------

__global__ __launch_bounds__(512) void bucket_scan(const int* __restrict__ bcnt,
                                                   int* __restrict__ bbase,
                                                   int* __restrict__ rows,
                                                   int E1, int E2, int E3) {
    __shared__ int sdata[512];
    __shared__ int sseg[512];
    int t = threadIdx.x;
    int v = (t < NBK) ? bcnt[t] : 0;
    int seg = (t < L2S) ? 0 : (t < L3S) ? 1 : (t < C0S) ? 2 :
              (t < C1S) ? 3 : (t < C2S) ? 4 : (t < C3S) ? 5 : 6;
    sdata[t] = v; sseg[t] = seg;
    __syncthreads();
    for (int off = 1; off < 512; off <<= 1) {
        int add = (t >= off && sseg[t - off] == seg) ? sdata[t - off] : 0;
        __syncthreads();
        sdata[t] += add;
        __syncthreads();
    }
    if (t < NBK) bbase[t] = sdata[t] - v;
    if (t == 0) rows[SB1 + 0] = E1;
    if (t == 1) rows[SB2 + 1] = E2;
    if (t == 2) rows[SB3 + 2] = E3;
    if (t == 3) rows[SB4 + 3] = N0c;
    if (t == 4) rows[SB5 + 4] = N1c;
    if (t == 5) rows[SB6 + 5] = N2c;
    if (t == 6) rows[SBT + 6] = N3c;
}

// ---------- phase C: two-sweep coarse scatter (no per-item global atomics) ----------
// edge rec (uint4): {q0|q1<<16, q2|dst<<16, src, 0}; cluster rec (uint2): {node, bin}.

__global__ __launch_bounds__(1024) void scatter_coarse(
        const int* __restrict__ ei1, const int* __restrict__ ei2, const int* __restrict__ ei3,
        const float* __restrict__ ps1, const float* __restrict__ ps2, const float* __restrict__ ps3,
        const int* __restrict__ cl0, const int* __restrict__ cl1,
        const int* __restrict__ cl2, const int* __restrict__ cl3,
        const int* __restrict__ bbase, int* __restrict__ gcur, int* __restrict__ ccnt,
        uint4* __restrict__ qe, uint2* __restrict__ qc,
        int E1, int E2, int E3, int CH, long long IT) {
    __shared__ int lcnt[NBK];
    __shared__ int gb[NBK];
    __shared__ int lcell[128];
    int t = threadIdx.x;
    for (int i = t; i < NBK; i += 1024) lcnt[i] = 0;
    if (t < 128) lcell[t] = 0;
    __syncthreads();
    long long start = (long long)blockIdx.x * CH;
    long long end = start + CH; if (end > IT) end = IT;
    long long Etot = (long long)E1 + E2 + E3;

    // sweep A: count local buckets
    for (long long g = start + t; g < end; g += 1024)
        atomicAdd(&lcnt[coarse_bkt(g, ei1, ei2, ei3, cl0, cl1, cl2, cl3, E1, E2, E3)], 1);
    __syncthreads();
    for (int i = t; i < NBK; i += 1024) {
        gb[i] = lcnt[i] ? atomicAdd(&gcur[i], lcnt[i]) : 0;
        lcnt[i] = 0;
    }
    __syncthreads();

    // sweep B: place records
    for (long long g = start + t; g < end; g += 1024) {
        if (g < Etot) {
            int e, dst, src, bkt, qoff;
            const float* ps;
            if (g < E1)      { e = (int)g;           dst = ei1[E1 + e]; src = ei1[e]; ps = ps1; bkt = dst >> 9;         qoff = 0; }
            else if (g < (long long)E1 + E2)
                             { e = (int)(g - E1);    dst = ei2[E2 + e]; src = ei2[e]; ps = ps2; bkt = L2S + (dst >> 9); qoff = E1; }
            else             { e = (int)(g - E1 - E2); dst = ei3[E3 + e]; src = ei3[e]; ps = ps3; bkt = L3S + (dst >> 9); qoff = E1 + E2; }
            unsigned q0 = qz16(ps[(size_t)e * 3]);
            unsigned q1 = qz16(ps[(size_t)e * 3 + 1]);
            unsigned q2 = qz16(ps[(size_t)e * 3 + 2]);
            int r = atomicAdd(&lcnt[bkt], 1);
            qe[qoff + bbase[bkt] + gb[bkt] + r] =
                make_uint4(q0 | (q1 << 16), q2 | ((unsigned)dst << 16), (unsigned)src, 0u);
            if (g >= E1) {
                int cell = (int)(((q0 >> 14) << 4) | ((q1 >> 14) << 2) | (q2 >> 14));
                atomicAdd(&lcell[(g < (long long)E1 + E2) ? cell : 64 + cell], 1);
            }
        } else {
            int i, bin, bkt, qoff;
            if (g < Etot + N0c)             { i = (int)(g - Etot);                   bin = cl0[i]; bkt = C0S + (bin >> 9); qoff = 0; }
            else if (g < Etot + N0c + N1c)  { i = (int)(g - Etot - N0c);             bin = cl1[i]; bkt = C1S + (bin >> 9); qoff = N0c; }
            else if (g < Etot + N0c + N1c + N2c)
                                            { i = (int)(g - Etot - N0c - N1c);       bin = cl2[i]; bkt = C2S + (bin >> 9); qoff = N0c + N1c; }
            else                            { i = (int)(g - Etot - N0c - N1c - N2c); bin = cl3[i]; bkt = C3S + (bin >> 9); qoff = N0c + N1c + N2c; }
            int r = atomicAdd(&lcnt[bkt], 1);
            qc[qoff + bbase[bkt] + gb[bkt] + r] = make_uint2((unsigned)i, (unsigned)bin);
        }
    }
    __syncthreads();
    if (t < 128 && lcell[t]) atomicAdd(&ccnt[t], lcell[t]);
}

// ---------- coff + blockcell from cell counts ----------

__global__ void coff_build(const int* __restrict__ ccnt, int* __restrict__ coff,
                           int* __restrict__ blockcell2, int* __restrict__ blockcell3) {
    int t = threadIdx.x;
    if (t == 0) {
        int acc = 0;
        for (int c = 0; c < 64; c++) {
            coff[c] = acc;
            int nbk = (ccnt[c] + 255) >> 8;
            for (int k = 0; k < nbk; k++) blockcell2[(acc >> 8) + k] = c;
            acc += nbk << 8;
        }
    }
    if (t == 1) {
        int acc = 0;
        for (int c = 0; c < 64; c++) {
            coff[64 + c] = acc;
            int nbk = (ccnt[64 + c] + 255) >> 8;
            for (int k = 0; k < nbk; k++) blockcell3[(acc >> 8) + k] = c;
            acc += nbk << 8;
        }
    }
}

// ---------- phase D: per-bucket fine pass — rows, pay1, vpay+dpos, mem lists ----------

__global__ __launch_bounds__(1024) void pass2_all(
        const uint4* __restrict__ qe, const uint2* __restrict__ qc,
        const int* __restrict__ bbase, const int* __restrict__ bcnt,
        int* __restrict__ rows,
        uint2* __restrict__ pay1,
        uint2* __restrict__ vpay2, int* __restrict__ dpos2,
        uint2* __restrict__ vpay3, int* __restrict__ dpos3,
        int* __restrict__ mem0, int* __restrict__ mem1,
        int* __restrict__ mem2, int* __restrict__ mem3,
        int* __restrict__ ccur, const int* __restrict__ coff,
        int E1, int E2, int E3) {
    __shared__ int scnt[512];
    __shared__ int rowv[512];
    __shared__ int scur[512];
    __shared__ int lcell[64];
    __shared__ int gcb[64];
    __shared__ int ccur_l[64];
    int t = threadIdx.x;
    int b = blockIdx.x;

    int kind, lb;
    const uint4* qr = nullptr; const uint2* cr = nullptr;
    int* rowp; uint2* vp = nullptr; int* dp = nullptr; int* memp = nullptr;
    int cofs = 0;
    if (b < L2S)      { kind = 1; lb = b;       qr = qe + bbase[b];             rowp = rows; }
    else if (b < L3S) { kind = 2; lb = b - L2S; qr = qe + E1 + bbase[b];        rowp = rows + SB1 + 1; vp = vpay2; dp = dpos2; cofs = 0; }
    else if (b < C0S) { kind = 3; lb = b - L3S; qr = qe + E1 + E2 + bbase[b];   rowp = rows + SB2 + 2; vp = vpay3; dp = dpos3; cofs = 64; }
    else if (b < C1S) { kind = 4; lb = b - C0S; cr = qc + bbase[b];             rowp = rows + SB3 + 3; memp = mem0; }
    else if (b < C2S) { kind = 5; lb = b - C1S; cr = qc + N0c + bbase[b];       rowp = rows + SB4 + 4; memp = mem1; }
    else if (b < C3S) { kind = 6; lb = b - C2S; cr = qc + N0c + N1c + bbase[b]; rowp = rows + SB5 + 5; memp = mem2; }
    else              { kind = 7; lb = b - C3S; cr = qc + N0c + N1c + N2c + bbase[b]; rowp = rows + SB6 + 6; memp = mem3; }
    int n = bcnt[b];
    int ebase = bbase[b];
    int rowoff = lb << 9;

    if (t < 512) { scnt[t] = 0; scur[t] = 0; }
    if (t < 64) { lcell[t] = 0; ccur_l[t] = 0; }
    __syncthreads();

    // sweep 1: count fine bins (+cells for edge lvl2/3)
    if (kind <= 3) {
        for (int i = t; i < n; i += 1024) {
            uint4 r = qr[i];
            atomicAdd(&scnt[(r.y >> 16) & 511], 1);
            if (kind >= 2) {
                int cell = (int)((((r.x & 0xFFFFu) >> 14) << 4) | ((r.x >> 30) << 2) | ((r.y & 0xFFFFu) >> 14));
                atomicAdd(&lcell[cell], 1);
            }
        }
    } else {
        for (int i = t; i < n; i += 1024) {
            uint2 r = cr[i];
            atomicAdd(&scnt[r.y & 511], 1);
        }
    }
    __syncthreads();

    // exclusive scan of 512 bins; write row offsets
    {
        int v = (t < 512) ? scnt[t] : 0;
        if (t < 512) rowv[t] = v;
        __syncthreads();
        for (int off = 1; off < 512; off <<= 1) {
            int add = (t >= off && t < 512) ? rowv[t - off] : 0;
            __syncthreads();
            if (t < 512) rowv[t] += add;
            __syncthreads();
        }
        if (t < 512) {
            int base = ebase + rowv[t] - v;
            rowv[t] = base;
            rowp[rowoff + t] = base;
        }
    }
    if (kind >= 2 && kind <= 3 && t < 64)
        gcb[t] = lcell[t] ? atomicAdd(&ccur[cofs + t], lcell[t]) : 0;
    __syncthreads();

    // sweep 2: place
    if (kind == 1) {
        for (int i = t; i < n; i += 1024) {
            uint4 r = qr[i];
            int d9 = (r.y >> 16) & 511;
            int pos = atomicAdd(&scur[d9], 1);
            pay1[rowv[d9] + pos] = make_uint2(r.x, (r.y & 0xFFFFu) | (r.z << 16));
        }
    } else if (kind <= 3) {
        for (int i = t; i < n; i += 1024) {
            uint4 r = qr[i];
            int d9 = (r.y >> 16) & 511;
            int dpv = rowv[d9] + atomicAdd(&scur[d9], 1);
            int cell = (int)((((r.x & 0xFFFFu) >> 14) << 4) | ((r.x >> 30) << 2) | ((r.y & 0xFFFFu) >> 14));
            int cl = atomicAdd(&ccur_l[cell], 1);
            int slot = coff[cofs + cell] + gcb[cell] + cl;
            vp[slot] = make_uint2(r.x, (r.y & 0xFFFFu) | (r.z << 16));
            dp[slot] = dpv;
        }
    } else {
        for (int i = t; i < n; i += 1024) {
            uint2 r = cr[i];
            int b9 = r.y & 511;
            memp[rowv[b9] + atomicAdd(&scur[b9], 1)] = (int)r.x;
        }
    }
}

// ---------- pooling ----------

__global__ void pool1ch_kernel(const float* __restrict__ in, const int* __restrict__ crow,
                               const int* __restrict__ mem, float* __restrict__ out, int n) {
    int nd = blockIdx.x * blockDim.x + threadIdx.x;
    if (nd >= n) return;
    int beg = crow[nd], end = crow[nd + 1];
    float v = -INFINITY;
    for (int p = beg; p < end; p++) v = fmaxf(v, in[mem[p]]);
    out[nd] = (beg == end) ? 0.0f : v;
}

__global__ void pool32ch_kernel(const float* __restrict__ in, const int* __restrict__ crow,
                                const int* __restrict__ mem, float* __restrict__ out, int n) {
    int tid = blockIdx.x * blockDim.x + threadIdx.x;
    int nd = tid >> 5, o = tid & 31;
    if (nd >= n) return;
    int beg = crow[nd], end = crow[nd + 1];
    float v = -INFINITY;
    for (int p = beg; p < end; p++) v = fmaxf(v, in[(size_t)mem[p] * 32 + o]);
    out[(size_t)nd * 32 + o] = (beg == end) ? 0.0f : v;
}

// ---------- cell conv via MFMA fp16, quantized payload ----------

__global__ __launch_bounds__(256, 4) void conv_cell_mfma(
        const float* __restrict__ x, const uint2* __restrict__ vpay, const int* __restrict__ dposA,
        const int* __restrict__ blockcell, const _Float16* __restrict__ WT,
        _Float16* __restrict__ y, int E) {
    __shared__ _Float16 Wl[8 * 1024];   // [c][o][i]  16 KB
    __shared__ _Float16 xh[256 * 32];   // [e][i]     16 KB
    __shared__ uint4 wcl[256];          // w8 per edge  4 KB
    __shared__ int dinfo[256];

    int cell = blockcell[blockIdx.x];
    if (cell < 0) return;   // fully-padded trailing block

    int t = threadIdx.x;
    int base = blockIdx.x * 256;
    uint2 vq = vpay[base + t];
    int d = dposA[base + t];
    dinfo[t] = d;
    int src = (d < 0) ? 0 : (int)(vq.y >> 16);

    // per-edge corner weights from quantized pseudo
    {
        const float inv = 1.0f / 16384.0f;
        float fx = (float)(vq.x & 16383u) * inv;
        float fy = (float)((vq.x >> 16) & 16383u) * inv;
        float fz = (float)(vq.y & 16383u) * inv;
        float gx0 = 1.0f - fx, gy0 = 1.0f - fy, gz0 = 1.0f - fz;
        wpack_u pk;
        pk.h[0] = (_Float16)(gx0 * gy0 * gz0);
        pk.h[1] = (_Float16)(fx  * gy0 * gz0);
        pk.h[2] = (_Float16)(gx0 * fy  * gz0);
        pk.h[3] = (_Float16)(fx  * fy  * gz0);
        pk.h[4] = (_Float16)(gx0 * gy0 * fz );
        pk.h[5] = (_Float16)(fx  * gy0 * fz );
        pk.h[6] = (_Float16)(gx0 * fy  * fz );
        pk.h[7] = (_Float16)(fx  * fy  * fz );
        wcl[t] = pk.u;
    }

    // stage W (fp16, o-major) for this cell's 8 corners
    {
        int kx = cell >> 4, ky = (cell >> 2) & 3, kz = cell & 3;
        int c = t >> 5, o = t & 31;
        int id0 = kx + ((c >> 0) & 1);
        int id1 = ky + ((c >> 1) & 1);
        int id2 = kz + ((c >> 2) & 1);
        int flat = (id0 * KS + id1) * KS + id2;
        const uint4* s4 = (const uint4*)(WT + (size_t)flat * 1024 + o * 32);
        uint4* dst = (uint4*)&Wl[c * 1024 + o * 32];
        #pragma unroll
        for (int j = 0; j < 4; j++) dst[j] = s4[j];
    }

    // stage x (fp16)
    {
        const float4* xr = (const float4*)(x + (size_t)src * 32);
        _Float16* xd = &xh[t * 32];
        #pragma unroll
        for (int j = 0; j < 8; j++) {
            float4 v = xr[j];
            xd[j * 4 + 0] = (_Float16)v.x;
            xd[j * 4 + 1] = (_Float16)v.y;
            xd[j * 4 + 2] = (_Float16)v.z;
            xd[j * 4 + 3] = (_Float16)v.w;
        }
    }
    __syncthreads();

    int wv = t >> 6, lane = t & 63;
    int quad = lane >> 4, mrow = lane & 15;
    const _Float16* whal = (const _Float16*)wcl;

    hf8_t xf[4];
    #pragma unroll
    for (int mt = 0; mt < 4; mt++) {
        int em = wv * 64 + mt * 16 + mrow;
        xf[mt] = *(const hf8_t*)&xh[em * 32 + quad * 8];
    }

    f32x4_t acc[4][2];
    #pragma unroll
    for (int mt = 0; mt < 4; mt++) {
        acc[mt][0] = (f32x4_t)0.0f;
        acc[mt][1] = (f32x4_t)0.0f;
    }

    #pragma unroll
    for (int c = 0; c < 8; c++) {
        hf8_t b0 = *(const hf8_t*)&Wl[c * 1024 + mrow * 32 + quad * 8];
        hf8_t b1 = *(const hf8_t*)&Wl[c * 1024 + (16 + mrow) * 32 + quad * 8];
        #pragma unroll
        for (int mt = 0; mt < 4; mt++) {
            int em = wv * 64 + mt * 16 + mrow;
            _Float16 wcv = whal[em * 8 + c];
            hf8_t af = xf[mt] * wcv;
            acc[mt][0] = __builtin_amdgcn_mfma_f32_16x16x32_f16(af, b0, acc[mt][0], 0, 0, 0);
            acc[mt][1] = __builtin_amdgcn_mfma_f32_16x16x32_f16(af, b1, acc[mt][1], 0, 0, 0);
        }
    }

    #pragma unroll
    for (int mt = 0; mt < 4; mt++) {
        #pragma unroll
        for (int reg = 0; reg < 4; reg++) {
            int el = wv * 64 + mt * 16 + quad * 4 + reg;
            int dd = dinfo[el];
            if (dd >= 0) {
                y[(size_t)dd * 32 + mrow]      = (_Float16)acc[mt][0][reg];
                y[(size_t)dd * 32 + 16 + mrow] = (_Float16)acc[mt][1][reg];
            }
        }
    }
}

// ---------- gather finalize ----------

__global__ void gather_fin_kernel(const _Float16* __restrict__ y, const int* __restrict__ row_start,
                                  const float* __restrict__ x, const float* __restrict__ root,
                                  const float* __restrict__ b, float* __restrict__ out, int n) {
    int tid = blockIdx.x * blockDim.x + threadIdx.x;
    int nd = tid >> 5, o = tid & 31;
    if (nd >= n) return;
    int beg = row_start[nd], end = row_start[nd + 1];
    float acc = 0.0f;
    for (int p = beg; p < end; p++) acc += (float)y[(size_t)p * 32 + o];
    acc /= fmaxf((float)(end - beg), 1.0f);
    const float* __restrict__ xr = x + (size_t)nd * 32;
    float rsum = 0.0f;
    #pragma unroll
    for (int i = 0; i < 32; i++) rsum += xr[i] * root[i * 32 + o];
    float v = acc + rsum + b[o];
    out[(size_t)nd * 32 + o] = (v > 0.0f) ? v : expm1f(v);
}

// ---------- conv1 (cin=1) node-centric: 8B quantized payload, o-major W1 in LDS ----------

__global__ __launch_bounds__(256) void conv1_node_kernel(
        const float* __restrict__ x, const uint2* __restrict__ pay1,
        const int* __restrict__ row_start, const float* __restrict__ W,
        const float* __restrict__ root, const float* __restrict__ b,
        float* __restrict__ out, int n) {
    __shared__ float Wl[32 * K3];   // [o][bin], stride 125 -> bank-permuted, 15.6 KB
    for (int i = threadIdx.x; i < K3 * 32; i += 256) {
        int bin = i >> 5, o = i & 31;
        Wl[o * K3 + bin] = W[i];
    }
    __syncthreads();

    int tid = blockIdx.x * blockDim.x + threadIdx.x;
    int nd = tid >> 5, o = tid & 31;
    if (nd >= n) return;
    int beg = row_start[nd], end = row_start[nd + 1];
    const float inv = 1.0f / 16384.0f;
    const float* Wo = &Wl[o * K3];
    float acc = 0.0f;
    for (int idx = beg; idx < end; idx++) {
        uint2 pq = pay1[idx];
        int k0 = (int)((pq.x & 0xFFFFu) >> 14);
        int k1 = (int)(pq.x >> 30);
        int k2 = (int)((pq.y & 0xFFFFu) >> 14);
        float fx = (float)(pq.x & 16383u) * inv;
        float fy = (float)((pq.x >> 16) & 16383u) * inv;
        float fz = (float)(pq.y & 16383u) * inv;
        int src = (int)(pq.y >> 16);
        int f0 = (k0 * 5 + k1) * 5 + k2;
        const float* Wf = Wo + f0;
        float gx0 = 1.0f - fx, gy0 = 1.0f - fy, gz0 = 1.0f - fz;
        float a00 = gx0 * Wf[0] + fx * Wf[25];
        float a01 = gx0 * Wf[5] + fx * Wf[30];
        float a10 = gx0 * Wf[1] + fx * Wf[26];
        float a11 = gx0 * Wf[6] + fx * Wf[31];
        float s = gz0 * (gy0 * a00 + fy * a01) + fz * (gy0 * a10 + fy * a11);
        acc += x[src] * s;
    }
    float v = acc / fmaxf((float)(end - beg), 1.0f) + x[nd] * root[o] + b[o];
    out[(size_t)nd * 32 + o] = (v > 0.0f) ? v : expm1f(v);
}

// ---------- FC + log_softmax ----------

__global__ void fc_kernel(const float* __restrict__ h, const float* __restrict__ fw,
                          const float* __restrict__ fb, float* __restrict__ out, int B) {
    int tid = blockIdx.x * blockDim.x + threadIdx.x;
    int row = tid >> 5, lane = tid & 31;
    if (row >= B) return;
    const float* hb = h + (size_t)row * 256;
    float lg[10];
    #pragma unroll
    for (int j = 0; j < 10; j++) lg[j] = 0.0f;
    for (int tt = lane; tt < 256; tt += 32) {
        float hv = hb[tt];
        const float* fr = fw + tt * 10;
        #pragma unroll
        for (int j = 0; j < 10; j++) lg[j] += hv * fr[j];
    }
    #pragma unroll
    for (int off = 16; off > 0; off >>= 1)
        #pragma unroll
        for (int j = 0; j < 10; j++) lg[j] += __shfl_down(lg[j], off, 32);
    if (lane == 0) {
        #pragma unroll
        for (int j = 0; j < 10; j++) lg[j] += fb[j];
        float m = lg[0];
        #pragma unroll
        for (int j = 1; j < 10; j++) m = fmaxf(m, lg[j]);
        float s = 0.0f;
        #pragma unroll
        for (int j = 0; j < 10; j++) s += expf(lg[j] - m);
        float lse = logf(s) + m;
        #pragma unroll
        for (int j = 0; j < 10; j++) out[(size_t)row * 10 + j] = lg[j] - lse;
    }
}

// ---------- launch ----------

static inline int cdiv(long long a, int b) { return (int)((a + b - 1) / b); }

extern "C" void kernel_launch(void* const* d_in, const int* in_sizes, int n_in,
                              void* d_out, int out_size, void* d_ws, size_t ws_size,
                              hipStream_t stream) {
    const int N1 = N1c, N2 = N2c, N3 = N3c, B8 = B8c;
    const int B = B8 / 8;

    const float* x      = (const float*)d_in[0];
    const int*   cl0    = (const int*)d_in[1];
    const int*   ei1    = (const int*)d_in[2];
    const float* ps1    = (const float*)d_in[3];
    const int*   cl1    = (const int*)d_in[4];
    const int*   ei2    = (const int*)d_in[5];
    const float* ps2    = (const float*)d_in[6];
    const int*   cl2    = (const int*)d_in[7];
    const int*   ei3    = (const int*)d_in[8];
    const float* ps3    = (const float*)d_in[9];
    const int*   cl3    = (const int*)d_in[10];
    const float* W1     = (const float*)d_in[11];
    const float* root1  = (const float*)d_in[12];
    const float* b1     = (const float*)d_in[13];
    const float* W2     = (const float*)d_in[14];
    const float* root2  = (const float*)d_in[15];
    const float* b2     = (const float*)d_in[16];
    const float* W3     = (const float*)d_in[17];
    const float* root3  = (const float*)d_in[18];
    const float* b3     = (const float*)d_in[19];
    const float* fc_w   = (const float*)d_in[20];
    const float* fc_b   = (const float*)d_in[21];
    float* out = (float*)d_out;

    const int E1 = in_sizes[2] / 2;
    const int E2 = in_sizes[5] / 2;
    const int E3 = in_sizes[8] / 2;
    const long long Etot = (long long)E1 + E2 + E3;
    const long long IT = Etot + N0c + N1c + N2c + N3c;

    const int grid2 = cdiv((long long)E2 + 64 * 255, 256);
    const int grid3 = cdiv((long long)E3 + 64 * 255, 256);
    const int pad2 = grid2 * 256, pad3 = grid3 * 256;
    const int ymax = (E2 > E3 ? E2 : E3);

    // ---- workspace layout ----
    char* wp = (char*)d_ws;
    float* p0  = (float*)wp;               wp += (size_t)N1 * 4;
    float* h1  = (float*)wp;               wp += (size_t)N1 * 32 * 4;
    float* p1  = (float*)wp;               wp += (size_t)N2 * 32 * 4;
    float* h2  = (float*)wp;               wp += (size_t)N2 * 32 * 4;
    float* p2  = (float*)wp;               wp += (size_t)N3 * 32 * 4;
    float* h3  = (float*)wp;               wp += (size_t)N3 * 32 * 4;
    float* p3  = (float*)wp;               wp += (size_t)B8 * 32 * 4;
    // zeroed-together region: [bcnt | gcur | ccnt | ccur]
    int* bcnt  = (int*)wp;                 wp += NBK * 4;
    int* gcur  = (int*)wp;                 wp += NBK * 4;
    int* ccnt  = (int*)wp;                 wp += 128 * 4;
    int* ccur  = (int*)wp;                 wp += 128 * 4;
    size_t zero_bytes = (size_t)(wp - (char*)bcnt);
    int* bbase = (int*)wp;                 wp += NBK * 4;
    int* coff  = (int*)wp;                 wp += 128 * 4;
    int* rows  = (int*)wp;                 wp += (size_t)(SBT + 7) * 4;
    int* mem0  = (int*)wp;                 wp += (size_t)N0c * 4;
    int* mem1  = (int*)wp;                 wp += (size_t)N1c * 4;
    int* mem2  = (int*)wp;                 wp += (size_t)N2c * 4;
    int* mem3  = (int*)wp;                 wp += (size_t)N3c * 4;
    uint2* pay1  = (uint2*)wp;             wp += (size_t)E1 * 8;
    uint4* qe    = (uint4*)wp;             wp += (size_t)Etot * 16;
    uint2* qc    = (uint2*)wp;             wp += (size_t)(N0c + N1c + N2c + N3c) * 8;
    uint2* vpay2 = (uint2*)wp;             wp += (size_t)pad2 * 8;
    uint2* vpay3 = (uint2*)wp;             wp += (size_t)pad3 * 8;
    int* dpos2 = (int*)wp;                 wp += (size_t)pad2 * 4;
    int* dpos3 = (int*)wp;                 wp += (size_t)pad3 * 4;   // contiguous with dpos2
    int* blockcell2 = (int*)wp;            wp += (size_t)grid2 * 4;
    int* blockcell3 = (int*)wp;            wp += (size_t)grid3 * 4;  // contiguous with blockcell2
    _Float16* WT2 = (_Float16*)wp;         wp += (size_t)K3 * 1024 * 2;
    _Float16* WT3 = (_Float16*)wp;         wp += (size_t)K3 * 1024 * 2;
    _Float16* yh = (_Float16*)wp;          // ymax*32 halves

    int* row1  = rows;
    int* row2  = rows + SB1 + 1;
    int* row3  = rows + SB2 + 2;
    int* crow0 = rows + SB3 + 3;
    int* crow1 = rows + SB4 + 4;
    int* crow2 = rows + SB5 + 5;
    int* crow3 = rows + SB6 + 6;

    const int T = 256;
    const int CH = 16384;
    const int gridC = cdiv(IT, CH);

    // ========== indexing phase (input-only, radix-style, no per-item global atomics) ==========
    hipMemsetAsync(bcnt, 0, zero_bytes, stream);
    hipMemsetAsync(dpos2, 0xFF, ((size_t)pad2 + pad3) * 4, stream);
    hipMemsetAsync(blockcell2, 0xFF, ((size_t)grid2 + grid3) * 4, stream);
    wtrans_kernel<<<cdiv((long long)K3 * 1024, T), T, 0, stream>>>(W2, W3, WT2, WT3);
    coarse_hist<<<gridC, 1024, 0, stream>>>(ei1, ei2, ei3, cl0, cl1, cl2, cl3,
                                            bcnt, E1, E2, E3, CH, IT);
    bucket_scan<<<1, 512, 0, stream>>>(bcnt, bbase, rows, E1, E2, E3);
    scatter_coarse<<<gridC, 1024, 0, stream>>>(
        ei1, ei2, ei3, ps1, ps2, ps3, cl0, cl1, cl2, cl3,
        bbase, gcur, ccnt, qe, qc, E1, E2, E3, CH, IT);
    coff_build<<<1, 64, 0, stream>>>(ccnt, coff, blockcell2, blockcell3);
    pass2_all<<<NBK, 1024, 0, stream>>>(
        qe, qc, bbase, bcnt, rows, pay1, vpay2, dpos2, vpay3, dpos3,
        mem0, mem1, mem2, mem3, ccur, coff, E1, E2, E3);

    // ========== pipeline ==========
    pool1ch_kernel<<<cdiv(N1, T), T, 0, stream>>>(x, crow0, mem0, p0, N1);

    conv1_node_kernel<<<cdiv((long long)N1 * 32, T), T, 0, stream>>>(
        p0, pay1, row1, W1, root1, b1, h1, N1);

    pool32ch_kernel<<<cdiv((long long)N2 * 32, T), T, 0, stream>>>(h1, crow1, mem1, p1, N2);

    conv_cell_mfma<<<grid2, 256, 0, stream>>>(p1, vpay2, dpos2, blockcell2, WT2, yh, E2);
    gather_fin_kernel<<<cdiv((long long)N2 * 32, T), T, 0, stream>>>(
        yh, row2, p1, root2, b2, h2, N2);

    pool32ch_kernel<<<cdiv((long long)N3 * 32, T), T, 0, stream>>>(h2, crow2, mem2, p2, N3);

    conv_cell_mfma<<<grid3, 256, 0, stream>>>(p2, vpay3, dpos3, blockcell3, WT3, yh, E3);
    gather_fin_kernel<<<cdiv((long long)N3 * 32, T), T, 0, stream>>>(
        yh, row3, p2, root3, b3, h3, N3);

    pool32ch_kernel<<<cdiv((long long)B8 * 32, T), T, 0, stream>>>(h3, crow3, mem3, p3, B8);

    fc_kernel<<<cdiv((long long)B * 32, T), T, 0, stream>>>(p3, fc_w, fc_b, out, B);
}